// Round 9
// baseline (150.981 us; speedup 1.0000x reference)
//
#include <hip/hip_runtime.h>

#define DEV __device__ __forceinline__

typedef __attribute__((ext_vector_type(8))) __bf16 bf16x8;
typedef __attribute__((ext_vector_type(4))) float f32x4;
typedef __attribute__((ext_vector_type(8))) unsigned short ushort8;
typedef __attribute__((ext_vector_type(2))) unsigned short ushort2v;
typedef __attribute__((ext_vector_type(2))) unsigned int uint2v;

DEV float sigmoidf_(float x){ return 1.0f/(1.0f + __expf(-x)); }
DEV float tanhf_(float x){
    x = fminf(15.0f, fmaxf(-15.0f, x));
    float e = __expf(2.0f*x);
    return (e - 1.0f)/(e + 1.0f);
}
DEV unsigned short f2bf(float f){
    unsigned u = __builtin_bit_cast(unsigned, f);
    unsigned r = (u + 0x7FFFu + ((u>>16)&1u)) >> 16;
    return (unsigned short)r;
}
DEV float bf2f(unsigned short u){
    return __builtin_bit_cast(float, ((unsigned)u)<<16);
}
DEV unsigned cvt_pk_bf16(float lo, float hi){
    unsigned r;
    asm("v_cvt_pk_bf16_f32 %0, %1, %2" : "=v"(r) : "v"(lo), "v"(hi));
    return r;
}

// ---------- merged prep: conv/proj/mix weights -> bf16 packs ; pack x,h -> buf1, h -> buf2-lo ----------
__global__ __launch_bounds__(256)
void prep_kernel(const float* __restrict__ conv_w, const float* __restrict__ convL_w,
                 const float* __restrict__ wz, const float* __restrict__ wm,
                 const float* __restrict__ wq, const float* __restrict__ wk,
                 const float* __restrict__ wv, const float* __restrict__ wk2,
                 const float* __restrict__ wv2,
                 const float* __restrict__ x, const float* __restrict__ h,
                 unsigned short* __restrict__ wpk1, unsigned short* __restrict__ wpk2,
                 unsigned short* __restrict__ wzb, unsigned short* __restrict__ wmb,
                 unsigned short* __restrict__ wph, unsigned short* __restrict__ wpm,
                 unsigned short* __restrict__ buf1, unsigned short* __restrict__ buf2)
{
    __shared__ float tile[128][65];
    if (blockIdx.x < 1152) {
        int idx = blockIdx.x*256 + threadIdx.x;
        {
            int co  = idx / (128*9);
            int rem = idx - co*(128*9);
            int ci  = rem / 9;
            int tap = rem - ci*9;
            int kchunk = (ci>>5)*9 + tap;
            int o = (kchunk*256 + co)*32 + (ci&31);
            wpk1[o] = f2bf(conv_w[idx]);
            wpk2[o] = f2bf(convL_w[idx]);
        }
        if (idx < 128*128) wzb[idx] = f2bf(wz[idx]);
        if (idx < 192*192) wmb[idx] = f2bf(wm[idx]);
        if (idx < 32*64){
            wph[idx]        = f2bf(wq[idx]);
            wph[2048 + idx] = f2bf(wk[idx]);
            wpm[idx]        = f2bf(wk2[idx]);
        }
        if (idx < 64*64){
            wph[4096 + idx] = f2bf(wv[idx]);
            wpm[2048 + idx] = f2bf(wv2[idx]);
        }
    } else {
        int bx = blockIdx.x - 1152;
        int b  = bx >> 4;
        int p0 = (bx & 15) * 64;
        int t  = threadIdx.x;
        for (int k=t;k<8192;k+=256){
            int ci = k>>6, pp = k&63;
            const float* s = (ci<64) ? x + (size_t)(b*64+ci)*1024
                                     : h + (size_t)(b*64+ci-64)*1024;
            tile[ci][pp] = s[p0+pp];
        }
        __syncthreads();
        for (int k=t;k<4096;k+=256){
            int pp = k>>6, c2 = k&63;
            ushort2v v;
            v.x = f2bf(tile[c2*2][pp]);
            v.y = f2bf(tile[c2*2+1][pp]);
            *reinterpret_cast<ushort2v*>(buf1 + (size_t)(b*1024+p0+pp)*128 + c2*2) = v;
            if (c2 >= 32)
                *reinterpret_cast<ushort2v*>(buf2 + (size_t)(b*1024+p0+pp)*128 + (c2-32)*2) = v;
        }
    }
}

// ---------- implicit-GEMM 3x3 conv via MFMA: 2-row tiles, 4 blocks/CU ----------
// inp: [16][1024pix][128ci] bf16 ; wpk: [36][256co][32] bf16 ; out: [16][256][1024] bf16
// stats: [16][256][16][2] f32
__global__ __launch_bounds__(256, 4)
void conv_mfma_kernel(const unsigned short* __restrict__ inp,
                      const unsigned short* __restrict__ wpk,
                      const float* __restrict__ bias,
                      unsigned short* __restrict__ out,
                      float* __restrict__ stats)
{
    const int b   = blockIdx.z;
    const int co0 = blockIdx.y * 64;
    const int r0  = blockIdx.x * 2;
    const int t   = threadIdx.x;
    const int l   = t & 63;
    const int wv  = t >> 6;
    const int l15 = l & 15;
    const int lhi = l >> 4;
    const int wrow = wv & 1;      // output row within the 2-row tile
    const int wcol = wv >> 1;     // column half (0: cols 0-15, 1: 16-31)

    __shared__ __align__(16) unsigned short in_t[17408];  // 136 pixlin x 128ci, swizzled (34KB)
    __shared__ float red_s[4][64];
    __shared__ float red_q[4][64];

    for (int it = t; it < 2176; it += 256) {
        int pixlin = it >> 4, oct = it & 15;
        int rr = pixlin / 34;
        int cc = pixlin - rr*34;
        int gr = r0 + rr - 1, gc = cc - 1;
        ushort8 v = {};
        if ((unsigned)gr < 32u && (unsigned)gc < 32u)
            v = *reinterpret_cast<const ushort8*>(
                    inp + ((size_t)(b*1024 + gr*32 + gc)*128) + oct*8);
        unsigned byte = (unsigned)(pixlin*256 + oct*16) ^ (((unsigned)pixlin & 7u) << 4);
        *reinterpret_cast<ushort8*>(reinterpret_cast<char*>(in_t) + byte) = v;
    }

    f32x4 acc[4];
#pragma unroll
    for (int i=0;i<4;i++) acc[i] = (f32x4){0.f,0.f,0.f,0.f};

    __syncthreads();

    bf16x8 afc[4], afn[4];
#define LDA_(K, DST) do { const unsigned short* wrow_ = wpk + ((K)*256 + co0)*32; \
        for (int i_=0;i_<4;i_++) DST[i_] = *reinterpret_cast<const bf16x8*>(wrow_ + (i_*16 + l15)*32 + lhi*8); } while(0)

    LDA_(0, afc);
#pragma unroll
    for (int k=0; k<36; ++k){
        if (k < 35) LDA_(k+1, afn);
        const int cic = k/9, tap = k - 9*(k/9);
        const int ky = tap/3, kx = tap - 3*(tap/3);
        int pixlin = (wrow + ky)*34 + (wcol*16 + l15 + kx);
        unsigned byte = (unsigned)(pixlin*256 + cic*64 + lhi*16)
                        ^ (((unsigned)pixlin & 7u) << 4);
        bf16x8 bfr = *reinterpret_cast<const bf16x8*>(
                         reinterpret_cast<const char*>(in_t) + byte);
#pragma unroll
        for (int i=0;i<4;i++)
            acc[i] = __builtin_amdgcn_mfma_f32_16x16x32_bf16(afc[i], bfr, acc[i], 0,0,0);
        if (k < 35){
#pragma unroll
            for (int i=0;i<4;i++) afc[i] = afn[i];
        }
    }
#undef LDA_

    const int orow = r0 + wrow;
    const int ocol = wcol*16 + l15;
    float s_ir[4][4], q_ir[4][4];
#pragma unroll
    for (int i=0;i<4;i++){
        int cobase = co0 + i*16 + lhi*4;
#pragma unroll
        for (int r=0;r<4;r++){
            float e0 = acc[i][r] + bias[cobase+r];
            out[(size_t)(b*256 + cobase + r)*1024 + orow*32 + ocol] = f2bf(e0);
            s_ir[i][r] = e0;
            q_ir[i][r] = e0*e0;
        }
    }
#pragma unroll
    for (int i=0;i<4;i++)
#pragma unroll
        for (int r=0;r<4;r++){
            float s = s_ir[i][r], q = q_ir[i][r];
            s += __shfl_xor(s,1); q += __shfl_xor(q,1);
            s += __shfl_xor(s,2); q += __shfl_xor(q,2);
            s += __shfl_xor(s,4); q += __shfl_xor(q,4);
            s += __shfl_xor(s,8); q += __shfl_xor(q,8);
            s_ir[i][r] = s; q_ir[i][r] = q;
        }
    if (l15 == 0){
#pragma unroll
        for (int i=0;i<4;i++)
#pragma unroll
            for (int r=0;r<4;r++){
                red_s[wv][i*16 + lhi*4 + r] = s_ir[i][r];
                red_q[wv][i*16 + lhi*4 + r] = q_ir[i][r];
            }
    }
    __syncthreads();
    if (t < 64){
        float S = red_s[0][t]+red_s[1][t]+red_s[2][t]+red_s[3][t];
        float Q = red_q[0][t]+red_q[1][t]+red_q[2][t]+red_q[3][t];
        float* sp = stats + ((size_t)(b*256 + co0 + t)*16 + blockIdx.x)*2;
        sp[0] = S; sp[1] = Q;
    }
}

// ---------- GN gate1, 32-pixel tiles ----------
__global__ __launch_bounds__(256)
void gn_gate1_kernel(const unsigned short* __restrict__ cc, const float* __restrict__ stats,
                     const float* __restrict__ gnw, const float* __restrict__ gnb,
                     const float* __restrict__ c_in,
                     unsigned short* __restrict__ buf2, unsigned short* __restrict__ sig_pm)
{
    const int b  = blockIdx.y;
    const int p0 = blockIdx.x * 32;
    const int t  = threadIdx.x;
    __shared__ float sc[256][2];
    __shared__ __align__(16) unsigned short cct[10240];   // [256ch][40] (80B rows)

    {
        const float* sp = stats + (size_t)(b*256 + t)*32;
        float S=0.f, Q=0.f;
#pragma unroll
        for (int k=0;k<16;k++){ S += sp[2*k]; Q += sp[2*k+1]; }
        float mu  = S*(1.0f/1024.0f);
        float var = Q*(1.0f/1024.0f) - mu*mu;
        float rs  = rsqrtf(var + 1e-5f);
        float gw  = gnw[t];
        sc[t][0] = rs*gw;
        sc[t][1] = gnb[t] - mu*rs*gw;
    }
    for (int it=t; it<1024; it+=256){
        int row = it>>2, oct = it&3;
        ushort8 v = *reinterpret_cast<const ushort8*>(
            cc + (size_t)(b*256+row)*1024 + p0 + oct*8);
        *reinterpret_cast<ushort8*>(cct + row*40 + oct*8) = v;
    }
    __syncthreads();

    const int p = t & 31, cg = t >> 5;
    float cn[8], so[8];
#pragma unroll
    for (int j=0;j<8;j++){
        int ch = cg*8 + j;
        float xg[4];
#pragma unroll
        for (int g=0; g<4; g++){
            int row = g*64 + ch;
            float v = bf2f(cct[row*40 + p]);
            xg[g] = v*sc[row][0] + sc[row][1];
        }
        float cv = c_in[(size_t)(b*64+ch)*1024 + p0 + p];
        cn[j] = sigmoidf_(xg[1])*cv + sigmoidf_(xg[0])*tanhf_(xg[3]);
        so[j] = sigmoidf_(xg[2]);
    }
    ushort8 v0, s0;
#pragma unroll
    for (int j=0;j<8;j++){ v0[j]=f2bf(cn[j]); s0[j]=f2bf(so[j]); }
    size_t prow = (size_t)(b*1024 + p0 + p);
    *reinterpret_cast<ushort8*>(buf2 + prow*128 + 64 + cg*8) = v0;
    *reinterpret_cast<ushort8*>(sig_pm + prow*64 + cg*8)     = s0;
}

// ---------- GN gate2 + projections fused, 32-pixel tiles ----------
__global__ __launch_bounds__(256)
void gn2_proj_kernel(const unsigned short* __restrict__ cc, const float* __restrict__ stats,
                     const float* __restrict__ gnw, const float* __restrict__ gnb,
                     const float* __restrict__ lc_in, const unsigned short* __restrict__ sig_pm,
                     const float* __restrict__ m_in,
                     const unsigned short* __restrict__ wph, const unsigned short* __restrict__ wpm,
                     const float* __restrict__ bq, const float* __restrict__ bk,
                     const float* __restrict__ bv, const float* __restrict__ bk2,
                     const float* __restrict__ bv2,
                     float* __restrict__ out_lc, float* __restrict__ out_c,
                     unsigned short* __restrict__ hT,
                     unsigned short* __restrict__ Qb, unsigned short* __restrict__ Khb,
                     unsigned short* __restrict__ Kmb,
                     unsigned short* __restrict__ Vhb, unsigned short* __restrict__ Vmb)
{
    const int b  = blockIdx.y;
    const int p0 = blockIdx.x * 32;
    const int t  = threadIdx.x;
    const int l  = t & 63;
    const int w  = t >> 6;
    const int l15 = l & 15, lhi = l >> 4;

    __shared__ float sc[256][2];
    // phase1: [256ch][40] gate tile (20KB). phase2 reuse (bytes):
    //   hp [0,4096) ; mp [4096,8192) ; qk [8192,12288) ; km [12288,16384)
    __shared__ __align__(16) unsigned short cct[10240];

    {
        const float* sp = stats + (size_t)(b*256 + t)*32;
        float S=0.f, Q=0.f;
#pragma unroll
        for (int k=0;k<16;k++){ S += sp[2*k]; Q += sp[2*k+1]; }
        float mu  = S*(1.0f/1024.0f);
        float var = Q*(1.0f/1024.0f) - mu*mu;
        float rs  = rsqrtf(var + 1e-5f);
        float gw  = gnw[t];
        sc[t][0] = rs*gw;
        sc[t][1] = gnb[t] - mu*rs*gw;
    }
    for (int it=t; it<1024; it+=256){
        int row = it>>2, oct = it&3;
        ushort8 v = *reinterpret_cast<const ushort8*>(
            cc + (size_t)(b*256+row)*1024 + p0 + oct*8);
        *reinterpret_cast<ushort8*>(cct + row*40 + oct*8) = v;
    }
    __syncthreads();

    const int p = t & 31, cg = t >> 5;
    const size_t prow = (size_t)(b*1024 + p0 + p);
    float hm[8], mr[8];
    {
        ushort8 sv = *reinterpret_cast<const ushort8*>(sig_pm + prow*64 + cg*8);
#pragma unroll
        for (int j=0;j<8;j++){
            int ch = cg*8 + j;
            float xg[4];
#pragma unroll
            for (int g=0; g<4; g++){
                int row = g*64 + ch;
                float v = bf2f(cct[row*40 + p]);
                xg[g] = v*sc[row][0] + sc[row][1];
            }
            float lv  = lc_in[(size_t)(b*64+ch)*1024 + p0 + p];
            float lcn = sigmoidf_(xg[1])*lv + sigmoidf_(xg[0])*tanhf_(xg[3]);
            float cnx = sigmoidf_(xg[2])*tanhf_(lcn);
            out_lc[(size_t)(b*64+ch)*1024 + p0 + p] = lcn;
            out_c [(size_t)(b*64+ch)*1024 + p0 + p] = cnx;
            hm[j] = bf2f(sv[j])*tanhf_(cnx);
            mr[j] = m_in[(size_t)(b*64+ch)*1024 + p0 + p];
        }
    }
    __syncthreads();   // all cct gate reads done

    {
        ushort8 h0, m0;
#pragma unroll
        for (int j=0;j<8;j++){ h0[j]=f2bf(hm[j]); m0[j]=f2bf(mr[j]); }
        unsigned hb = (unsigned)(p*128) + (((unsigned)(cg*16)) ^ ((unsigned)(p&7)<<4));
        *reinterpret_cast<ushort8*>(reinterpret_cast<char*>(cct) + hb) = h0;
        *reinterpret_cast<ushort8*>(reinterpret_cast<char*>(cct) + 4096 + hb) = m0;
        *reinterpret_cast<ushort8*>(hT + prow*64 + cg*8) = h0;
    }
    __syncthreads();

    // proj: waves 0-1 -> h (Q,K,V), waves 2-3 -> m (Km,Vm). pixel frag = (w&1)*16.
    const int pass = w >> 1;
    const int pix  = (w&1)*16 + l15;
    const unsigned xsw = ((unsigned)(pix&7)) << 4;
    if (pass == 0){
        f32x4 dh[8];
#pragma unroll
        for (int i=0;i<8;i++) dh[i] = (f32x4){0.f,0.f,0.f,0.f};
#pragma unroll
        for (int ks=0; ks<2; ++ks){
            unsigned xb = (unsigned)(pix*128) + (((unsigned)(ks*64 + lhi*16)) ^ xsw);
            bf16x8 xh = *reinterpret_cast<const bf16x8*>(reinterpret_cast<const char*>(cct) + xb);
#pragma unroll
            for (int ocf=0; ocf<8; ocf++){
                bf16x8 af = *reinterpret_cast<const bf16x8*>(
                    wph + (size_t)(ocf*16 + l15)*64 + ks*32 + lhi*8);
                dh[ocf] = __builtin_amdgcn_mfma_f32_16x16x32_bf16(af, xh, dh[ocf], 0,0,0);
            }
        }
#pragma unroll
        for (int ocf=0; ocf<4; ocf++)
#pragma unroll
            for (int r=0;r<4;r++){
                int vc = ocf*16 + lhi*4 + r;
                Vhb[(size_t)(b*64+vc)*1024 + p0 + pix] = f2bf(dh[4+ocf][r] + bv[vc]);
            }
#pragma unroll
        for (int ocf=0; ocf<2; ocf++)
#pragma unroll
            for (int r=0;r<4;r++){
                int qc = ocf*16 + lhi*4 + r;
                unsigned byq = (unsigned)(pix*128) + (((unsigned)(qc*2))      ^ xsw);
                unsigned byk = (unsigned)(pix*128) + (((unsigned)(64 + qc*2)) ^ xsw);
                *reinterpret_cast<unsigned short*>(reinterpret_cast<char*>(cct) + 8192 + byq)
                    = f2bf(dh[ocf][r]   + bq[qc]);
                *reinterpret_cast<unsigned short*>(reinterpret_cast<char*>(cct) + 8192 + byk)
                    = f2bf(dh[2+ocf][r] + bk[qc]);
            }
    } else {
        f32x4 dm[6];
#pragma unroll
        for (int i=0;i<6;i++) dm[i] = (f32x4){0.f,0.f,0.f,0.f};
#pragma unroll
        for (int ks=0; ks<2; ++ks){
            unsigned xb = (unsigned)(pix*128) + (((unsigned)(ks*64 + lhi*16)) ^ xsw);
            bf16x8 xm = *reinterpret_cast<const bf16x8*>(
                reinterpret_cast<const char*>(cct) + 4096 + xb);
#pragma unroll
            for (int ocf=0; ocf<6; ocf++){
                bf16x8 am = *reinterpret_cast<const bf16x8*>(
                    wpm + (size_t)(ocf*16 + l15)*64 + ks*32 + lhi*8);
                dm[ocf] = __builtin_amdgcn_mfma_f32_16x16x32_bf16(am, xm, dm[ocf], 0,0,0);
            }
        }
#pragma unroll
        for (int ocf=0; ocf<4; ocf++)
#pragma unroll
            for (int r=0;r<4;r++){
                int vc = ocf*16 + lhi*4 + r;
                Vmb[(size_t)(b*64+vc)*1024 + p0 + pix] = f2bf(dm[2+ocf][r] + bv2[vc]);
            }
#pragma unroll
        for (int ocf=0; ocf<2; ocf++)
#pragma unroll
            for (int r=0;r<4;r++){
                int qc = ocf*16 + lhi*4 + r;
                unsigned byq = (unsigned)(pix*128) + (((unsigned)(qc*2)) ^ xsw);
                *reinterpret_cast<unsigned short*>(reinterpret_cast<char*>(cct) + 12288 + byq)
                    = f2bf(dm[ocf][r] + bk2[qc]);
            }
    }
    __syncthreads();

    {   // flush Q/K: 32 rows x 8 octs
        int pr = t>>3, oct = t&7;
        unsigned byte = (unsigned)(pr*128) + (((unsigned)(oct*16)) ^ ((unsigned)(pr&7)<<4));
        ushort8 v = *reinterpret_cast<const ushort8*>(
            reinterpret_cast<const char*>(cct) + 8192 + byte);
        if (oct < 4) *reinterpret_cast<ushort8*>(Qb  + (size_t)(b*1024+p0+pr)*32 + oct*8) = v;
        else         *reinterpret_cast<ushort8*>(Khb + (size_t)(b*1024+p0+pr)*32 + (oct-4)*8) = v;
    }
    if (t < 128){  // flush Km: 32 rows x 4 octs
        int pr = t>>2, oct = t&3;
        unsigned byte = (unsigned)(pr*128) + (((unsigned)(oct*16)) ^ ((unsigned)(pr&7)<<4));
        ushort8 v = *reinterpret_cast<const ushort8*>(
            reinterpret_cast<const char*>(cct) + 12288 + byte);
        *reinterpret_cast<ushort8*>(Kmb + (size_t)(b*1024+p0+pr)*32 + oct*8) = v;
    }
}

// ---------- fused attention + final mix ----------
__global__ __launch_bounds__(256)
void attn_final_kernel(const unsigned short* __restrict__ Qb,
                       const unsigned short* __restrict__ Kh,
                       const unsigned short* __restrict__ Km,
                       const unsigned short* __restrict__ Vh,
                       const unsigned short* __restrict__ Vm,
                       const unsigned short* __restrict__ hT,
                       const unsigned short* __restrict__ wzb,
                       const unsigned short* __restrict__ wmb,
                       const float* __restrict__ bz, const float* __restrict__ bm,
                       const float* __restrict__ m_in,
                       float* __restrict__ out_h, float* __restrict__ out_m)
{
    const int bid  = blockIdx.x;
    const int xcd  = bid & 7;
    const int slot = bid >> 3;
    const int b    = xcd*2 + (slot>>5);
    const int p0   = (slot & 31) * 32;
    const int t   = threadIdx.x;
    const int l   = t & 63;
    const int w   = t >> 6;
    const int l15 = l & 15, g = l >> 4;
    const int pass = w >> 1;
    const int ph   = w & 1;

    __shared__ __align__(16) unsigned short Kt[2][2][2560];
    __shared__ __align__(16) unsigned short Vt[2][2][4096];
    __shared__ __align__(16) unsigned short Pt[2][2048];
    __shared__ __align__(16) unsigned short Bs[32*192];

    const bf16x8 qa = *reinterpret_cast<const bf16x8*>(
        Qb + (size_t)(b*1024 + p0 + ph*16 + l15)*32 + g*8);

    float m_run = -1e30f, l_run = 0.0f;
    f32x4 acc[4];
#pragma unroll
    for (int cf=0;cf<4;cf++) acc[cf] = (f32x4){0.f,0.f,0.f,0.f};

    const int krow = t>>2, koct = t&3;
    const int vrow = t>>3, voct = t&7;
    const unsigned kwb  = (unsigned)(krow*80 + koct*16);
    const unsigned vwb0 = (unsigned)(vrow*128)      + (((unsigned)voct*16) ^ ((unsigned)(vrow&7)<<4));
    const unsigned vwb1 = (unsigned)((vrow+32)*128) + (((unsigned)voct*16) ^ ((unsigned)((vrow+32)&7)<<4));

    ushort8 kr0, kr1, vv0, vv1, vv2, vv3;
#define LDSTAGE(Q0N) do { \
        kr0 = *reinterpret_cast<const ushort8*>(Kh + (size_t)(b*1024 + (Q0N) + krow)*32 + koct*8); \
        kr1 = *reinterpret_cast<const ushort8*>(Km + (size_t)(b*1024 + (Q0N) + krow)*32 + koct*8); \
        vv0 = *reinterpret_cast<const ushort8*>(Vh + (size_t)(b*64 + vrow)*1024 + (Q0N) + voct*8); \
        vv1 = *reinterpret_cast<const ushort8*>(Vh + (size_t)(b*64 + vrow+32)*1024 + (Q0N) + voct*8); \
        vv2 = *reinterpret_cast<const ushort8*>(Vm + (size_t)(b*64 + vrow)*1024 + (Q0N) + voct*8); \
        vv3 = *reinterpret_cast<const ushort8*>(Vm + (size_t)(b*64 + vrow+32)*1024 + (Q0N) + voct*8); \
    } while(0)
#define WRSTAGE(BUF) do { \
        *reinterpret_cast<ushort8*>(reinterpret_cast<char*>(Kt[0][BUF]) + kwb)  = kr0; \
        *reinterpret_cast<ushort8*>(reinterpret_cast<char*>(Kt[1][BUF]) + kwb)  = kr1; \
        *reinterpret_cast<ushort8*>(reinterpret_cast<char*>(Vt[0][BUF]) + vwb0) = vv0; \
        *reinterpret_cast<ushort8*>(reinterpret_cast<char*>(Vt[0][BUF]) + vwb1) = vv1; \
        *reinterpret_cast<ushort8*>(reinterpret_cast<char*>(Vt[1][BUF]) + vwb0) = vv2; \
        *reinterpret_cast<ushort8*>(reinterpret_cast<char*>(Vt[1][BUF]) + vwb1) = vv3; \
    } while(0)

    LDSTAGE(0);
    WRSTAGE(0);
    __syncthreads();

    const unsigned prow = (unsigned)(ph*16 + l15);
    const unsigned psw  = (prow & 7u) << 4;
    char* Pbase = reinterpret_cast<char*>(Pt[pass]);

    for (int it=0; it<16; ++it){
        const int cur = it & 1;
        if (it < 15) LDSTAGE((it+1)*64);

        f32x4 s2[4];
#pragma unroll
        for (int qt=0; qt<4; qt++){
            const bf16x8 kb = *reinterpret_cast<const bf16x8*>(
                reinterpret_cast<const char*>(Kt[pass][cur]) + (qt*16 + l15)*80 + g*16);
            s2[qt] = __builtin_amdgcn_mfma_f32_16x16x32_bf16(kb, qa, (f32x4){0.f,0.f,0.f,0.f}, 0,0,0);
        }

        float pm = s2[0][0];
#pragma unroll
        for (int qt=0; qt<4; qt++)
#pragma unroll
            for (int r=0;r<4;r++) pm = fmaxf(pm, s2[qt][r]);
        pm = fmaxf(pm, __shfl_xor(pm, 16));
        pm = fmaxf(pm, __shfl_xor(pm, 32));

        if (!__all(pm <= m_run + 8.0f)){
            float mn = fmaxf(m_run, pm);
            float f  = __expf(m_run - mn);
            m_run = mn;
            l_run *= f;
#pragma unroll
            for (int r=0;r<4;r++){
                float fr = __shfl(f, (l & 48) | ((l>>4)*4 + r), 64);
#pragma unroll
                for (int cf=0;cf<4;cf++) acc[cf][r] *= fr;
            }
        }

        float e[4][4];
        float lsum = 0.f;
#pragma unroll
        for (int qt=0; qt<4; qt++)
#pragma unroll
            for (int r=0;r<4;r++){
                float ev = __expf(s2[qt][r] - m_run);
                e[qt][r] = ev;
                lsum += ev;
            }
        lsum += __shfl_xor(lsum, 16);
        lsum += __shfl_xor(lsum, 32);
        l_run += lsum;

#pragma unroll
        for (int qt=0; qt<4; qt++){
            uint2v pk;
            pk.x = cvt_pk_bf16(e[qt][0], e[qt][1]);
            pk.y = cvt_pk_bf16(e[qt][2], e[qt][3]);
            unsigned byte = prow*128 + (((unsigned)(qt*32 + g*8)) ^ psw);
            *reinterpret_cast<uint2v*>(Pbase + byte) = pk;
        }

#pragma unroll
        for (int ks=0;ks<2;ks++){
            unsigned abyte = prow*128 + (((unsigned)(ks*64 + g*16)) ^ psw);
            const bf16x8 pa = *reinterpret_cast<const bf16x8*>(Pbase + abyte);
#pragma unroll
            for (int cf=0;cf<4;cf++){
                unsigned vrw = (unsigned)(cf*16 + l15);
                unsigned vbyte = vrw*128 + (((unsigned)(ks*64 + g*16)) ^ ((vrw&7u)<<4));
                const bf16x8 vb = *reinterpret_cast<const bf16x8*>(
                    reinterpret_cast<const char*>(Vt[pass][cur]) + vbyte);
                acc[cf] = __builtin_amdgcn_mfma_f32_16x16x32_bf16(pa, vb, acc[cf], 0,0,0);
            }
        }

        if (it < 15) WRSTAGE(cur^1);
        __syncthreads();
    }
#undef LDSTAGE
#undef WRSTAGE

    {
        float rl = 1.0f / l_run;
        float rr[4];
#pragma unroll
        for (int r=0;r<4;r++) rr[r] = __shfl(rl, (l & 48) | ((l>>4)*4 + r), 64);
#pragma unroll
        for (int cf=0;cf<4;cf++)
#pragma unroll
            for (int r=0;r<4;r++){
                unsigned pix = (unsigned)(ph*16 + g*4 + r);
                unsigned cch = (unsigned)(pass*64 + cf*16 + l15);
                unsigned byte = pix*384 + ((cch*2) ^ ((pix&7u)<<4));
                *reinterpret_cast<unsigned short*>(reinterpret_cast<char*>(Bs) + byte)
                    = f2bf(acc[cf][r]*rr[r]);
            }
    }
    {
        int row = t>>3, oct = t&7;
        ushort8 v = *reinterpret_cast<const ushort8*>(
            hT + (size_t)(b*1024 + p0 + row)*64 + oct*8);
        unsigned byte = (unsigned)(row*384) + 256u + (((unsigned)oct*16) ^ ((unsigned)(row&7)<<4));
        *reinterpret_cast<ushort8*>(reinterpret_cast<char*>(Bs) + byte) = v;
    }
    __syncthreads();

    f32x4 acc1[2][2];
#pragma unroll
    for (int i=0;i<2;i++)
#pragma unroll
        for (int cf=0;cf<2;cf++) acc1[i][cf] = (f32x4){0.f,0.f,0.f,0.f};
#pragma unroll
    for (int ks=0; ks<4; ++ks){
        bf16x8 af[2];
#pragma unroll
        for (int i=0;i<2;i++)
            af[i] = *reinterpret_cast<const bf16x8*>(
                wzb + (size_t)(w*32 + i*16 + l15)*128 + ks*32 + g*8);
#pragma unroll
        for (int cf=0;cf<2;cf++){
            unsigned p = (unsigned)(cf*16 + l15);
            unsigned byte = p*384 + (((unsigned)(ks*64 + g*16)) ^ ((p&7u)<<4));
            const bf16x8 bfr = *reinterpret_cast<const bf16x8*>(
                reinterpret_cast<const char*>(Bs) + byte);
            acc1[0][cf] = __builtin_amdgcn_mfma_f32_16x16x32_bf16(af[0], bfr, acc1[0][cf], 0,0,0);
            acc1[1][cf] = __builtin_amdgcn_mfma_f32_16x16x32_bf16(af[1], bfr, acc1[1][cf], 0,0,0);
        }
    }
    __syncthreads();
#pragma unroll
    for (int i=0;i<2;i++){
        int co = w*32 + i*16 + g*4;
#pragma unroll
        for (int cf=0;cf<2;cf++){
            unsigned p = (unsigned)(cf*16 + l15);
#pragma unroll
            for (int r=0;r<4;r++){
                float val = acc1[i][cf][r] + bz[co+r];
                unsigned byte = p*384 + (((unsigned)((co+r)*2)) ^ ((p&7u)<<4));
                *reinterpret_cast<unsigned short*>(reinterpret_cast<char*>(Bs) + byte) = f2bf(val);
            }
        }
    }
    __syncthreads();

    f32x4 acc2[3][2];
#pragma unroll
    for (int j=0;j<3;j++)
#pragma unroll
        for (int cf=0;cf<2;cf++) acc2[j][cf] = (f32x4){0.f,0.f,0.f,0.f};
#pragma unroll
    for (int ks=0; ks<6; ++ks){
        bf16x8 am[3];
#pragma unroll
        for (int j=0;j<3;j++)
            am[j] = *reinterpret_cast<const bf16x8*>(
                wmb + (size_t)(j*64 + w*16 + l15)*192 + ks*32 + g*8);
#pragma unroll
        for (int cf=0;cf<2;cf++){
            unsigned p = (unsigned)(cf*16 + l15);
            unsigned byte = p*384 + (((unsigned)(ks*64 + g*16)) ^ ((p&7u)<<4));
            const bf16x8 bfr = *reinterpret_cast<const bf16x8*>(
                reinterpret_cast<const char*>(Bs) + byte);
#pragma unroll
            for (int j=0;j<3;j++)
                acc2[j][cf] = __builtin_amdgcn_mfma_f32_16x16x32_bf16(am[j], bfr, acc2[j][cf], 0,0,0);
        }
    }

    const int ch0 = w*16 + g*4;
#pragma unroll
    for (int cf=0;cf<2;cf++){
        int pix = p0 + cf*16 + l15;
#pragma unroll
        for (int r=0;r<4;r++){
            int ch = ch0 + r;
            float mo = acc2[0][cf][r] + bm[ch];
            float mg = acc2[1][cf][r] + bm[64+ch];
            float mi = sigmoidf_(acc2[2][cf][r] + bm[128+ch]);
            float mv = m_in[(size_t)(b*64+ch)*1024 + pix];
            float mn = (1.0f - mi)*mv + mi*tanhf_(mg);
            out_m[(size_t)(b*64+ch)*1024 + pix] = mn;
            out_h[(size_t)(b*64+ch)*1024 + pix] = sigmoidf_(mo)*mn;
        }
    }
}

extern "C" void kernel_launch(void* const* d_in, const int* in_sizes, int n_in,
                              void* d_out, int out_size, void* d_ws, size_t ws_size,
                              hipStream_t stream)
{
    const float* x      = (const float*)d_in[0];
    const float* h      = (const float*)d_in[1];
    const float* c      = (const float*)d_in[2];
    const float* m      = (const float*)d_in[3];
    const float* lc     = (const float*)d_in[4];
    const float* conv_w = (const float*)d_in[5];
    const float* conv_b = (const float*)d_in[6];
    const float* gn1_w  = (const float*)d_in[7];
    const float* gn1_b  = (const float*)d_in[8];
    const float* convL_w= (const float*)d_in[9];
    const float* convL_b= (const float*)d_in[10];
    const float* gn2_w  = (const float*)d_in[11];
    const float* gn2_b  = (const float*)d_in[12];
    const float* wq  = (const float*)d_in[13];
    const float* bq  = (const float*)d_in[14];
    const float* wk  = (const float*)d_in[15];
    const float* bk  = (const float*)d_in[16];
    const float* wk2 = (const float*)d_in[17];
    const float* bk2 = (const float*)d_in[18];
    const float* wv  = (const float*)d_in[19];
    const float* bv  = (const float*)d_in[20];
    const float* wv2 = (const float*)d_in[21];
    const float* bv2 = (const float*)d_in[22];
    const float* wz  = (const float*)d_in[23];
    const float* bz  = (const float*)d_in[24];
    const float* wmw = (const float*)d_in[25];
    const float* bm  = (const float*)d_in[26];

    float* out = (float*)d_out;
    float* F = (float*)d_ws;
    unsigned short* cc_bf  = (unsigned short*)F;              // [16][256][1024] bf16
    unsigned short* buf1   = (unsigned short*)(F + 4194304);  // conv1 input [16][1024][128]
    unsigned short* buf2   = (unsigned short*)(F + 5242880);  // conv2 input
    unsigned short* hT     = (unsigned short*)(F + 6291456);  // [16][1024][64] bf16
    unsigned short* Qb     = (unsigned short*)(F + 6815744);
    unsigned short* Khb    = (unsigned short*)(F + 7077888);
    unsigned short* Kmb    = (unsigned short*)(F + 7340032);
    unsigned short* Vhb    = (unsigned short*)(F + 7602176);
    unsigned short* Vmb    = (unsigned short*)(F + 8126464);
    unsigned short* sig_pm = (unsigned short*)(F + 8650752);  // [16][1024][64] bf16
    unsigned short* wpk1   = (unsigned short*)(F + 9175040);
    unsigned short* wpk2   = (unsigned short*)(F + 9322496);
    unsigned short* wzb    = (unsigned short*)(F + 9469952);
    unsigned short* wmb    = (unsigned short*)(F + 9478144);
    unsigned short* wph    = (unsigned short*)(F + 9496576);  // [128][64] bf16
    unsigned short* wpm    = (unsigned short*)(F + 9500672);  // [96][64] bf16
    float*          stats  = F + 9503744;                     // [16][256][16][2] f32

    dim3 blk256(256);
    prep_kernel<<<dim3(1408), blk256, 0, stream>>>(conv_w, convL_w, wz, wmw,
                                                   wq, wk, wv, wk2, wv2, x, h,
                                                   wpk1, wpk2, wzb, wmb, wph, wpm,
                                                   buf1, buf2);
    dim3 cgrid(16, 4, 16);
    conv_mfma_kernel<<<cgrid, blk256, 0, stream>>>(buf1, wpk1, conv_b, cc_bf, stats);
    gn_gate1_kernel<<<dim3(32,16), blk256, 0, stream>>>(cc_bf, stats, gn1_w, gn1_b, c,
                                                        buf2, sig_pm);
    conv_mfma_kernel<<<cgrid, blk256, 0, stream>>>(buf2, wpk2, convL_b, cc_bf, stats);
    gn2_proj_kernel<<<dim3(32,16), blk256, 0, stream>>>(cc_bf, stats, gn2_w, gn2_b,
                                                        lc, sig_pm, m, wph, wpm,
                                                        bq, bk, bv, bk2, bv2,
                                                        out + 3*1048576 /*lc_next*/,
                                                        out + 1*1048576 /*c_next*/,
                                                        hT, Qb, Khb, Kmb, Vhb, Vmb);
    attn_final_kernel<<<dim3(512), blk256, 0, stream>>>(Qb, Khb, Kmb, Vhb, Vmb, hT,
                                                        wzb, wmb, bz, bm, m,
                                                        out /*h_next*/, out + 2*1048576 /*m_next*/);
    (void)in_sizes; (void)n_in; (void)out_size; (void)ws_size;
}

// Round 10
// 119.285 us; speedup vs baseline: 1.2657x; 1.2657x over previous
//
#include <hip/hip_runtime.h>

#define DEV __device__ __forceinline__

typedef __attribute__((ext_vector_type(8))) __bf16 bf16x8;
typedef __attribute__((ext_vector_type(4))) float f32x4;
typedef __attribute__((ext_vector_type(8))) unsigned short ushort8;
typedef __attribute__((ext_vector_type(2))) unsigned short ushort2v;
typedef __attribute__((ext_vector_type(2))) unsigned int uint2v;

DEV float sigmoidf_(float x){ return 1.0f/(1.0f + __expf(-x)); }
DEV float tanhf_(float x){
    x = fminf(15.0f, fmaxf(-15.0f, x));
    float e = __expf(2.0f*x);
    return (e - 1.0f)/(e + 1.0f);
}
DEV unsigned short f2bf(float f){
    unsigned u = __builtin_bit_cast(unsigned, f);
    unsigned r = (u + 0x7FFFu + ((u>>16)&1u)) >> 16;
    return (unsigned short)r;
}
DEV float bf2f(unsigned short u){
    return __builtin_bit_cast(float, ((unsigned)u)<<16);
}
DEV unsigned cvt_pk_bf16(float lo, float hi){
    unsigned r;
    asm("v_cvt_pk_bf16_f32 %0, %1, %2" : "=v"(r) : "v"(lo), "v"(hi));
    return r;
}

// ---------- merged prep: weights -> bf16 packs ; pack x,h -> PADDED buf1, h -> PADDED buf2-lo ;
// ---------- border-zero blocks for both padded buffers ----------
// padded layout: [b][34*34=1156 px][128ci] bf16, px = (row+1)*34 + (col+1)
__global__ __launch_bounds__(256)
void prep_kernel(const float* __restrict__ conv_w, const float* __restrict__ convL_w,
                 const float* __restrict__ wz, const float* __restrict__ wm,
                 const float* __restrict__ wq, const float* __restrict__ wk,
                 const float* __restrict__ wv, const float* __restrict__ wk2,
                 const float* __restrict__ wv2,
                 const float* __restrict__ x, const float* __restrict__ h,
                 unsigned short* __restrict__ wpk1, unsigned short* __restrict__ wpk2,
                 unsigned short* __restrict__ wzb, unsigned short* __restrict__ wmb,
                 unsigned short* __restrict__ wph, unsigned short* __restrict__ wpm,
                 unsigned short* __restrict__ buf1, unsigned short* __restrict__ buf2)
{
    __shared__ float tile[128][65];
    if (blockIdx.x < 1152) {
        int idx = blockIdx.x*256 + threadIdx.x;
        {
            int co  = idx / (128*9);
            int rem = idx - co*(128*9);
            int ci  = rem / 9;
            int tap = rem - ci*9;
            int kchunk = (ci>>5)*9 + tap;
            int o = (kchunk*256 + co)*32 + (ci&31);
            wpk1[o] = f2bf(conv_w[idx]);
            wpk2[o] = f2bf(convL_w[idx]);
        }
        if (idx < 128*128) wzb[idx] = f2bf(wz[idx]);
        if (idx < 192*192) wmb[idx] = f2bf(wm[idx]);
        if (idx < 32*64){
            wph[idx]        = f2bf(wq[idx]);
            wph[2048 + idx] = f2bf(wk[idx]);
            wpm[idx]        = f2bf(wk2[idx]);
        }
        if (idx < 64*64){
            wph[4096 + idx] = f2bf(wv[idx]);
            wpm[2048 + idx] = f2bf(wv2[idx]);
        }
    } else if (blockIdx.x < 1184) {
        // border zero: 32 blocks, one per (b, buffer)
        int bx2 = blockIdx.x - 1152;
        int b = bx2 >> 1;
        unsigned short* buf = (bx2 & 1) ? buf2 : buf1;
        for (int i = threadIdx.x; i < 8448; i += 256){
            int px = i >> 6, u = i & 63;
            int rr, cc2;
            if (px < 34)      { rr = 0;         cc2 = px; }
            else if (px < 68) { rr = 33;        cc2 = px-34; }
            else if (px < 100){ rr = px-68+1;   cc2 = 0; }
            else              { rr = px-100+1;  cc2 = 33; }
            reinterpret_cast<unsigned*>(buf + (size_t)(b*1156 + rr*34 + cc2)*128)[u] = 0u;
        }
    } else {
        int bx = blockIdx.x - 1184;
        int b  = bx >> 4;
        int p0 = (bx & 15) * 64;
        int t  = threadIdx.x;
        for (int k=t;k<8192;k+=256){
            int ci = k>>6, pp = k&63;
            const float* s = (ci<64) ? x + (size_t)(b*64+ci)*1024
                                     : h + (size_t)(b*64+ci-64)*1024;
            tile[ci][pp] = s[p0+pp];
        }
        __syncthreads();
        for (int k=t;k<4096;k+=256){
            int pp = k>>6, c2 = k&63;
            int p  = p0 + pp;
            size_t pidx = (size_t)(b*1156 + ((p>>5)+1)*34 + (p&31) + 1);
            ushort2v v;
            v.x = f2bf(tile[c2*2][pp]);
            v.y = f2bf(tile[c2*2+1][pp]);
            *reinterpret_cast<ushort2v*>(buf1 + pidx*128 + c2*2) = v;
            if (c2 >= 32)
                *reinterpret_cast<ushort2v*>(buf2 + pidx*128 + (c2-32)*2) = v;
        }
    }
}

// ---------- implicit-GEMM 3x3 conv via MFMA: padded input, async DMA staging, PF2 ----------
// inp: [16][1156 px][128ci] bf16 padded ; wpk: [36][256co][32] bf16 ; out: [16][256][1024] bf16
// stats: [16][256][8][2] f32
__global__ __launch_bounds__(256)
void conv_mfma_kernel(const unsigned short* __restrict__ inp,
                      const unsigned short* __restrict__ wpk,
                      const float* __restrict__ bias,
                      unsigned short* __restrict__ out,
                      float* __restrict__ stats)
{
    const int b   = blockIdx.z;
    const int co0 = blockIdx.y * 64;
    const int r0  = blockIdx.x * 4;
    const int t   = threadIdx.x;
    const int l   = t & 63;
    const int wv  = t >> 6;
    const int l15 = l & 15;
    const int lhi = l >> 4;

    __shared__ __align__(16) unsigned short in_t[26112];  // 204 pixlin x 128ci, XOR-swizzled
    __shared__ float red_s[4][64];
    __shared__ float red_q[4][64];

    // async global->LDS staging: 51 wave-slots of 1KB, pre-swizzled SOURCE, linear LDS dest
    {
        const char* gsrc = reinterpret_cast<const char*>(inp + (size_t)(b*1156 + r0*34)*128);
#pragma unroll
        for (int it = 0; it < 13; ++it){
            unsigned lbase = (unsigned)(it*4096 + wv*1024);
            if (lbase < 52224u){
                unsigned beta = lbase + (unsigned)l*16u;
                unsigned soff = (beta & ~255u) + ((beta & 0xF0u) ^ (((beta>>8)&7u)<<4));
                __builtin_amdgcn_global_load_lds(
                    (const __attribute__((address_space(1))) void*)(gsrc + soff),
                    (__attribute__((address_space(3))) void*)(
                        (__attribute__((address_space(3))) char*)in_t + lbase),
                    16, 0, 0);
            }
        }
    }

    f32x4 acc[4][2];
#pragma unroll
    for (int i=0;i<4;i++)
#pragma unroll
        for (int f=0;f<2;f++)
            acc[i][f] = (f32x4){0.f,0.f,0.f,0.f};

    bf16x8 areg[3][4], breg[2][2];
#define LDA_(K, SLOT) do { const unsigned short* wrow_ = wpk + ((K)*256 + co0)*32; \
        for (int i_=0;i_<4;i_++) areg[SLOT][i_] = *reinterpret_cast<const bf16x8*>(wrow_ + (i_*16 + l15)*32 + lhi*8); } while(0)
#define LDB_(K, SLOT) do { const int cic_ = (K)/9, tap_ = (K) - 9*((K)/9); \
        const int ky_ = tap_/3, kx_ = tap_ - 3*(tap_/3); \
        for (int f_=0;f_<2;f_++){ int pl_ = (wv + ky_)*34 + (f_*16 + l15 + kx_); \
            unsigned by_ = (unsigned)(pl_*256 + cic_*64 + lhi*16) ^ (((unsigned)pl_ & 7u) << 4); \
            breg[SLOT][f_] = *reinterpret_cast<const bf16x8*>(reinterpret_cast<const char*>(in_t) + by_); } } while(0)

    // A-loads are global: issue 2 deep BEFORE the barrier (DMA drains at barrier too)
    LDA_(0, 0); LDA_(1, 1);
    __syncthreads();
    LDB_(0, 0);
#pragma unroll
    for (int k=0; k<36; ++k){
        const int ks = k % 3, bs = k & 1;
        if (k+2 < 36) { const int kn = (k+2) % 3; LDA_(k+2, kn); }
        if (k+1 < 36) { const int bn = (k+1) & 1; LDB_(k+1, bn); }
#pragma unroll
        for (int i=0;i<4;i++){
            acc[i][0] = __builtin_amdgcn_mfma_f32_16x16x32_bf16(areg[ks][i], breg[bs][0], acc[i][0], 0,0,0);
            acc[i][1] = __builtin_amdgcn_mfma_f32_16x16x32_bf16(areg[ks][i], breg[bs][1], acc[i][1], 0,0,0);
        }
    }
#undef LDA_
#undef LDB_

    const int orow = r0 + wv;
    float s_ir[4][4], q_ir[4][4];
#pragma unroll
    for (int i=0;i<4;i++){
        int cobase = co0 + i*16 + lhi*4;
#pragma unroll
        for (int r=0;r<4;r++){
            float bs = bias[cobase+r];
            float e0 = acc[i][0][r] + bs;
            float e1 = acc[i][1][r] + bs;
            out[(size_t)(b*256 + cobase + r)*1024 + orow*32 + l15]      = f2bf(e0);
            out[(size_t)(b*256 + cobase + r)*1024 + orow*32 + 16 + l15] = f2bf(e1);
            s_ir[i][r] = e0 + e1;
            q_ir[i][r] = e0*e0 + e1*e1;
        }
    }
#pragma unroll
    for (int i=0;i<4;i++)
#pragma unroll
        for (int r=0;r<4;r++){
            float s = s_ir[i][r], q = q_ir[i][r];
            s += __shfl_xor(s,1); q += __shfl_xor(q,1);
            s += __shfl_xor(s,2); q += __shfl_xor(q,2);
            s += __shfl_xor(s,4); q += __shfl_xor(q,4);
            s += __shfl_xor(s,8); q += __shfl_xor(q,8);
            s_ir[i][r] = s; q_ir[i][r] = q;
        }
    if (l15 == 0){
#pragma unroll
        for (int i=0;i<4;i++)
#pragma unroll
            for (int r=0;r<4;r++){
                red_s[wv][i*16 + lhi*4 + r] = s_ir[i][r];
                red_q[wv][i*16 + lhi*4 + r] = q_ir[i][r];
            }
    }
    __syncthreads();
    if (t < 64){
        float S = red_s[0][t]+red_s[1][t]+red_s[2][t]+red_s[3][t];
        float Q = red_q[0][t]+red_q[1][t]+red_q[2][t]+red_q[3][t];
        float* sp = stats + ((size_t)(b*256 + co0 + t)*8 + blockIdx.x)*2;
        sp[0] = S; sp[1] = Q;
    }
}

// ---------- GN gate1, 32-pixel tiles; writes c-gate into PADDED buf2-hi ----------
__global__ __launch_bounds__(256)
void gn_gate1_kernel(const unsigned short* __restrict__ cc, const float* __restrict__ stats,
                     const float* __restrict__ gnw, const float* __restrict__ gnb,
                     const float* __restrict__ c_in,
                     unsigned short* __restrict__ buf2, unsigned short* __restrict__ sig_pm)
{
    const int b  = blockIdx.y;
    const int p0 = blockIdx.x * 32;
    const int t  = threadIdx.x;
    __shared__ float sc[256][2];
    __shared__ __align__(16) unsigned short cct[10240];   // [256ch][40] (80B rows)

    {
        const float* sp = stats + (size_t)(b*256 + t)*16;
        float S=0.f, Q=0.f;
#pragma unroll
        for (int k=0;k<8;k++){ S += sp[2*k]; Q += sp[2*k+1]; }
        float mu  = S*(1.0f/1024.0f);
        float var = Q*(1.0f/1024.0f) - mu*mu;
        float rs  = rsqrtf(var + 1e-5f);
        float gw  = gnw[t];
        sc[t][0] = rs*gw;
        sc[t][1] = gnb[t] - mu*rs*gw;
    }
    for (int it=t; it<1024; it+=256){
        int row = it>>2, oct = it&3;
        ushort8 v = *reinterpret_cast<const ushort8*>(
            cc + (size_t)(b*256+row)*1024 + p0 + oct*8);
        *reinterpret_cast<ushort8*>(cct + row*40 + oct*8) = v;
    }
    __syncthreads();

    const int p = t & 31, cg = t >> 5;
    float cn[8], so[8];
#pragma unroll
    for (int j=0;j<8;j++){
        int ch = cg*8 + j;
        float xg[4];
#pragma unroll
        for (int g=0; g<4; g++){
            int row = g*64 + ch;
            float v = bf2f(cct[row*40 + p]);
            xg[g] = v*sc[row][0] + sc[row][1];
        }
        float cv = c_in[(size_t)(b*64+ch)*1024 + p0 + p];
        cn[j] = sigmoidf_(xg[1])*cv + sigmoidf_(xg[0])*tanhf_(xg[3]);
        so[j] = sigmoidf_(xg[2]);
    }
    ushort8 v0, s0;
#pragma unroll
    for (int j=0;j<8;j++){ v0[j]=f2bf(cn[j]); s0[j]=f2bf(so[j]); }
    int pg = p0 + p;
    size_t pidx = (size_t)(b*1156 + ((pg>>5)+1)*34 + (pg&31) + 1);
    *reinterpret_cast<ushort8*>(buf2 + pidx*128 + 64 + cg*8) = v0;
    *reinterpret_cast<ushort8*>(sig_pm + (size_t)(b*1024 + pg)*64 + cg*8) = s0;
}

// ---------- GN gate2 + projections fused, 32-pixel tiles ----------
__global__ __launch_bounds__(256)
void gn2_proj_kernel(const unsigned short* __restrict__ cc, const float* __restrict__ stats,
                     const float* __restrict__ gnw, const float* __restrict__ gnb,
                     const float* __restrict__ lc_in, const unsigned short* __restrict__ sig_pm,
                     const float* __restrict__ m_in,
                     const unsigned short* __restrict__ wph, const unsigned short* __restrict__ wpm,
                     const float* __restrict__ bq, const float* __restrict__ bk,
                     const float* __restrict__ bv, const float* __restrict__ bk2,
                     const float* __restrict__ bv2,
                     float* __restrict__ out_lc, float* __restrict__ out_c,
                     unsigned short* __restrict__ hT,
                     unsigned short* __restrict__ Qb, unsigned short* __restrict__ Khb,
                     unsigned short* __restrict__ Kmb,
                     unsigned short* __restrict__ Vhb, unsigned short* __restrict__ Vmb)
{
    const int b  = blockIdx.y;
    const int p0 = blockIdx.x * 32;
    const int t  = threadIdx.x;
    const int l  = t & 63;
    const int w  = t >> 6;
    const int l15 = l & 15, lhi = l >> 4;

    __shared__ float sc[256][2];
    // phase1: [256ch][40] gate tile. phase2 reuse (bytes):
    //   hp [0,4096) ; mp [4096,8192) ; qk [8192,12288) ; km [12288,16384)
    __shared__ __align__(16) unsigned short cct[10240];

    {
        const float* sp = stats + (size_t)(b*256 + t)*16;
        float S=0.f, Q=0.f;
#pragma unroll
        for (int k=0;k<8;k++){ S += sp[2*k]; Q += sp[2*k+1]; }
        float mu  = S*(1.0f/1024.0f);
        float var = Q*(1.0f/1024.0f) - mu*mu;
        float rs  = rsqrtf(var + 1e-5f);
        float gw  = gnw[t];
        sc[t][0] = rs*gw;
        sc[t][1] = gnb[t] - mu*rs*gw;
    }
    for (int it=t; it<1024; it+=256){
        int row = it>>2, oct = it&3;
        ushort8 v = *reinterpret_cast<const ushort8*>(
            cc + (size_t)(b*256+row)*1024 + p0 + oct*8);
        *reinterpret_cast<ushort8*>(cct + row*40 + oct*8) = v;
    }
    __syncthreads();

    const int p = t & 31, cg = t >> 5;
    const size_t prow = (size_t)(b*1024 + p0 + p);
    float hm[8], mr[8];
    {
        ushort8 sv = *reinterpret_cast<const ushort8*>(sig_pm + prow*64 + cg*8);
#pragma unroll
        for (int j=0;j<8;j++){
            int ch = cg*8 + j;
            float xg[4];
#pragma unroll
            for (int g=0; g<4; g++){
                int row = g*64 + ch;
                float v = bf2f(cct[row*40 + p]);
                xg[g] = v*sc[row][0] + sc[row][1];
            }
            float lv  = lc_in[(size_t)(b*64+ch)*1024 + p0 + p];
            float lcn = sigmoidf_(xg[1])*lv + sigmoidf_(xg[0])*tanhf_(xg[3]);
            float cnx = sigmoidf_(xg[2])*tanhf_(lcn);
            out_lc[(size_t)(b*64+ch)*1024 + p0 + p] = lcn;
            out_c [(size_t)(b*64+ch)*1024 + p0 + p] = cnx;
            hm[j] = bf2f(sv[j])*tanhf_(cnx);
            mr[j] = m_in[(size_t)(b*64+ch)*1024 + p0 + p];
        }
    }
    __syncthreads();   // all cct gate reads done

    {
        ushort8 h0, m0;
#pragma unroll
        for (int j=0;j<8;j++){ h0[j]=f2bf(hm[j]); m0[j]=f2bf(mr[j]); }
        unsigned hb = (unsigned)(p*128) + (((unsigned)(cg*16)) ^ ((unsigned)(p&7)<<4));
        *reinterpret_cast<ushort8*>(reinterpret_cast<char*>(cct) + hb) = h0;
        *reinterpret_cast<ushort8*>(reinterpret_cast<char*>(cct) + 4096 + hb) = m0;
        *reinterpret_cast<ushort8*>(hT + prow*64 + cg*8) = h0;
    }
    __syncthreads();

    // proj: waves 0-1 -> h (Q,K,V), waves 2-3 -> m (Km,Vm). pixel frag = (w&1)*16.
    const int pass = w >> 1;
    const int pix  = (w&1)*16 + l15;
    const unsigned xsw = ((unsigned)(pix&7)) << 4;
    if (pass == 0){
        f32x4 dh[8];
#pragma unroll
        for (int i=0;i<8;i++) dh[i] = (f32x4){0.f,0.f,0.f,0.f};
#pragma unroll
        for (int ks=0; ks<2; ++ks){
            unsigned xb = (unsigned)(pix*128) + (((unsigned)(ks*64 + lhi*16)) ^ xsw);
            bf16x8 xh = *reinterpret_cast<const bf16x8*>(reinterpret_cast<const char*>(cct) + xb);
#pragma unroll
            for (int ocf=0; ocf<8; ocf++){
                bf16x8 af = *reinterpret_cast<const bf16x8*>(
                    wph + (size_t)(ocf*16 + l15)*64 + ks*32 + lhi*8);
                dh[ocf] = __builtin_amdgcn_mfma_f32_16x16x32_bf16(af, xh, dh[ocf], 0,0,0);
            }
        }
#pragma unroll
        for (int ocf=0; ocf<4; ocf++)
#pragma unroll
            for (int r=0;r<4;r++){
                int vc = ocf*16 + lhi*4 + r;
                Vhb[(size_t)(b*64+vc)*1024 + p0 + pix] = f2bf(dh[4+ocf][r] + bv[vc]);
            }
#pragma unroll
        for (int ocf=0; ocf<2; ocf++)
#pragma unroll
            for (int r=0;r<4;r++){
                int qc = ocf*16 + lhi*4 + r;
                unsigned byq = (unsigned)(pix*128) + (((unsigned)(qc*2))      ^ xsw);
                unsigned byk = (unsigned)(pix*128) + (((unsigned)(64 + qc*2)) ^ xsw);
                *reinterpret_cast<unsigned short*>(reinterpret_cast<char*>(cct) + 8192 + byq)
                    = f2bf(dh[ocf][r]   + bq[qc]);
                *reinterpret_cast<unsigned short*>(reinterpret_cast<char*>(cct) + 8192 + byk)
                    = f2bf(dh[2+ocf][r] + bk[qc]);
            }
    } else {
        f32x4 dm[6];
#pragma unroll
        for (int i=0;i<6;i++) dm[i] = (f32x4){0.f,0.f,0.f,0.f};
#pragma unroll
        for (int ks=0; ks<2; ++ks){
            unsigned xb = (unsigned)(pix*128) + (((unsigned)(ks*64 + lhi*16)) ^ xsw);
            bf16x8 xm = *reinterpret_cast<const bf16x8*>(
                reinterpret_cast<const char*>(cct) + 4096 + xb);
#pragma unroll
            for (int ocf=0; ocf<6; ocf++){
                bf16x8 am = *reinterpret_cast<const bf16x8*>(
                    wpm + (size_t)(ocf*16 + l15)*64 + ks*32 + lhi*8);
                dm[ocf] = __builtin_amdgcn_mfma_f32_16x16x32_bf16(am, xm, dm[ocf], 0,0,0);
            }
        }
#pragma unroll
        for (int ocf=0; ocf<4; ocf++)
#pragma unroll
            for (int r=0;r<4;r++){
                int vc = ocf*16 + lhi*4 + r;
                Vmb[(size_t)(b*64+vc)*1024 + p0 + pix] = f2bf(dm[2+ocf][r] + bv2[vc]);
            }
#pragma unroll
        for (int ocf=0; ocf<2; ocf++)
#pragma unroll
            for (int r=0;r<4;r++){
                int qc = ocf*16 + lhi*4 + r;
                unsigned byq = (unsigned)(pix*128) + (((unsigned)(qc*2)) ^ xsw);
                *reinterpret_cast<unsigned short*>(reinterpret_cast<char*>(cct) + 12288 + byq)
                    = f2bf(dm[ocf][r] + bk2[qc]);
            }
    }
    __syncthreads();

    {   // flush Q/K: 32 rows x 8 octs
        int pr = t>>3, oct = t&7;
        unsigned byte = (unsigned)(pr*128) + (((unsigned)(oct*16)) ^ ((unsigned)(pr&7)<<4));
        ushort8 v = *reinterpret_cast<const ushort8*>(
            reinterpret_cast<const char*>(cct) + 8192 + byte);
        if (oct < 4) *reinterpret_cast<ushort8*>(Qb  + (size_t)(b*1024+p0+pr)*32 + oct*8) = v;
        else         *reinterpret_cast<ushort8*>(Khb + (size_t)(b*1024+p0+pr)*32 + (oct-4)*8) = v;
    }
    if (t < 128){  // flush Km: 32 rows x 4 octs
        int pr = t>>2, oct = t&3;
        unsigned byte = (unsigned)(pr*128) + (((unsigned)(oct*16)) ^ ((unsigned)(pr&7)<<4));
        ushort8 v = *reinterpret_cast<const ushort8*>(
            reinterpret_cast<const char*>(cct) + 12288 + byte);
        *reinterpret_cast<ushort8*>(Kmb + (size_t)(b*1024+p0+pr)*32 + oct*8) = v;
    }
}

// ---------- fused attention + final mix ----------
__global__ __launch_bounds__(256)
void attn_final_kernel(const unsigned short* __restrict__ Qb,
                       const unsigned short* __restrict__ Kh,
                       const unsigned short* __restrict__ Km,
                       const unsigned short* __restrict__ Vh,
                       const unsigned short* __restrict__ Vm,
                       const unsigned short* __restrict__ hT,
                       const unsigned short* __restrict__ wzb,
                       const unsigned short* __restrict__ wmb,
                       const float* __restrict__ bz, const float* __restrict__ bm,
                       const float* __restrict__ m_in,
                       float* __restrict__ out_h, float* __restrict__ out_m)
{
    const int bid  = blockIdx.x;
    const int xcd  = bid & 7;
    const int slot = bid >> 3;
    const int b    = xcd*2 + (slot>>5);
    const int p0   = (slot & 31) * 32;
    const int t   = threadIdx.x;
    const int l   = t & 63;
    const int w   = t >> 6;
    const int l15 = l & 15, g = l >> 4;
    const int pass = w >> 1;
    const int ph   = w & 1;

    __shared__ __align__(16) unsigned short Kt[2][2][2560];
    __shared__ __align__(16) unsigned short Vt[2][2][4096];
    __shared__ __align__(16) unsigned short Pt[2][2048];
    __shared__ __align__(16) unsigned short Bs[32*192];

    const bf16x8 qa = *reinterpret_cast<const bf16x8*>(
        Qb + (size_t)(b*1024 + p0 + ph*16 + l15)*32 + g*8);

    float m_run = -1e30f, l_run = 0.0f;
    f32x4 acc[4];
#pragma unroll
    for (int cf=0;cf<4;cf++) acc[cf] = (f32x4){0.f,0.f,0.f,0.f};

    const int krow = t>>2, koct = t&3;
    const int vrow = t>>3, voct = t&7;
    const unsigned kwb  = (unsigned)(krow*80 + koct*16);
    const unsigned vwb0 = (unsigned)(vrow*128)      + (((unsigned)voct*16) ^ ((unsigned)(vrow&7)<<4));
    const unsigned vwb1 = (unsigned)((vrow+32)*128) + (((unsigned)voct*16) ^ ((unsigned)((vrow+32)&7)<<4));

    ushort8 kr0, kr1, vv0, vv1, vv2, vv3;
#define LDSTAGE(Q0N) do { \
        kr0 = *reinterpret_cast<const ushort8*>(Kh + (size_t)(b*1024 + (Q0N) + krow)*32 + koct*8); \
        kr1 = *reinterpret_cast<const ushort8*>(Km + (size_t)(b*1024 + (Q0N) + krow)*32 + koct*8); \
        vv0 = *reinterpret_cast<const ushort8*>(Vh + (size_t)(b*64 + vrow)*1024 + (Q0N) + voct*8); \
        vv1 = *reinterpret_cast<const ushort8*>(Vh + (size_t)(b*64 + vrow+32)*1024 + (Q0N) + voct*8); \
        vv2 = *reinterpret_cast<const ushort8*>(Vm + (size_t)(b*64 + vrow)*1024 + (Q0N) + voct*8); \
        vv3 = *reinterpret_cast<const ushort8*>(Vm + (size_t)(b*64 + vrow+32)*1024 + (Q0N) + voct*8); \
    } while(0)
#define WRSTAGE(BUF) do { \
        *reinterpret_cast<ushort8*>(reinterpret_cast<char*>(Kt[0][BUF]) + kwb)  = kr0; \
        *reinterpret_cast<ushort8*>(reinterpret_cast<char*>(Kt[1][BUF]) + kwb)  = kr1; \
        *reinterpret_cast<ushort8*>(reinterpret_cast<char*>(Vt[0][BUF]) + vwb0) = vv0; \
        *reinterpret_cast<ushort8*>(reinterpret_cast<char*>(Vt[0][BUF]) + vwb1) = vv1; \
        *reinterpret_cast<ushort8*>(reinterpret_cast<char*>(Vt[1][BUF]) + vwb0) = vv2; \
        *reinterpret_cast<ushort8*>(reinterpret_cast<char*>(Vt[1][BUF]) + vwb1) = vv3; \
    } while(0)

    LDSTAGE(0);
    WRSTAGE(0);
    __syncthreads();

    const unsigned prow = (unsigned)(ph*16 + l15);
    const unsigned psw  = (prow & 7u) << 4;
    char* Pbase = reinterpret_cast<char*>(Pt[pass]);

    for (int it=0; it<16; ++it){
        const int cur = it & 1;
        if (it < 15) LDSTAGE((it+1)*64);

        f32x4 s2[4];
#pragma unroll
        for (int qt=0; qt<4; qt++){
            const bf16x8 kb = *reinterpret_cast<const bf16x8*>(
                reinterpret_cast<const char*>(Kt[pass][cur]) + (qt*16 + l15)*80 + g*16);
            s2[qt] = __builtin_amdgcn_mfma_f32_16x16x32_bf16(kb, qa, (f32x4){0.f,0.f,0.f,0.f}, 0,0,0);
        }

        float pm = s2[0][0];
#pragma unroll
        for (int qt=0; qt<4; qt++)
#pragma unroll
            for (int r=0;r<4;r++) pm = fmaxf(pm, s2[qt][r]);
        pm = fmaxf(pm, __shfl_xor(pm, 16));
        pm = fmaxf(pm, __shfl_xor(pm, 32));

        if (!__all(pm <= m_run + 8.0f)){
            float mn = fmaxf(m_run, pm);
            float f  = __expf(m_run - mn);
            m_run = mn;
            l_run *= f;
#pragma unroll
            for (int r=0;r<4;r++){
                float fr = __shfl(f, (l & 48) | ((l>>4)*4 + r), 64);
#pragma unroll
                for (int cf=0;cf<4;cf++) acc[cf][r] *= fr;
            }
        }

        float e[4][4];
        float lsum = 0.f;
#pragma unroll
        for (int qt=0; qt<4; qt++)
#pragma unroll
            for (int r=0;r<4;r++){
                float ev = __expf(s2[qt][r] - m_run);
                e[qt][r] = ev;
                lsum += ev;
            }
        lsum += __shfl_xor(lsum, 16);
        lsum += __shfl_xor(lsum, 32);
        l_run += lsum;

#pragma unroll
        for (int qt=0; qt<4; qt++){
            uint2v pk;
            pk.x = cvt_pk_bf16(e[qt][0], e[qt][1]);
            pk.y = cvt_pk_bf16(e[qt][2], e[qt][3]);
            unsigned byte = prow*128 + (((unsigned)(qt*32 + g*8)) ^ psw);
            *reinterpret_cast<uint2v*>(Pbase + byte) = pk;
        }

#pragma unroll
        for (int ks=0;ks<2;ks++){
            unsigned abyte = prow*128 + (((unsigned)(ks*64 + g*16)) ^ psw);
            const bf16x8 pa = *reinterpret_cast<const bf16x8*>(Pbase + abyte);
#pragma unroll
            for (int cf=0;cf<4;cf++){
                unsigned vrw = (unsigned)(cf*16 + l15);
                unsigned vbyte = vrw*128 + (((unsigned)(ks*64 + g*16)) ^ ((vrw&7u)<<4));
                const bf16x8 vb = *reinterpret_cast<const bf16x8*>(
                    reinterpret_cast<const char*>(Vt[pass][cur]) + vbyte);
                acc[cf] = __builtin_amdgcn_mfma_f32_16x16x32_bf16(pa, vb, acc[cf], 0,0,0);
            }
        }

        if (it < 15) WRSTAGE(cur^1);
        __syncthreads();
    }
#undef LDSTAGE
#undef WRSTAGE

    {
        float rl = 1.0f / l_run;
        float rr[4];
#pragma unroll
        for (int r=0;r<4;r++) rr[r] = __shfl(rl, (l & 48) | ((l>>4)*4 + r), 64);
#pragma unroll
        for (int cf=0;cf<4;cf++)
#pragma unroll
            for (int r=0;r<4;r++){
                unsigned pix = (unsigned)(ph*16 + g*4 + r);
                unsigned cch = (unsigned)(pass*64 + cf*16 + l15);
                unsigned byte = pix*384 + ((cch*2) ^ ((pix&7u)<<4));
                *reinterpret_cast<unsigned short*>(reinterpret_cast<char*>(Bs) + byte)
                    = f2bf(acc[cf][r]*rr[r]);
            }
    }
    {
        int row = t>>3, oct = t&7;
        ushort8 v = *reinterpret_cast<const ushort8*>(
            hT + (size_t)(b*1024 + p0 + row)*64 + oct*8);
        unsigned byte = (unsigned)(row*384) + 256u + (((unsigned)oct*16) ^ ((unsigned)(row&7)<<4));
        *reinterpret_cast<ushort8*>(reinterpret_cast<char*>(Bs) + byte) = v;
    }
    __syncthreads();

    f32x4 acc1[2][2];
#pragma unroll
    for (int i=0;i<2;i++)
#pragma unroll
        for (int cf=0;cf<2;cf++) acc1[i][cf] = (f32x4){0.f,0.f,0.f,0.f};
#pragma unroll
    for (int ks=0; ks<4; ++ks){
        bf16x8 af[2];
#pragma unroll
        for (int i=0;i<2;i++)
            af[i] = *reinterpret_cast<const bf16x8*>(
                wzb + (size_t)(w*32 + i*16 + l15)*128 + ks*32 + g*8);
#pragma unroll
        for (int cf=0;cf<2;cf++){
            unsigned p = (unsigned)(cf*16 + l15);
            unsigned byte = p*384 + (((unsigned)(ks*64 + g*16)) ^ ((p&7u)<<4));
            const bf16x8 bfr = *reinterpret_cast<const bf16x8*>(
                reinterpret_cast<const char*>(Bs) + byte);
            acc1[0][cf] = __builtin_amdgcn_mfma_f32_16x16x32_bf16(af[0], bfr, acc1[0][cf], 0,0,0);
            acc1[1][cf] = __builtin_amdgcn_mfma_f32_16x16x32_bf16(af[1], bfr, acc1[1][cf], 0,0,0);
        }
    }
    __syncthreads();
#pragma unroll
    for (int i=0;i<2;i++){
        int co = w*32 + i*16 + g*4;
#pragma unroll
        for (int cf=0;cf<2;cf++){
            unsigned p = (unsigned)(cf*16 + l15);
#pragma unroll
            for (int r=0;r<4;r++){
                float val = acc1[i][cf][r] + bz[co+r];
                unsigned byte = p*384 + (((unsigned)((co+r)*2)) ^ ((p&7u)<<4));
                *reinterpret_cast<unsigned short*>(reinterpret_cast<char*>(Bs) + byte) = f2bf(val);
            }
        }
    }
    __syncthreads();

    f32x4 acc2[3][2];
#pragma unroll
    for (int j=0;j<3;j++)
#pragma unroll
        for (int cf=0;cf<2;cf++) acc2[j][cf] = (f32x4){0.f,0.f,0.f,0.f};
#pragma unroll
    for (int ks=0; ks<6; ++ks){
        bf16x8 am[3];
#pragma unroll
        for (int j=0;j<3;j++)
            am[j] = *reinterpret_cast<const bf16x8*>(
                wmb + (size_t)(j*64 + w*16 + l15)*192 + ks*32 + g*8);
#pragma unroll
        for (int cf=0;cf<2;cf++){
            unsigned p = (unsigned)(cf*16 + l15);
            unsigned byte = p*384 + (((unsigned)(ks*64 + g*16)) ^ ((p&7u)<<4));
            const bf16x8 bfr = *reinterpret_cast<const bf16x8*>(
                reinterpret_cast<const char*>(Bs) + byte);
#pragma unroll
            for (int j=0;j<3;j++)
                acc2[j][cf] = __builtin_amdgcn_mfma_f32_16x16x32_bf16(am[j], bfr, acc2[j][cf], 0,0,0);
        }
    }

    const int ch0 = w*16 + g*4;
#pragma unroll
    for (int cf=0;cf<2;cf++){
        int pix = p0 + cf*16 + l15;
#pragma unroll
        for (int r=0;r<4;r++){
            int ch = ch0 + r;
            float mo = acc2[0][cf][r] + bm[ch];
            float mg = acc2[1][cf][r] + bm[64+ch];
            float mi = sigmoidf_(acc2[2][cf][r] + bm[128+ch]);
            float mv = m_in[(size_t)(b*64+ch)*1024 + pix];
            float mn = (1.0f - mi)*mv + mi*tanhf_(mg);
            out_m[(size_t)(b*64+ch)*1024 + pix] = mn;
            out_h[(size_t)(b*64+ch)*1024 + pix] = sigmoidf_(mo)*mn;
        }
    }
}

extern "C" void kernel_launch(void* const* d_in, const int* in_sizes, int n_in,
                              void* d_out, int out_size, void* d_ws, size_t ws_size,
                              hipStream_t stream)
{
    const float* x      = (const float*)d_in[0];
    const float* h      = (const float*)d_in[1];
    const float* c      = (const float*)d_in[2];
    const float* m      = (const float*)d_in[3];
    const float* lc     = (const float*)d_in[4];
    const float* conv_w = (const float*)d_in[5];
    const float* conv_b = (const float*)d_in[6];
    const float* gn1_w  = (const float*)d_in[7];
    const float* gn1_b  = (const float*)d_in[8];
    const float* convL_w= (const float*)d_in[9];
    const float* convL_b= (const float*)d_in[10];
    const float* gn2_w  = (const float*)d_in[11];
    const float* gn2_b  = (const float*)d_in[12];
    const float* wq  = (const float*)d_in[13];
    const float* bq  = (const float*)d_in[14];
    const float* wk  = (const float*)d_in[15];
    const float* bk  = (const float*)d_in[16];
    const float* wk2 = (const float*)d_in[17];
    const float* bk2 = (const float*)d_in[18];
    const float* wv  = (const float*)d_in[19];
    const float* bv  = (const float*)d_in[20];
    const float* wv2 = (const float*)d_in[21];
    const float* bv2 = (const float*)d_in[22];
    const float* wz  = (const float*)d_in[23];
    const float* bz  = (const float*)d_in[24];
    const float* wmw = (const float*)d_in[25];
    const float* bm  = (const float*)d_in[26];

    float* out = (float*)d_out;
    float* F = (float*)d_ws;
    unsigned short* cc_bf  = (unsigned short*)F;              // [16][256][1024] bf16
    unsigned short* buf1   = (unsigned short*)(F + 2097152);  // padded [16][1156][128]
    unsigned short* buf2   = (unsigned short*)(F + 3280896);  // padded
    unsigned short* hT     = (unsigned short*)(F + 4464640);  // [16][1024][64]
    unsigned short* Qb     = (unsigned short*)(F + 4988928);
    unsigned short* Khb    = (unsigned short*)(F + 5251072);
    unsigned short* Kmb    = (unsigned short*)(F + 5513216);
    unsigned short* Vhb    = (unsigned short*)(F + 5775360);
    unsigned short* Vmb    = (unsigned short*)(F + 6299648);
    unsigned short* sig_pm = (unsigned short*)(F + 6823936);  // [16][1024][64]
    unsigned short* wpk1   = (unsigned short*)(F + 7348224);
    unsigned short* wpk2   = (unsigned short*)(F + 7495680);
    unsigned short* wzb    = (unsigned short*)(F + 7643136);
    unsigned short* wmb    = (unsigned short*)(F + 7651328);
    unsigned short* wph    = (unsigned short*)(F + 7669760);
    unsigned short* wpm    = (unsigned short*)(F + 7673856);
    float*          stats  = F + 7676928;                     // [16][256][8][2] f32

    dim3 blk256(256);
    prep_kernel<<<dim3(1440), blk256, 0, stream>>>(conv_w, convL_w, wz, wmw,
                                                   wq, wk, wv, wk2, wv2, x, h,
                                                   wpk1, wpk2, wzb, wmb, wph, wpm,
                                                   buf1, buf2);
    dim3 cgrid(8, 4, 16);
    conv_mfma_kernel<<<cgrid, blk256, 0, stream>>>(buf1, wpk1, conv_b, cc_bf, stats);
    gn_gate1_kernel<<<dim3(32,16), blk256, 0, stream>>>(cc_bf, stats, gn1_w, gn1_b, c,
                                                        buf2, sig_pm);
    conv_mfma_kernel<<<cgrid, blk256, 0, stream>>>(buf2, wpk2, convL_b, cc_bf, stats);
    gn2_proj_kernel<<<dim3(32,16), blk256, 0, stream>>>(cc_bf, stats, gn2_w, gn2_b,
                                                        lc, sig_pm, m, wph, wpm,
                                                        bq, bk, bv, bk2, bv2,
                                                        out + 3*1048576 /*lc_next*/,
                                                        out + 1*1048576 /*c_next*/,
                                                        hT, Qb, Khb, Kmb, Vhb, Vmb);
    attn_final_kernel<<<dim3(512), blk256, 0, stream>>>(Qb, Khb, Kmb, Vhb, Vmb, hT,
                                                        wzb, wmb, bz, bm, m,
                                                        out /*h_next*/, out + 2*1048576 /*m_next*/);
    (void)in_sizes; (void)n_in; (void)out_size; (void)ws_size;
}

// Round 11
// 109.496 us; speedup vs baseline: 1.3789x; 1.0894x over previous
//
#include <hip/hip_runtime.h>

#define DEV __device__ __forceinline__

typedef __attribute__((ext_vector_type(8))) __bf16 bf16x8;
typedef __attribute__((ext_vector_type(4))) float f32x4;
typedef __attribute__((ext_vector_type(8))) unsigned short ushort8;
typedef __attribute__((ext_vector_type(2))) unsigned short ushort2v;
typedef __attribute__((ext_vector_type(2))) unsigned int uint2v;

DEV float sigmoidf_(float x){ return 1.0f/(1.0f + __expf(-x)); }
DEV float tanhf_(float x){
    x = fminf(15.0f, fmaxf(-15.0f, x));
    float e = __expf(2.0f*x);
    return (e - 1.0f)/(e + 1.0f);
}
DEV unsigned short f2bf(float f){
    unsigned u = __builtin_bit_cast(unsigned, f);
    unsigned r = (u + 0x7FFFu + ((u>>16)&1u)) >> 16;
    return (unsigned short)r;
}
DEV float bf2f(unsigned short u){
    return __builtin_bit_cast(float, ((unsigned)u)<<16);
}
DEV unsigned cvt_pk_bf16(float lo, float hi){
    unsigned r;
    asm("v_cvt_pk_bf16_f32 %0, %1, %2" : "=v"(r) : "v"(lo), "v"(hi));
    return r;
}

// ---------- merged prep: weights -> bf16 packs (coalesced stores) ; pack x,h -> PADDED buf1/buf2 ----------
// padded layout: [b][34*34=1156 px][128ci] bf16, px = (row+1)*34 + (col+1)
__global__ __launch_bounds__(256)
void prep_kernel(const float* __restrict__ conv_w, const float* __restrict__ convL_w,
                 const float* __restrict__ wz, const float* __restrict__ wm,
                 const float* __restrict__ wq, const float* __restrict__ wk,
                 const float* __restrict__ wv, const float* __restrict__ wk2,
                 const float* __restrict__ wv2,
                 const float* __restrict__ x, const float* __restrict__ h,
                 unsigned short* __restrict__ wpk1, unsigned short* __restrict__ wpk2,
                 unsigned short* __restrict__ wzb, unsigned short* __restrict__ wmb,
                 unsigned short* __restrict__ wph, unsigned short* __restrict__ wpm,
                 unsigned short* __restrict__ buf1, unsigned short* __restrict__ buf2)
{
    __shared__ float tile[128][65];
    if (blockIdx.x < 1152) {
        int oidx = blockIdx.x*256 + threadIdx.x;   // output-major: fully coalesced stores
        {
            int ci5 = oidx & 31;
            int co  = (oidx >> 5) & 255;
            int kch = oidx >> 13;                  // 0..35
            int cic = kch / 9, tap = kch - 9*cic;
            int src = co*1152 + (cic*32 + ci5)*9 + tap;
            wpk1[oidx] = f2bf(conv_w[src]);
            wpk2[oidx] = f2bf(convL_w[src]);
        }
        if (oidx < 128*128) wzb[oidx] = f2bf(wz[oidx]);
        if (oidx < 192*192) wmb[oidx] = f2bf(wm[oidx]);
        if (oidx < 32*64){
            wph[oidx]        = f2bf(wq[oidx]);
            wph[2048 + oidx] = f2bf(wk[oidx]);
            wpm[oidx]        = f2bf(wk2[oidx]);
        }
        if (oidx < 64*64){
            wph[4096 + oidx] = f2bf(wv[oidx]);
            wpm[2048 + oidx] = f2bf(wv2[oidx]);
        }
    } else if (blockIdx.x < 1184) {
        int bx2 = blockIdx.x - 1152;
        int b = bx2 >> 1;
        unsigned short* buf = (bx2 & 1) ? buf2 : buf1;
        for (int i = threadIdx.x; i < 8448; i += 256){
            int px = i >> 6, u = i & 63;
            int rr, cc2;
            if (px < 34)      { rr = 0;         cc2 = px; }
            else if (px < 68) { rr = 33;        cc2 = px-34; }
            else if (px < 100){ rr = px-68+1;   cc2 = 0; }
            else              { rr = px-100+1;  cc2 = 33; }
            reinterpret_cast<unsigned*>(buf + (size_t)(b*1156 + rr*34 + cc2)*128)[u] = 0u;
        }
    } else {
        int bx = blockIdx.x - 1184;
        int b  = bx >> 4;
        int p0 = (bx & 15) * 64;
        int t  = threadIdx.x;
        for (int k=t;k<8192;k+=256){
            int ci = k>>6, pp = k&63;
            const float* s = (ci<64) ? x + (size_t)(b*64+ci)*1024
                                     : h + (size_t)(b*64+ci-64)*1024;
            tile[ci][pp] = s[p0+pp];
        }
        __syncthreads();
        for (int k=t;k<4096;k+=256){
            int pp = k>>6, c2 = k&63;
            int p  = p0 + pp;
            size_t pidx = (size_t)(b*1156 + ((p>>5)+1)*34 + (p&31) + 1);
            ushort2v v;
            v.x = f2bf(tile[c2*2][pp]);
            v.y = f2bf(tile[c2*2+1][pp]);
            *reinterpret_cast<ushort2v*>(buf1 + pidx*128 + c2*2) = v;
            if (c2 >= 32)
                *reinterpret_cast<ushort2v*>(buf2 + pidx*128 + (c2-32)*2) = v;
        }
    }
}

// ---------- implicit-GEMM 3x3 conv via MFMA: padded input, async DMA staging, A-ring-4 / B-ring-3 ----------
// inp: [16][1156 px][128ci] bf16 padded ; wpk: [36][256co][32] bf16 ; out: [16][256][1024] bf16
// statsS/statsQ: [16][8 part][256 ch] f32
__global__ __launch_bounds__(256, 2)
void conv_mfma_kernel(const unsigned short* __restrict__ inp,
                      const unsigned short* __restrict__ wpk,
                      const float* __restrict__ bias,
                      unsigned short* __restrict__ out,
                      float* __restrict__ statsS, float* __restrict__ statsQ)
{
    const int b   = blockIdx.z;
    const int co0 = blockIdx.y * 64;
    const int r0  = blockIdx.x * 4;
    const int t   = threadIdx.x;
    const int l   = t & 63;
    const int wv  = t >> 6;
    const int l15 = l & 15;
    const int lhi = l >> 4;

    __shared__ __align__(16) unsigned short in_t[26112];  // 204 pixlin x 128ci, XOR-swizzled

    // async global->LDS staging: 51 wave-slots of 1KB, pre-swizzled SOURCE, linear LDS dest
    {
        const char* gsrc = reinterpret_cast<const char*>(inp + (size_t)(b*1156 + r0*34)*128);
#pragma unroll
        for (int it = 0; it < 13; ++it){
            unsigned lbase = (unsigned)(it*4096 + wv*1024);
            if (lbase < 52224u){
                unsigned beta = lbase + (unsigned)l*16u;
                unsigned soff = (beta & ~255u) + ((beta & 0xF0u) ^ (((beta>>8)&7u)<<4));
                __builtin_amdgcn_global_load_lds(
                    (const __attribute__((address_space(1))) void*)(gsrc + soff),
                    (__attribute__((address_space(3))) void*)(
                        (__attribute__((address_space(3))) char*)in_t + lbase),
                    16, 0, 0);
            }
        }
    }

    f32x4 acc[4][2];
#pragma unroll
    for (int i=0;i<4;i++)
#pragma unroll
        for (int f=0;f<2;f++)
            acc[i][f] = (f32x4){0.f,0.f,0.f,0.f};

    bf16x8 areg[4][4], breg[3][2];
#define LDA_(K, SLOT) do { const unsigned short* wrow_ = wpk + ((K)*256 + co0)*32; \
        for (int i_=0;i_<4;i_++) areg[SLOT][i_] = *reinterpret_cast<const bf16x8*>(wrow_ + (i_*16 + l15)*32 + lhi*8); } while(0)
#define LDB_(K, SLOT) do { const int cic_ = (K)/9, tap_ = (K) - 9*((K)/9); \
        const int ky_ = tap_/3, kx_ = tap_ - 3*(tap_/3); \
        for (int f_=0;f_<2;f_++){ int pl_ = (wv + ky_)*34 + (f_*16 + l15 + kx_); \
            unsigned by_ = (unsigned)(pl_*256 + cic_*64 + lhi*16) ^ (((unsigned)pl_ & 7u) << 4); \
            breg[SLOT][f_] = *reinterpret_cast<const bf16x8*>(reinterpret_cast<const char*>(in_t) + by_); } } while(0)

    // A-loads are global: issue 3 deep BEFORE the barrier (they drain with the DMA)
    LDA_(0, 0); LDA_(1, 1); LDA_(2, 2);
    __syncthreads();
    LDB_(0, 0); LDB_(1, 1);
#pragma unroll
    for (int k=0; k<36; ++k){
        const int as = k & 3, bs = k % 3;
        if (k+3 < 36) LDA_(k+3, (k+3)&3);
        if (k+2 < 36) LDB_(k+2, (k+2)%3);
#pragma unroll
        for (int i=0;i<4;i++){
            acc[i][0] = __builtin_amdgcn_mfma_f32_16x16x32_bf16(areg[as][i], breg[bs][0], acc[i][0], 0,0,0);
            acc[i][1] = __builtin_amdgcn_mfma_f32_16x16x32_bf16(areg[as][i], breg[bs][1], acc[i][1], 0,0,0);
        }
    }
#undef LDA_
#undef LDB_

    __syncthreads();   // all in_t reads done; reuse LDS for stat reduction
    float* red = reinterpret_cast<float*>(in_t);   // [0,256): S by wave ; [256,512): Q

    const int orow = r0 + wv;
    float s_ir[4][4], q_ir[4][4];
#pragma unroll
    for (int i=0;i<4;i++){
        int cobase = co0 + i*16 + lhi*4;
#pragma unroll
        for (int r=0;r<4;r++){
            float bs = bias[cobase+r];
            float e0 = acc[i][0][r] + bs;
            float e1 = acc[i][1][r] + bs;
            out[(size_t)(b*256 + cobase + r)*1024 + orow*32 + l15]      = f2bf(e0);
            out[(size_t)(b*256 + cobase + r)*1024 + orow*32 + 16 + l15] = f2bf(e1);
            s_ir[i][r] = e0 + e1;
            q_ir[i][r] = e0*e0 + e1*e1;
        }
    }
#pragma unroll
    for (int i=0;i<4;i++)
#pragma unroll
        for (int r=0;r<4;r++){
            float s = s_ir[i][r], q = q_ir[i][r];
            s += __shfl_xor(s,1); q += __shfl_xor(q,1);
            s += __shfl_xor(s,2); q += __shfl_xor(q,2);
            s += __shfl_xor(s,4); q += __shfl_xor(q,4);
            s += __shfl_xor(s,8); q += __shfl_xor(q,8);
            s_ir[i][r] = s; q_ir[i][r] = q;
        }
    if (l15 == 0){
#pragma unroll
        for (int i=0;i<4;i++)
#pragma unroll
            for (int r=0;r<4;r++){
                red[wv*64 + i*16 + lhi*4 + r]       = s_ir[i][r];
                red[256 + wv*64 + i*16 + lhi*4 + r] = q_ir[i][r];
            }
    }
    __syncthreads();
    if (t < 64){
        float S = red[t]+red[64+t]+red[128+t]+red[192+t];
        float Q = red[256+t]+red[320+t]+red[384+t]+red[448+t];
        statsS[((size_t)b*8 + blockIdx.x)*256 + co0 + t] = S;
        statsQ[((size_t)b*8 + blockIdx.x)*256 + co0 + t] = Q;
    }
}

// ---------- GN gate1, 32-pixel tiles; coalesced stats; writes c-gate into PADDED buf2-hi ----------
__global__ __launch_bounds__(256)
void gn_gate1_kernel(const unsigned short* __restrict__ cc,
                     const float* __restrict__ statsS, const float* __restrict__ statsQ,
                     const float* __restrict__ gnw, const float* __restrict__ gnb,
                     const float* __restrict__ c_in,
                     unsigned short* __restrict__ buf2, unsigned short* __restrict__ sig_pm)
{
    const int b  = blockIdx.y;
    const int p0 = blockIdx.x * 32;
    const int t  = threadIdx.x;
    __shared__ float sc[256][2];
    __shared__ __align__(16) unsigned short cct[10240];   // [256ch][40] (80B rows)

    {
        float S=0.f, Q=0.f;
#pragma unroll
        for (int part=0; part<8; ++part){
            S += statsS[((size_t)b*8 + part)*256 + t];
            Q += statsQ[((size_t)b*8 + part)*256 + t];
        }
        float mu  = S*(1.0f/1024.0f);
        float var = Q*(1.0f/1024.0f) - mu*mu;
        float rs  = rsqrtf(var + 1e-5f);
        float gw  = gnw[t];
        sc[t][0] = rs*gw;
        sc[t][1] = gnb[t] - mu*rs*gw;
    }
    for (int it=t; it<1024; it+=256){
        int row = it>>2, oct = it&3;
        ushort8 v = *reinterpret_cast<const ushort8*>(
            cc + (size_t)(b*256+row)*1024 + p0 + oct*8);
        *reinterpret_cast<ushort8*>(cct + row*40 + oct*8) = v;
    }
    __syncthreads();

    const int p = t & 31, cg = t >> 5;
    float cn[8], so[8];
#pragma unroll
    for (int j=0;j<8;j++){
        int ch = cg*8 + j;
        float xg[4];
#pragma unroll
        for (int g=0; g<4; g++){
            int row = g*64 + ch;
            float v = bf2f(cct[row*40 + p]);
            xg[g] = v*sc[row][0] + sc[row][1];
        }
        float cv = c_in[(size_t)(b*64+ch)*1024 + p0 + p];
        cn[j] = sigmoidf_(xg[1])*cv + sigmoidf_(xg[0])*tanhf_(xg[3]);
        so[j] = sigmoidf_(xg[2]);
    }
    ushort8 v0, s0;
#pragma unroll
    for (int j=0;j<8;j++){ v0[j]=f2bf(cn[j]); s0[j]=f2bf(so[j]); }
    int pg = p0 + p;
    size_t pidx = (size_t)(b*1156 + ((pg>>5)+1)*34 + (pg&31) + 1);
    *reinterpret_cast<ushort8*>(buf2 + pidx*128 + 64 + cg*8) = v0;
    *reinterpret_cast<ushort8*>(sig_pm + (size_t)(b*1024 + pg)*64 + cg*8) = s0;
}

// ---------- GN gate2 + projections fused, 32-pixel tiles, coalesced stats ----------
__global__ __launch_bounds__(256)
void gn2_proj_kernel(const unsigned short* __restrict__ cc,
                     const float* __restrict__ statsS, const float* __restrict__ statsQ,
                     const float* __restrict__ gnw, const float* __restrict__ gnb,
                     const float* __restrict__ lc_in, const unsigned short* __restrict__ sig_pm,
                     const float* __restrict__ m_in,
                     const unsigned short* __restrict__ wph, const unsigned short* __restrict__ wpm,
                     const float* __restrict__ bq, const float* __restrict__ bk,
                     const float* __restrict__ bv, const float* __restrict__ bk2,
                     const float* __restrict__ bv2,
                     float* __restrict__ out_lc, float* __restrict__ out_c,
                     unsigned short* __restrict__ hT,
                     unsigned short* __restrict__ Qb, unsigned short* __restrict__ Khb,
                     unsigned short* __restrict__ Kmb,
                     unsigned short* __restrict__ Vhb, unsigned short* __restrict__ Vmb)
{
    const int b  = blockIdx.y;
    const int p0 = blockIdx.x * 32;
    const int t  = threadIdx.x;
    const int l  = t & 63;
    const int w  = t >> 6;
    const int l15 = l & 15, lhi = l >> 4;

    __shared__ float sc[256][2];
    // phase1: [256ch][40] gate tile. phase2 reuse (bytes):
    //   hp [0,4096) ; mp [4096,8192) ; qk [8192,12288) ; km [12288,16384)
    __shared__ __align__(16) unsigned short cct[10240];

    {
        float S=0.f, Q=0.f;
#pragma unroll
        for (int part=0; part<8; ++part){
            S += statsS[((size_t)b*8 + part)*256 + t];
            Q += statsQ[((size_t)b*8 + part)*256 + t];
        }
        float mu  = S*(1.0f/1024.0f);
        float var = Q*(1.0f/1024.0f) - mu*mu;
        float rs  = rsqrtf(var + 1e-5f);
        float gw  = gnw[t];
        sc[t][0] = rs*gw;
        sc[t][1] = gnb[t] - mu*rs*gw;
    }
    for (int it=t; it<1024; it+=256){
        int row = it>>2, oct = it&3;
        ushort8 v = *reinterpret_cast<const ushort8*>(
            cc + (size_t)(b*256+row)*1024 + p0 + oct*8);
        *reinterpret_cast<ushort8*>(cct + row*40 + oct*8) = v;
    }
    __syncthreads();

    const int p = t & 31, cg = t >> 5;
    const size_t prow = (size_t)(b*1024 + p0 + p);
    float hm[8], mr[8];
    {
        ushort8 sv = *reinterpret_cast<const ushort8*>(sig_pm + prow*64 + cg*8);
#pragma unroll
        for (int j=0;j<8;j++){
            int ch = cg*8 + j;
            float xg[4];
#pragma unroll
            for (int g=0; g<4; g++){
                int row = g*64 + ch;
                float v = bf2f(cct[row*40 + p]);
                xg[g] = v*sc[row][0] + sc[row][1];
            }
            float lv  = lc_in[(size_t)(b*64+ch)*1024 + p0 + p];
            float lcn = sigmoidf_(xg[1])*lv + sigmoidf_(xg[0])*tanhf_(xg[3]);
            float cnx = sigmoidf_(xg[2])*tanhf_(lcn);
            out_lc[(size_t)(b*64+ch)*1024 + p0 + p] = lcn;
            out_c [(size_t)(b*64+ch)*1024 + p0 + p] = cnx;
            hm[j] = bf2f(sv[j])*tanhf_(cnx);
            mr[j] = m_in[(size_t)(b*64+ch)*1024 + p0 + p];
        }
    }
    __syncthreads();   // all cct gate reads done

    {
        ushort8 h0, m0;
#pragma unroll
        for (int j=0;j<8;j++){ h0[j]=f2bf(hm[j]); m0[j]=f2bf(mr[j]); }
        unsigned hb = (unsigned)(p*128) + (((unsigned)(cg*16)) ^ ((unsigned)(p&7)<<4));
        *reinterpret_cast<ushort8*>(reinterpret_cast<char*>(cct) + hb) = h0;
        *reinterpret_cast<ushort8*>(reinterpret_cast<char*>(cct) + 4096 + hb) = m0;
        *reinterpret_cast<ushort8*>(hT + prow*64 + cg*8) = h0;
    }
    __syncthreads();

    // proj: waves 0-1 -> h (Q,K,V), waves 2-3 -> m (Km,Vm). pixel frag = (w&1)*16.
    const int pass = w >> 1;
    const int pix  = (w&1)*16 + l15;
    const unsigned xsw = ((unsigned)(pix&7)) << 4;
    if (pass == 0){
        f32x4 dh[8];
#pragma unroll
        for (int i=0;i<8;i++) dh[i] = (f32x4){0.f,0.f,0.f,0.f};
#pragma unroll
        for (int ks=0; ks<2; ++ks){
            unsigned xb = (unsigned)(pix*128) + (((unsigned)(ks*64 + lhi*16)) ^ xsw);
            bf16x8 xh = *reinterpret_cast<const bf16x8*>(reinterpret_cast<const char*>(cct) + xb);
#pragma unroll
            for (int ocf=0; ocf<8; ocf++){
                bf16x8 af = *reinterpret_cast<const bf16x8*>(
                    wph + (size_t)(ocf*16 + l15)*64 + ks*32 + lhi*8);
                dh[ocf] = __builtin_amdgcn_mfma_f32_16x16x32_bf16(af, xh, dh[ocf], 0,0,0);
            }
        }
#pragma unroll
        for (int ocf=0; ocf<4; ocf++)
#pragma unroll
            for (int r=0;r<4;r++){
                int vc = ocf*16 + lhi*4 + r;
                Vhb[(size_t)(b*64+vc)*1024 + p0 + pix] = f2bf(dh[4+ocf][r] + bv[vc]);
            }
#pragma unroll
        for (int ocf=0; ocf<2; ocf++)
#pragma unroll
            for (int r=0;r<4;r++){
                int qc = ocf*16 + lhi*4 + r;
                unsigned byq = (unsigned)(pix*128) + (((unsigned)(qc*2))      ^ xsw);
                unsigned byk = (unsigned)(pix*128) + (((unsigned)(64 + qc*2)) ^ xsw);
                *reinterpret_cast<unsigned short*>(reinterpret_cast<char*>(cct) + 8192 + byq)
                    = f2bf(dh[ocf][r]   + bq[qc]);
                *reinterpret_cast<unsigned short*>(reinterpret_cast<char*>(cct) + 8192 + byk)
                    = f2bf(dh[2+ocf][r] + bk[qc]);
            }
    } else {
        f32x4 dm[6];
#pragma unroll
        for (int i=0;i<6;i++) dm[i] = (f32x4){0.f,0.f,0.f,0.f};
#pragma unroll
        for (int ks=0; ks<2; ++ks){
            unsigned xb = (unsigned)(pix*128) + (((unsigned)(ks*64 + lhi*16)) ^ xsw);
            bf16x8 xm = *reinterpret_cast<const bf16x8*>(
                reinterpret_cast<const char*>(cct) + 4096 + xb);
#pragma unroll
            for (int ocf=0; ocf<6; ocf++){
                bf16x8 am = *reinterpret_cast<const bf16x8*>(
                    wpm + (size_t)(ocf*16 + l15)*64 + ks*32 + lhi*8);
                dm[ocf] = __builtin_amdgcn_mfma_f32_16x16x32_bf16(am, xm, dm[ocf], 0,0,0);
            }
        }
#pragma unroll
        for (int ocf=0; ocf<4; ocf++)
#pragma unroll
            for (int r=0;r<4;r++){
                int vc = ocf*16 + lhi*4 + r;
                Vmb[(size_t)(b*64+vc)*1024 + p0 + pix] = f2bf(dm[2+ocf][r] + bv2[vc]);
            }
#pragma unroll
        for (int ocf=0; ocf<2; ocf++)
#pragma unroll
            for (int r=0;r<4;r++){
                int qc = ocf*16 + lhi*4 + r;
                unsigned byq = (unsigned)(pix*128) + (((unsigned)(qc*2)) ^ xsw);
                *reinterpret_cast<unsigned short*>(reinterpret_cast<char*>(cct) + 12288 + byq)
                    = f2bf(dm[ocf][r] + bk2[qc]);
            }
    }
    __syncthreads();

    {   // flush Q/K: 32 rows x 8 octs
        int pr = t>>3, oct = t&7;
        unsigned byte = (unsigned)(pr*128) + (((unsigned)(oct*16)) ^ ((unsigned)(pr&7)<<4));
        ushort8 v = *reinterpret_cast<const ushort8*>(
            reinterpret_cast<const char*>(cct) + 8192 + byte);
        if (oct < 4) *reinterpret_cast<ushort8*>(Qb  + (size_t)(b*1024+p0+pr)*32 + oct*8) = v;
        else         *reinterpret_cast<ushort8*>(Khb + (size_t)(b*1024+p0+pr)*32 + (oct-4)*8) = v;
    }
    if (t < 128){  // flush Km: 32 rows x 4 octs
        int pr = t>>2, oct = t&3;
        unsigned byte = (unsigned)(pr*128) + (((unsigned)(oct*16)) ^ ((unsigned)(pr&7)<<4));
        ushort8 v = *reinterpret_cast<const ushort8*>(
            reinterpret_cast<const char*>(cct) + 12288 + byte);
        *reinterpret_cast<ushort8*>(Kmb + (size_t)(b*1024+p0+pr)*32 + oct*8) = v;
    }
}

// ---------- fused attention + final mix ----------
__global__ __launch_bounds__(256)
void attn_final_kernel(const unsigned short* __restrict__ Qb,
                       const unsigned short* __restrict__ Kh,
                       const unsigned short* __restrict__ Km,
                       const unsigned short* __restrict__ Vh,
                       const unsigned short* __restrict__ Vm,
                       const unsigned short* __restrict__ hT,
                       const unsigned short* __restrict__ wzb,
                       const unsigned short* __restrict__ wmb,
                       const float* __restrict__ bz, const float* __restrict__ bm,
                       const float* __restrict__ m_in,
                       float* __restrict__ out_h, float* __restrict__ out_m)
{
    const int bid  = blockIdx.x;
    const int xcd  = bid & 7;
    const int slot = bid >> 3;
    const int b    = xcd*2 + (slot>>5);
    const int p0   = (slot & 31) * 32;
    const int t   = threadIdx.x;
    const int l   = t & 63;
    const int w   = t >> 6;
    const int l15 = l & 15, g = l >> 4;
    const int pass = w >> 1;
    const int ph   = w & 1;

    __shared__ __align__(16) unsigned short Kt[2][2][2560];
    __shared__ __align__(16) unsigned short Vt[2][2][4096];
    __shared__ __align__(16) unsigned short Pt[2][2048];
    __shared__ __align__(16) unsigned short Bs[32*192];

    const bf16x8 qa = *reinterpret_cast<const bf16x8*>(
        Qb + (size_t)(b*1024 + p0 + ph*16 + l15)*32 + g*8);

    float m_run = -1e30f, l_run = 0.0f;
    f32x4 acc[4];
#pragma unroll
    for (int cf=0;cf<4;cf++) acc[cf] = (f32x4){0.f,0.f,0.f,0.f};

    const int krow = t>>2, koct = t&3;
    const int vrow = t>>3, voct = t&7;
    const unsigned kwb  = (unsigned)(krow*80 + koct*16);
    const unsigned vwb0 = (unsigned)(vrow*128)      + (((unsigned)voct*16) ^ ((unsigned)(vrow&7)<<4));
    const unsigned vwb1 = (unsigned)((vrow+32)*128) + (((unsigned)voct*16) ^ ((unsigned)((vrow+32)&7)<<4));

    ushort8 kr0, kr1, vv0, vv1, vv2, vv3;
#define LDSTAGE(Q0N) do { \
        kr0 = *reinterpret_cast<const ushort8*>(Kh + (size_t)(b*1024 + (Q0N) + krow)*32 + koct*8); \
        kr1 = *reinterpret_cast<const ushort8*>(Km + (size_t)(b*1024 + (Q0N) + krow)*32 + koct*8); \
        vv0 = *reinterpret_cast<const ushort8*>(Vh + (size_t)(b*64 + vrow)*1024 + (Q0N) + voct*8); \
        vv1 = *reinterpret_cast<const ushort8*>(Vh + (size_t)(b*64 + vrow+32)*1024 + (Q0N) + voct*8); \
        vv2 = *reinterpret_cast<const ushort8*>(Vm + (size_t)(b*64 + vrow)*1024 + (Q0N) + voct*8); \
        vv3 = *reinterpret_cast<const ushort8*>(Vm + (size_t)(b*64 + vrow+32)*1024 + (Q0N) + voct*8); \
    } while(0)
#define WRSTAGE(BUF) do { \
        *reinterpret_cast<ushort8*>(reinterpret_cast<char*>(Kt[0][BUF]) + kwb)  = kr0; \
        *reinterpret_cast<ushort8*>(reinterpret_cast<char*>(Kt[1][BUF]) + kwb)  = kr1; \
        *reinterpret_cast<ushort8*>(reinterpret_cast<char*>(Vt[0][BUF]) + vwb0) = vv0; \
        *reinterpret_cast<ushort8*>(reinterpret_cast<char*>(Vt[0][BUF]) + vwb1) = vv1; \
        *reinterpret_cast<ushort8*>(reinterpret_cast<char*>(Vt[1][BUF]) + vwb0) = vv2; \
        *reinterpret_cast<ushort8*>(reinterpret_cast<char*>(Vt[1][BUF]) + vwb1) = vv3; \
    } while(0)

    LDSTAGE(0);
    WRSTAGE(0);
    __syncthreads();

    const unsigned prow = (unsigned)(ph*16 + l15);
    const unsigned psw  = (prow & 7u) << 4;
    char* Pbase = reinterpret_cast<char*>(Pt[pass]);

    for (int it=0; it<16; ++it){
        const int cur = it & 1;
        if (it < 15) LDSTAGE((it+1)*64);

        f32x4 s2[4];
#pragma unroll
        for (int qt=0; qt<4; qt++){
            const bf16x8 kb = *reinterpret_cast<const bf16x8*>(
                reinterpret_cast<const char*>(Kt[pass][cur]) + (qt*16 + l15)*80 + g*16);
            s2[qt] = __builtin_amdgcn_mfma_f32_16x16x32_bf16(kb, qa, (f32x4){0.f,0.f,0.f,0.f}, 0,0,0);
        }

        float pm = s2[0][0];
#pragma unroll
        for (int qt=0; qt<4; qt++)
#pragma unroll
            for (int r=0;r<4;r++) pm = fmaxf(pm, s2[qt][r]);
        pm = fmaxf(pm, __shfl_xor(pm, 16));
        pm = fmaxf(pm, __shfl_xor(pm, 32));

        if (!__all(pm <= m_run + 8.0f)){
            float mn = fmaxf(m_run, pm);
            float f  = __expf(m_run - mn);
            m_run = mn;
            l_run *= f;
#pragma unroll
            for (int r=0;r<4;r++){
                float fr = __shfl(f, (l & 48) | ((l>>4)*4 + r), 64);
#pragma unroll
                for (int cf=0;cf<4;cf++) acc[cf][r] *= fr;
            }
        }

        float e[4][4];
        float lsum = 0.f;
#pragma unroll
        for (int qt=0; qt<4; qt++)
#pragma unroll
            for (int r=0;r<4;r++){
                float ev = __expf(s2[qt][r] - m_run);
                e[qt][r] = ev;
                lsum += ev;
            }
        lsum += __shfl_xor(lsum, 16);
        lsum += __shfl_xor(lsum, 32);
        l_run += lsum;

#pragma unroll
        for (int qt=0; qt<4; qt++){
            uint2v pk;
            pk.x = cvt_pk_bf16(e[qt][0], e[qt][1]);
            pk.y = cvt_pk_bf16(e[qt][2], e[qt][3]);
            unsigned byte = prow*128 + (((unsigned)(qt*32 + g*8)) ^ psw);
            *reinterpret_cast<uint2v*>(Pbase + byte) = pk;
        }

#pragma unroll
        for (int ks=0;ks<2;ks++){
            unsigned abyte = prow*128 + (((unsigned)(ks*64 + g*16)) ^ psw);
            const bf16x8 pa = *reinterpret_cast<const bf16x8*>(Pbase + abyte);
#pragma unroll
            for (int cf=0;cf<4;cf++){
                unsigned vrw = (unsigned)(cf*16 + l15);
                unsigned vbyte = vrw*128 + (((unsigned)(ks*64 + g*16)) ^ ((vrw&7u)<<4));
                const bf16x8 vb = *reinterpret_cast<const bf16x8*>(
                    reinterpret_cast<const char*>(Vt[pass][cur]) + vbyte);
                acc[cf] = __builtin_amdgcn_mfma_f32_16x16x32_bf16(pa, vb, acc[cf], 0,0,0);
            }
        }

        if (it < 15) WRSTAGE(cur^1);
        __syncthreads();
    }
#undef LDSTAGE
#undef WRSTAGE

    {
        float rl = 1.0f / l_run;
        float rr[4];
#pragma unroll
        for (int r=0;r<4;r++) rr[r] = __shfl(rl, (l & 48) | ((l>>4)*4 + r), 64);
#pragma unroll
        for (int cf=0;cf<4;cf++)
#pragma unroll
            for (int r=0;r<4;r++){
                unsigned pix = (unsigned)(ph*16 + g*4 + r);
                unsigned cch = (unsigned)(pass*64 + cf*16 + l15);
                unsigned byte = pix*384 + ((cch*2) ^ ((pix&7u)<<4));
                *reinterpret_cast<unsigned short*>(reinterpret_cast<char*>(Bs) + byte)
                    = f2bf(acc[cf][r]*rr[r]);
            }
    }
    {
        int row = t>>3, oct = t&7;
        ushort8 v = *reinterpret_cast<const ushort8*>(
            hT + (size_t)(b*1024 + p0 + row)*64 + oct*8);
        unsigned byte = (unsigned)(row*384) + 256u + (((unsigned)oct*16) ^ ((unsigned)(row&7)<<4));
        *reinterpret_cast<ushort8*>(reinterpret_cast<char*>(Bs) + byte) = v;
    }
    __syncthreads();

    f32x4 acc1[2][2];
#pragma unroll
    for (int i=0;i<2;i++)
#pragma unroll
        for (int cf=0;cf<2;cf++) acc1[i][cf] = (f32x4){0.f,0.f,0.f,0.f};
#pragma unroll
    for (int ks=0; ks<4; ++ks){
        bf16x8 af[2];
#pragma unroll
        for (int i=0;i<2;i++)
            af[i] = *reinterpret_cast<const bf16x8*>(
                wzb + (size_t)(w*32 + i*16 + l15)*128 + ks*32 + g*8);
#pragma unroll
        for (int cf=0;cf<2;cf++){
            unsigned p = (unsigned)(cf*16 + l15);
            unsigned byte = p*384 + (((unsigned)(ks*64 + g*16)) ^ ((p&7u)<<4));
            const bf16x8 bfr = *reinterpret_cast<const bf16x8*>(
                reinterpret_cast<const char*>(Bs) + byte);
            acc1[0][cf] = __builtin_amdgcn_mfma_f32_16x16x32_bf16(af[0], bfr, acc1[0][cf], 0,0,0);
            acc1[1][cf] = __builtin_amdgcn_mfma_f32_16x16x32_bf16(af[1], bfr, acc1[1][cf], 0,0,0);
        }
    }
    __syncthreads();
#pragma unroll
    for (int i=0;i<2;i++){
        int co = w*32 + i*16 + g*4;
#pragma unroll
        for (int cf=0;cf<2;cf++){
            unsigned p = (unsigned)(cf*16 + l15);
#pragma unroll
            for (int r=0;r<4;r++){
                float val = acc1[i][cf][r] + bz[co+r];
                unsigned byte = p*384 + (((unsigned)((co+r)*2)) ^ ((p&7u)<<4));
                *reinterpret_cast<unsigned short*>(reinterpret_cast<char*>(Bs) + byte) = f2bf(val);
            }
        }
    }
    __syncthreads();

    f32x4 acc2[3][2];
#pragma unroll
    for (int j=0;j<3;j++)
#pragma unroll
        for (int cf=0;cf<2;cf++) acc2[j][cf] = (f32x4){0.f,0.f,0.f,0.f};
#pragma unroll
    for (int ks=0; ks<6; ++ks){
        bf16x8 am[3];
#pragma unroll
        for (int j=0;j<3;j++)
            am[j] = *reinterpret_cast<const bf16x8*>(
                wmb + (size_t)(j*64 + w*16 + l15)*192 + ks*32 + g*8);
#pragma unroll
        for (int cf=0;cf<2;cf++){
            unsigned p = (unsigned)(cf*16 + l15);
            unsigned byte = p*384 + (((unsigned)(ks*64 + g*16)) ^ ((p&7u)<<4));
            const bf16x8 bfr = *reinterpret_cast<const bf16x8*>(
                reinterpret_cast<const char*>(Bs) + byte);
#pragma unroll
            for (int j=0;j<3;j++)
                acc2[j][cf] = __builtin_amdgcn_mfma_f32_16x16x32_bf16(am[j], bfr, acc2[j][cf], 0,0,0);
        }
    }

    const int ch0 = w*16 + g*4;
#pragma unroll
    for (int cf=0;cf<2;cf++){
        int pix = p0 + cf*16 + l15;
#pragma unroll
        for (int r=0;r<4;r++){
            int ch = ch0 + r;
            float mo = acc2[0][cf][r] + bm[ch];
            float mg = acc2[1][cf][r] + bm[64+ch];
            float mi = sigmoidf_(acc2[2][cf][r] + bm[128+ch]);
            float mv = m_in[(size_t)(b*64+ch)*1024 + pix];
            float mn = (1.0f - mi)*mv + mi*tanhf_(mg);
            out_m[(size_t)(b*64+ch)*1024 + pix] = mn;
            out_h[(size_t)(b*64+ch)*1024 + pix] = sigmoidf_(mo)*mn;
        }
    }
}

extern "C" void kernel_launch(void* const* d_in, const int* in_sizes, int n_in,
                              void* d_out, int out_size, void* d_ws, size_t ws_size,
                              hipStream_t stream)
{
    const float* x      = (const float*)d_in[0];
    const float* h      = (const float*)d_in[1];
    const float* c      = (const float*)d_in[2];
    const float* m      = (const float*)d_in[3];
    const float* lc     = (const float*)d_in[4];
    const float* conv_w = (const float*)d_in[5];
    const float* conv_b = (const float*)d_in[6];
    const float* gn1_w  = (const float*)d_in[7];
    const float* gn1_b  = (const float*)d_in[8];
    const float* convL_w= (const float*)d_in[9];
    const float* convL_b= (const float*)d_in[10];
    const float* gn2_w  = (const float*)d_in[11];
    const float* gn2_b  = (const float*)d_in[12];
    const float* wq  = (const float*)d_in[13];
    const float* bq  = (const float*)d_in[14];
    const float* wk  = (const float*)d_in[15];
    const float* bk  = (const float*)d_in[16];
    const float* wk2 = (const float*)d_in[17];
    const float* bk2 = (const float*)d_in[18];
    const float* wv  = (const float*)d_in[19];
    const float* bv  = (const float*)d_in[20];
    const float* wv2 = (const float*)d_in[21];
    const float* bv2 = (const float*)d_in[22];
    const float* wz  = (const float*)d_in[23];
    const float* bz  = (const float*)d_in[24];
    const float* wmw = (const float*)d_in[25];
    const float* bm  = (const float*)d_in[26];

    float* out = (float*)d_out;
    float* F = (float*)d_ws;
    unsigned short* cc_bf  = (unsigned short*)F;              // [16][256][1024] bf16
    unsigned short* buf1   = (unsigned short*)(F + 2097152);  // padded [16][1156][128]
    unsigned short* buf2   = (unsigned short*)(F + 3280896);  // padded
    unsigned short* hT     = (unsigned short*)(F + 4464640);  // [16][1024][64]
    unsigned short* Qb     = (unsigned short*)(F + 4988928);
    unsigned short* Khb    = (unsigned short*)(F + 5251072);
    unsigned short* Kmb    = (unsigned short*)(F + 5513216);
    unsigned short* Vhb    = (unsigned short*)(F + 5775360);
    unsigned short* Vmb    = (unsigned short*)(F + 6299648);
    unsigned short* sig_pm = (unsigned short*)(F + 6823936);  // [16][1024][64]
    unsigned short* wpk1   = (unsigned short*)(F + 7348224);
    unsigned short* wpk2   = (unsigned short*)(F + 7495680);
    unsigned short* wzb    = (unsigned short*)(F + 7643136);
    unsigned short* wmb    = (unsigned short*)(F + 7651328);
    unsigned short* wph    = (unsigned short*)(F + 7669760);
    unsigned short* wpm    = (unsigned short*)(F + 7673856);
    float*          statsS = F + 7676928;                     // [16][8][256] f32
    float*          statsQ = F + 7709696;                     // [16][8][256] f32

    dim3 blk256(256);
    prep_kernel<<<dim3(1440), blk256, 0, stream>>>(conv_w, convL_w, wz, wmw,
                                                   wq, wk, wv, wk2, wv2, x, h,
                                                   wpk1, wpk2, wzb, wmb, wph, wpm,
                                                   buf1, buf2);
    dim3 cgrid(8, 4, 16);
    conv_mfma_kernel<<<cgrid, blk256, 0, stream>>>(buf1, wpk1, conv_b, cc_bf, statsS, statsQ);
    gn_gate1_kernel<<<dim3(32,16), blk256, 0, stream>>>(cc_bf, statsS, statsQ, gn1_w, gn1_b, c,
                                                        buf2, sig_pm);
    conv_mfma_kernel<<<cgrid, blk256, 0, stream>>>(buf2, wpk2, convL_b, cc_bf, statsS, statsQ);
    gn2_proj_kernel<<<dim3(32,16), blk256, 0, stream>>>(cc_bf, statsS, statsQ, gn2_w, gn2_b,
                                                        lc, sig_pm, m, wph, wpm,
                                                        bq, bk, bv, bk2, bv2,
                                                        out + 3*1048576 /*lc_next*/,
                                                        out + 1*1048576 /*c_next*/,
                                                        hT, Qb, Khb, Kmb, Vhb, Vmb);
    attn_final_kernel<<<dim3(512), blk256, 0, stream>>>(Qb, Khb, Kmb, Vhb, Vmb, hT,
                                                        wzb, wmb, bz, bm, m,
                                                        out /*h_next*/, out + 2*1048576 /*m_next*/);
    (void)in_sizes; (void)n_in; (void)out_size; (void)ws_size;
}

// Round 12
// 103.976 us; speedup vs baseline: 1.4521x; 1.0531x over previous
//
#include <hip/hip_runtime.h>

#define DEV __device__ __forceinline__

typedef __attribute__((ext_vector_type(8))) __bf16 bf16x8;
typedef __attribute__((ext_vector_type(4))) float f32x4;
typedef __attribute__((ext_vector_type(8))) unsigned short ushort8;
typedef __attribute__((ext_vector_type(2))) unsigned short ushort2v;
typedef __attribute__((ext_vector_type(2))) unsigned int uint2v;

DEV float sigmoidf_(float x){ return 1.0f/(1.0f + __expf(-x)); }
DEV float tanhf_(float x){
    x = fminf(15.0f, fmaxf(-15.0f, x));
    float e = __expf(2.0f*x);
    return (e - 1.0f)/(e + 1.0f);
}
DEV unsigned short f2bf(float f){
    unsigned u = __builtin_bit_cast(unsigned, f);
    unsigned r = (u + 0x7FFFu + ((u>>16)&1u)) >> 16;
    return (unsigned short)r;
}
DEV float bf2f(unsigned short u){
    return __builtin_bit_cast(float, ((unsigned)u)<<16);
}
DEV unsigned cvt_pk_bf16(float lo, float hi){
    unsigned r;
    asm("v_cvt_pk_bf16_f32 %0, %1, %2" : "=v"(r) : "v"(lo), "v"(hi));
    return r;
}

// ---------- merged prep: weights -> bf16 packs (coalesced stores) ; pack x,h -> PADDED buf1/buf2 ----------
// padded layout: [b][34*34=1156 px][128ci] bf16, px = (row+1)*34 + (col+1)
__global__ __launch_bounds__(256)
void prep_kernel(const float* __restrict__ conv_w, const float* __restrict__ convL_w,
                 const float* __restrict__ wz, const float* __restrict__ wm,
                 const float* __restrict__ wq, const float* __restrict__ wk,
                 const float* __restrict__ wv, const float* __restrict__ wk2,
                 const float* __restrict__ wv2,
                 const float* __restrict__ x, const float* __restrict__ h,
                 unsigned short* __restrict__ wpk1, unsigned short* __restrict__ wpk2,
                 unsigned short* __restrict__ wzb, unsigned short* __restrict__ wmb,
                 unsigned short* __restrict__ wph, unsigned short* __restrict__ wpm,
                 unsigned short* __restrict__ buf1, unsigned short* __restrict__ buf2)
{
    __shared__ float tile[128][65];
    if (blockIdx.x < 1152) {
        int oidx = blockIdx.x*256 + threadIdx.x;   // output-major: fully coalesced stores
        {
            int ci5 = oidx & 31;
            int co  = (oidx >> 5) & 255;
            int kch = oidx >> 13;                  // 0..35
            int cic = kch / 9, tap = kch - 9*cic;
            int src = co*1152 + (cic*32 + ci5)*9 + tap;
            wpk1[oidx] = f2bf(conv_w[src]);
            wpk2[oidx] = f2bf(convL_w[src]);
        }
        if (oidx < 128*128) wzb[oidx] = f2bf(wz[oidx]);
        if (oidx < 192*192) wmb[oidx] = f2bf(wm[oidx]);
        if (oidx < 32*64){
            wph[oidx]        = f2bf(wq[oidx]);
            wph[2048 + oidx] = f2bf(wk[oidx]);
            wpm[oidx]        = f2bf(wk2[oidx]);
        }
        if (oidx < 64*64){
            wph[4096 + oidx] = f2bf(wv[oidx]);
            wpm[2048 + oidx] = f2bf(wv2[oidx]);
        }
    } else if (blockIdx.x < 1184) {
        int bx2 = blockIdx.x - 1152;
        int b = bx2 >> 1;
        unsigned short* buf = (bx2 & 1) ? buf2 : buf1;
        for (int i = threadIdx.x; i < 8448; i += 256){
            int px = i >> 6, u = i & 63;
            int rr, cc2;
            if (px < 34)      { rr = 0;         cc2 = px; }
            else if (px < 68) { rr = 33;        cc2 = px-34; }
            else if (px < 100){ rr = px-68+1;   cc2 = 0; }
            else              { rr = px-100+1;  cc2 = 33; }
            reinterpret_cast<unsigned*>(buf + (size_t)(b*1156 + rr*34 + cc2)*128)[u] = 0u;
        }
    } else {
        int i  = blockIdx.x - 1184;                 // 0..255, XCD-swizzled: batch b on XCD b/2
        int b  = (i&7)*2 + ((i>>3)&1);
        int p0 = (i>>4) * 64;
        int t  = threadIdx.x;
        for (int k=t;k<8192;k+=256){
            int ci = k>>6, pp = k&63;
            const float* s = (ci<64) ? x + (size_t)(b*64+ci)*1024
                                     : h + (size_t)(b*64+ci-64)*1024;
            tile[ci][pp] = s[p0+pp];
        }
        __syncthreads();
        for (int k=t;k<4096;k+=256){
            int pp = k>>6, c2 = k&63;
            int p  = p0 + pp;
            size_t pidx = (size_t)(b*1156 + ((p>>5)+1)*34 + (p&31) + 1);
            ushort2v v;
            v.x = f2bf(tile[c2*2][pp]);
            v.y = f2bf(tile[c2*2+1][pp]);
            *reinterpret_cast<ushort2v*>(buf1 + pidx*128 + c2*2) = v;
            if (c2 >= 32)
                *reinterpret_cast<ushort2v*>(buf2 + pidx*128 + (c2-32)*2) = v;
        }
    }
}

// ---------- implicit-GEMM 3x3 conv via MFMA: padded input, async DMA staging, A-ring-4 / B-ring-3 ----------
// grid: flat 512, XCD-swizzled: b = (bid&7)*2+((bid>>3)&1), co0 = ((bid>>4)&3)*64, r0 = (bid>>6)*4
__global__ __launch_bounds__(256, 2)
void conv_mfma_kernel(const unsigned short* __restrict__ inp,
                      const unsigned short* __restrict__ wpk,
                      const float* __restrict__ bias,
                      unsigned short* __restrict__ out,
                      float* __restrict__ statsS, float* __restrict__ statsQ)
{
    const int bid = blockIdx.x;
    const int b   = (bid&7)*2 + ((bid>>3)&1);
    const int co0 = ((bid>>4)&3) * 64;
    const int rt  = bid>>6;                 // 0..7
    const int r0  = rt * 4;
    const int t   = threadIdx.x;
    const int l   = t & 63;
    const int wv  = t >> 6;
    const int l15 = l & 15;
    const int lhi = l >> 4;

    __shared__ __align__(16) unsigned short in_t[26112];  // 204 pixlin x 128ci, XOR-swizzled

    {
        const char* gsrc = reinterpret_cast<const char*>(inp + (size_t)(b*1156 + r0*34)*128);
#pragma unroll
        for (int it = 0; it < 13; ++it){
            unsigned lbase = (unsigned)(it*4096 + wv*1024);
            if (lbase < 52224u){
                unsigned beta = lbase + (unsigned)l*16u;
                unsigned soff = (beta & ~255u) + ((beta & 0xF0u) ^ (((beta>>8)&7u)<<4));
                __builtin_amdgcn_global_load_lds(
                    (const __attribute__((address_space(1))) void*)(gsrc + soff),
                    (__attribute__((address_space(3))) void*)(
                        (__attribute__((address_space(3))) char*)in_t + lbase),
                    16, 0, 0);
            }
        }
    }

    f32x4 acc[4][2];
#pragma unroll
    for (int i=0;i<4;i++)
#pragma unroll
        for (int f=0;f<2;f++)
            acc[i][f] = (f32x4){0.f,0.f,0.f,0.f};

    bf16x8 areg[4][4], breg[3][2];
#define LDA_(K, SLOT) do { const unsigned short* wrow_ = wpk + ((K)*256 + co0)*32; \
        for (int i_=0;i_<4;i_++) areg[SLOT][i_] = *reinterpret_cast<const bf16x8*>(wrow_ + (i_*16 + l15)*32 + lhi*8); } while(0)
#define LDB_(K, SLOT) do { const int cic_ = (K)/9, tap_ = (K) - 9*((K)/9); \
        const int ky_ = tap_/3, kx_ = tap_ - 3*(tap_/3); \
        for (int f_=0;f_<2;f_++){ int pl_ = (wv + ky_)*34 + (f_*16 + l15 + kx_); \
            unsigned by_ = (unsigned)(pl_*256 + cic_*64 + lhi*16) ^ (((unsigned)pl_ & 7u) << 4); \
            breg[SLOT][f_] = *reinterpret_cast<const bf16x8*>(reinterpret_cast<const char*>(in_t) + by_); } } while(0)

    LDA_(0, 0); LDA_(1, 1); LDA_(2, 2);
    __syncthreads();
    LDB_(0, 0); LDB_(1, 1);
#pragma unroll
    for (int k=0; k<36; ++k){
        const int as = k & 3, bs = k % 3;
        if (k+3 < 36) LDA_(k+3, (k+3)&3);
        if (k+2 < 36) LDB_(k+2, (k+2)%3);
        __builtin_amdgcn_s_setprio(1);
#pragma unroll
        for (int i=0;i<4;i++){
            acc[i][0] = __builtin_amdgcn_mfma_f32_16x16x32_bf16(areg[as][i], breg[bs][0], acc[i][0], 0,0,0);
            acc[i][1] = __builtin_amdgcn_mfma_f32_16x16x32_bf16(areg[as][i], breg[bs][1], acc[i][1], 0,0,0);
        }
        __builtin_amdgcn_s_setprio(0);
    }
#undef LDA_
#undef LDB_

    __syncthreads();   // all in_t reads done; reuse LDS for stat reduction
    float* red = reinterpret_cast<float*>(in_t);

    const int orow = r0 + wv;
    float s_ir[4][4], q_ir[4][4];
#pragma unroll
    for (int i=0;i<4;i++){
        int cobase = co0 + i*16 + lhi*4;
#pragma unroll
        for (int r=0;r<4;r++){
            float bs = bias[cobase+r];
            float e0 = acc[i][0][r] + bs;
            float e1 = acc[i][1][r] + bs;
            out[(size_t)(b*256 + cobase + r)*1024 + orow*32 + l15]      = f2bf(e0);
            out[(size_t)(b*256 + cobase + r)*1024 + orow*32 + 16 + l15] = f2bf(e1);
            s_ir[i][r] = e0 + e1;
            q_ir[i][r] = e0*e0 + e1*e1;
        }
    }
#pragma unroll
    for (int i=0;i<4;i++)
#pragma unroll
        for (int r=0;r<4;r++){
            float s = s_ir[i][r], q = q_ir[i][r];
            s += __shfl_xor(s,1); q += __shfl_xor(q,1);
            s += __shfl_xor(s,2); q += __shfl_xor(q,2);
            s += __shfl_xor(s,4); q += __shfl_xor(q,4);
            s += __shfl_xor(s,8); q += __shfl_xor(q,8);
            s_ir[i][r] = s; q_ir[i][r] = q;
        }
    if (l15 == 0){
#pragma unroll
        for (int i=0;i<4;i++)
#pragma unroll
            for (int r=0;r<4;r++){
                red[wv*64 + i*16 + lhi*4 + r]       = s_ir[i][r];
                red[256 + wv*64 + i*16 + lhi*4 + r] = q_ir[i][r];
            }
    }
    __syncthreads();
    if (t < 64){
        float S = red[t]+red[64+t]+red[128+t]+red[192+t];
        float Q = red[256+t]+red[320+t]+red[384+t]+red[448+t];
        statsS[((size_t)b*8 + rt)*256 + co0 + t] = S;
        statsQ[((size_t)b*8 + rt)*256 + co0 + t] = Q;
    }
}

// ---------- GN gate1, 32-pixel tiles (XCD-swizzled grid) ----------
__global__ __launch_bounds__(256)
void gn_gate1_kernel(const unsigned short* __restrict__ cc,
                     const float* __restrict__ statsS, const float* __restrict__ statsQ,
                     const float* __restrict__ gnw, const float* __restrict__ gnb,
                     const float* __restrict__ c_in,
                     unsigned short* __restrict__ buf2, unsigned short* __restrict__ sig_pm)
{
    const int bid = blockIdx.x;
    const int b   = (bid&7)*2 + ((bid>>3)&1);
    const int p0  = (bid>>4) * 32;
    const int t  = threadIdx.x;
    __shared__ float sc[256][2];
    __shared__ __align__(16) unsigned short cct[10240];   // [256ch][40] (80B rows)

    {
        float S=0.f, Q=0.f;
#pragma unroll
        for (int part=0; part<8; ++part){
            S += statsS[((size_t)b*8 + part)*256 + t];
            Q += statsQ[((size_t)b*8 + part)*256 + t];
        }
        float mu  = S*(1.0f/1024.0f);
        float var = Q*(1.0f/1024.0f) - mu*mu;
        float rs  = rsqrtf(var + 1e-5f);
        float gw  = gnw[t];
        sc[t][0] = rs*gw;
        sc[t][1] = gnb[t] - mu*rs*gw;
    }
    for (int it=t; it<1024; it+=256){
        int row = it>>2, oct = it&3;
        ushort8 v = *reinterpret_cast<const ushort8*>(
            cc + (size_t)(b*256+row)*1024 + p0 + oct*8);
        *reinterpret_cast<ushort8*>(cct + row*40 + oct*8) = v;
    }
    __syncthreads();

    const int p = t & 31, cg = t >> 5;
    float cn[8], so[8];
#pragma unroll
    for (int j=0;j<8;j++){
        int ch = cg*8 + j;
        float xg[4];
#pragma unroll
        for (int g=0; g<4; g++){
            int row = g*64 + ch;
            float v = bf2f(cct[row*40 + p]);
            xg[g] = v*sc[row][0] + sc[row][1];
        }
        float cv = c_in[(size_t)(b*64+ch)*1024 + p0 + p];
        cn[j] = sigmoidf_(xg[1])*cv + sigmoidf_(xg[0])*tanhf_(xg[3]);
        so[j] = sigmoidf_(xg[2]);
    }
    ushort8 v0, s0;
#pragma unroll
    for (int j=0;j<8;j++){ v0[j]=f2bf(cn[j]); s0[j]=f2bf(so[j]); }
    int pg = p0 + p;
    size_t pidx = (size_t)(b*1156 + ((pg>>5)+1)*34 + (pg&31) + 1);
    *reinterpret_cast<ushort8*>(buf2 + pidx*128 + 64 + cg*8) = v0;
    *reinterpret_cast<ushort8*>(sig_pm + (size_t)(b*1024 + pg)*64 + cg*8) = s0;
}

// ---------- GN gate2 + projections fused, 32-pixel tiles (XCD-swizzled grid) ----------
__global__ __launch_bounds__(256)
void gn2_proj_kernel(const unsigned short* __restrict__ cc,
                     const float* __restrict__ statsS, const float* __restrict__ statsQ,
                     const float* __restrict__ gnw, const float* __restrict__ gnb,
                     const float* __restrict__ lc_in, const unsigned short* __restrict__ sig_pm,
                     const float* __restrict__ m_in,
                     const unsigned short* __restrict__ wph, const unsigned short* __restrict__ wpm,
                     const float* __restrict__ bq, const float* __restrict__ bk,
                     const float* __restrict__ bv, const float* __restrict__ bk2,
                     const float* __restrict__ bv2,
                     float* __restrict__ out_lc, float* __restrict__ out_c,
                     unsigned short* __restrict__ hT,
                     unsigned short* __restrict__ Qb, unsigned short* __restrict__ Khb,
                     unsigned short* __restrict__ Kmb,
                     unsigned short* __restrict__ Vhb, unsigned short* __restrict__ Vmb)
{
    const int bid = blockIdx.x;
    const int b   = (bid&7)*2 + ((bid>>3)&1);
    const int p0  = (bid>>4) * 32;
    const int t  = threadIdx.x;
    const int l  = t & 63;
    const int w  = t >> 6;
    const int l15 = l & 15, lhi = l >> 4;

    __shared__ float sc[256][2];
    __shared__ __align__(16) unsigned short cct[10240];

    {
        float S=0.f, Q=0.f;
#pragma unroll
        for (int part=0; part<8; ++part){
            S += statsS[((size_t)b*8 + part)*256 + t];
            Q += statsQ[((size_t)b*8 + part)*256 + t];
        }
        float mu  = S*(1.0f/1024.0f);
        float var = Q*(1.0f/1024.0f) - mu*mu;
        float rs  = rsqrtf(var + 1e-5f);
        float gw  = gnw[t];
        sc[t][0] = rs*gw;
        sc[t][1] = gnb[t] - mu*rs*gw;
    }
    for (int it=t; it<1024; it+=256){
        int row = it>>2, oct = it&3;
        ushort8 v = *reinterpret_cast<const ushort8*>(
            cc + (size_t)(b*256+row)*1024 + p0 + oct*8);
        *reinterpret_cast<ushort8*>(cct + row*40 + oct*8) = v;
    }
    __syncthreads();

    const int p = t & 31, cg = t >> 5;
    const size_t prow = (size_t)(b*1024 + p0 + p);
    float hm[8], mr[8];
    {
        ushort8 sv = *reinterpret_cast<const ushort8*>(sig_pm + prow*64 + cg*8);
#pragma unroll
        for (int j=0;j<8;j++){
            int ch = cg*8 + j;
            float xg[4];
#pragma unroll
            for (int g=0; g<4; g++){
                int row = g*64 + ch;
                float v = bf2f(cct[row*40 + p]);
                xg[g] = v*sc[row][0] + sc[row][1];
            }
            float lv  = lc_in[(size_t)(b*64+ch)*1024 + p0 + p];
            float lcn = sigmoidf_(xg[1])*lv + sigmoidf_(xg[0])*tanhf_(xg[3]);
            float cnx = sigmoidf_(xg[2])*tanhf_(lcn);
            out_lc[(size_t)(b*64+ch)*1024 + p0 + p] = lcn;
            out_c [(size_t)(b*64+ch)*1024 + p0 + p] = cnx;
            hm[j] = bf2f(sv[j])*tanhf_(cnx);
            mr[j] = m_in[(size_t)(b*64+ch)*1024 + p0 + p];
        }
    }
    __syncthreads();

    {
        ushort8 h0, m0;
#pragma unroll
        for (int j=0;j<8;j++){ h0[j]=f2bf(hm[j]); m0[j]=f2bf(mr[j]); }
        unsigned hb = (unsigned)(p*128) + (((unsigned)(cg*16)) ^ ((unsigned)(p&7)<<4));
        *reinterpret_cast<ushort8*>(reinterpret_cast<char*>(cct) + hb) = h0;
        *reinterpret_cast<ushort8*>(reinterpret_cast<char*>(cct) + 4096 + hb) = m0;
        *reinterpret_cast<ushort8*>(hT + prow*64 + cg*8) = h0;
    }
    __syncthreads();

    const int pass = w >> 1;
    const int pix  = (w&1)*16 + l15;
    const unsigned xsw = ((unsigned)(pix&7)) << 4;
    if (pass == 0){
        f32x4 dh[8];
#pragma unroll
        for (int i=0;i<8;i++) dh[i] = (f32x4){0.f,0.f,0.f,0.f};
#pragma unroll
        for (int ks=0; ks<2; ++ks){
            unsigned xb = (unsigned)(pix*128) + (((unsigned)(ks*64 + lhi*16)) ^ xsw);
            bf16x8 xh = *reinterpret_cast<const bf16x8*>(reinterpret_cast<const char*>(cct) + xb);
            __builtin_amdgcn_s_setprio(1);
#pragma unroll
            for (int ocf=0; ocf<8; ocf++){
                bf16x8 af = *reinterpret_cast<const bf16x8*>(
                    wph + (size_t)(ocf*16 + l15)*64 + ks*32 + lhi*8);
                dh[ocf] = __builtin_amdgcn_mfma_f32_16x16x32_bf16(af, xh, dh[ocf], 0,0,0);
            }
            __builtin_amdgcn_s_setprio(0);
        }
#pragma unroll
        for (int ocf=0; ocf<4; ocf++)
#pragma unroll
            for (int r=0;r<4;r++){
                int vc = ocf*16 + lhi*4 + r;
                Vhb[(size_t)(b*64+vc)*1024 + p0 + pix] = f2bf(dh[4+ocf][r] + bv[vc]);
            }
#pragma unroll
        for (int ocf=0; ocf<2; ocf++)
#pragma unroll
            for (int r=0;r<4;r++){
                int qc = ocf*16 + lhi*4 + r;
                unsigned byq = (unsigned)(pix*128) + (((unsigned)(qc*2))      ^ xsw);
                unsigned byk = (unsigned)(pix*128) + (((unsigned)(64 + qc*2)) ^ xsw);
                *reinterpret_cast<unsigned short*>(reinterpret_cast<char*>(cct) + 8192 + byq)
                    = f2bf(dh[ocf][r]   + bq[qc]);
                *reinterpret_cast<unsigned short*>(reinterpret_cast<char*>(cct) + 8192 + byk)
                    = f2bf(dh[2+ocf][r] + bk[qc]);
            }
    } else {
        f32x4 dm[6];
#pragma unroll
        for (int i=0;i<6;i++) dm[i] = (f32x4){0.f,0.f,0.f,0.f};
#pragma unroll
        for (int ks=0; ks<2; ++ks){
            unsigned xb = (unsigned)(pix*128) + (((unsigned)(ks*64 + lhi*16)) ^ xsw);
            bf16x8 xm = *reinterpret_cast<const bf16x8*>(
                reinterpret_cast<const char*>(cct) + 4096 + xb);
            __builtin_amdgcn_s_setprio(1);
#pragma unroll
            for (int ocf=0; ocf<6; ocf++){
                bf16x8 am = *reinterpret_cast<const bf16x8*>(
                    wpm + (size_t)(ocf*16 + l15)*64 + ks*32 + lhi*8);
                dm[ocf] = __builtin_amdgcn_mfma_f32_16x16x32_bf16(am, xm, dm[ocf], 0,0,0);
            }
            __builtin_amdgcn_s_setprio(0);
        }
#pragma unroll
        for (int ocf=0; ocf<4; ocf++)
#pragma unroll
            for (int r=0;r<4;r++){
                int vc = ocf*16 + lhi*4 + r;
                Vmb[(size_t)(b*64+vc)*1024 + p0 + pix] = f2bf(dm[2+ocf][r] + bv2[vc]);
            }
#pragma unroll
        for (int ocf=0; ocf<2; ocf++)
#pragma unroll
            for (int r=0;r<4;r++){
                int qc = ocf*16 + lhi*4 + r;
                unsigned byq = (unsigned)(pix*128) + (((unsigned)(qc*2)) ^ xsw);
                *reinterpret_cast<unsigned short*>(reinterpret_cast<char*>(cct) + 12288 + byq)
                    = f2bf(dm[ocf][r] + bk2[qc]);
            }
    }
    __syncthreads();

    {   // flush Q/K: 32 rows x 8 octs
        int pr = t>>3, oct = t&7;
        unsigned byte = (unsigned)(pr*128) + (((unsigned)(oct*16)) ^ ((unsigned)(pr&7)<<4));
        ushort8 v = *reinterpret_cast<const ushort8*>(
            reinterpret_cast<const char*>(cct) + 8192 + byte);
        if (oct < 4) *reinterpret_cast<ushort8*>(Qb  + (size_t)(b*1024+p0+pr)*32 + oct*8) = v;
        else         *reinterpret_cast<ushort8*>(Khb + (size_t)(b*1024+p0+pr)*32 + (oct-4)*8) = v;
    }
    if (t < 128){  // flush Km: 32 rows x 4 octs
        int pr = t>>2, oct = t&3;
        unsigned byte = (unsigned)(pr*128) + (((unsigned)(oct*16)) ^ ((unsigned)(pr&7)<<4));
        ushort8 v = *reinterpret_cast<const ushort8*>(
            reinterpret_cast<const char*>(cct) + 12288 + byte);
        *reinterpret_cast<ushort8*>(Kmb + (size_t)(b*1024+p0+pr)*32 + oct*8) = v;
    }
}

// ---------- fused attention + final mix ----------
__global__ __launch_bounds__(256)
void attn_final_kernel(const unsigned short* __restrict__ Qb,
                       const unsigned short* __restrict__ Kh,
                       const unsigned short* __restrict__ Km,
                       const unsigned short* __restrict__ Vh,
                       const unsigned short* __restrict__ Vm,
                       const unsigned short* __restrict__ hT,
                       const unsigned short* __restrict__ wzb,
                       const unsigned short* __restrict__ wmb,
                       const float* __restrict__ bz, const float* __restrict__ bm,
                       const float* __restrict__ m_in,
                       float* __restrict__ out_h, float* __restrict__ out_m)
{
    const int bid  = blockIdx.x;
    const int xcd  = bid & 7;
    const int slot = bid >> 3;
    const int b    = xcd*2 + (slot>>5);
    const int p0   = (slot & 31) * 32;
    const int t   = threadIdx.x;
    const int l   = t & 63;
    const int w   = t >> 6;
    const int l15 = l & 15, g = l >> 4;
    const int pass = w >> 1;
    const int ph   = w & 1;

    __shared__ __align__(16) unsigned short Kt[2][2][2560];
    __shared__ __align__(16) unsigned short Vt[2][2][4096];
    __shared__ __align__(16) unsigned short Pt[2][2048];
    __shared__ __align__(16) unsigned short Bs[32*192];

    const bf16x8 qa = *reinterpret_cast<const bf16x8*>(
        Qb + (size_t)(b*1024 + p0 + ph*16 + l15)*32 + g*8);

    // T14: hT tile load issued at entry, held in regs through the loop
    const int hrow = t>>3, hoct = t&7;
    const ushort8 hreg = *reinterpret_cast<const ushort8*>(
        hT + (size_t)(b*1024 + p0 + hrow)*64 + hoct*8);

    float m_run = -1e30f, l_run = 0.0f;
    f32x4 acc[4];
#pragma unroll
    for (int cf=0;cf<4;cf++) acc[cf] = (f32x4){0.f,0.f,0.f,0.f};

    const int krow = t>>2, koct = t&3;
    const int vrow = t>>3, voct = t&7;
    const unsigned kwb  = (unsigned)(krow*80 + koct*16);
    const unsigned vwb0 = (unsigned)(vrow*128)      + (((unsigned)voct*16) ^ ((unsigned)(vrow&7)<<4));
    const unsigned vwb1 = (unsigned)((vrow+32)*128) + (((unsigned)voct*16) ^ ((unsigned)((vrow+32)&7)<<4));

    ushort8 kr0, kr1, vv0, vv1, vv2, vv3;
#define LDSTAGE(Q0N) do { \
        kr0 = *reinterpret_cast<const ushort8*>(Kh + (size_t)(b*1024 + (Q0N) + krow)*32 + koct*8); \
        kr1 = *reinterpret_cast<const ushort8*>(Km + (size_t)(b*1024 + (Q0N) + krow)*32 + koct*8); \
        vv0 = *reinterpret_cast<const ushort8*>(Vh + (size_t)(b*64 + vrow)*1024 + (Q0N) + voct*8); \
        vv1 = *reinterpret_cast<const ushort8*>(Vh + (size_t)(b*64 + vrow+32)*1024 + (Q0N) + voct*8); \
        vv2 = *reinterpret_cast<const ushort8*>(Vm + (size_t)(b*64 + vrow)*1024 + (Q0N) + voct*8); \
        vv3 = *reinterpret_cast<const ushort8*>(Vm + (size_t)(b*64 + vrow+32)*1024 + (Q0N) + voct*8); \
    } while(0)
#define WRSTAGE(BUF) do { \
        *reinterpret_cast<ushort8*>(reinterpret_cast<char*>(Kt[0][BUF]) + kwb)  = kr0; \
        *reinterpret_cast<ushort8*>(reinterpret_cast<char*>(Kt[1][BUF]) + kwb)  = kr1; \
        *reinterpret_cast<ushort8*>(reinterpret_cast<char*>(Vt[0][BUF]) + vwb0) = vv0; \
        *reinterpret_cast<ushort8*>(reinterpret_cast<char*>(Vt[0][BUF]) + vwb1) = vv1; \
        *reinterpret_cast<ushort8*>(reinterpret_cast<char*>(Vt[1][BUF]) + vwb0) = vv2; \
        *reinterpret_cast<ushort8*>(reinterpret_cast<char*>(Vt[1][BUF]) + vwb1) = vv3; \
    } while(0)

    LDSTAGE(0);
    WRSTAGE(0);
    __syncthreads();

    const unsigned prow = (unsigned)(ph*16 + l15);
    const unsigned psw  = (prow & 7u) << 4;
    char* Pbase = reinterpret_cast<char*>(Pt[pass]);

    for (int it=0; it<16; ++it){
        const int cur = it & 1;
        if (it < 15) LDSTAGE((it+1)*64);

        f32x4 s2[4];
        __builtin_amdgcn_s_setprio(1);
#pragma unroll
        for (int qt=0; qt<4; qt++){
            const bf16x8 kb = *reinterpret_cast<const bf16x8*>(
                reinterpret_cast<const char*>(Kt[pass][cur]) + (qt*16 + l15)*80 + g*16);
            s2[qt] = __builtin_amdgcn_mfma_f32_16x16x32_bf16(kb, qa, (f32x4){0.f,0.f,0.f,0.f}, 0,0,0);
        }
        __builtin_amdgcn_s_setprio(0);

        float pm = s2[0][0];
#pragma unroll
        for (int qt=0; qt<4; qt++)
#pragma unroll
            for (int r=0;r<4;r++) pm = fmaxf(pm, s2[qt][r]);
        pm = fmaxf(pm, __shfl_xor(pm, 16));
        pm = fmaxf(pm, __shfl_xor(pm, 32));

        if (!__all(pm <= m_run + 8.0f)){
            float mn = fmaxf(m_run, pm);
            float f  = __expf(m_run - mn);
            m_run = mn;
            l_run *= f;
#pragma unroll
            for (int r=0;r<4;r++){
                float fr = __shfl(f, (l & 48) | ((l>>4)*4 + r), 64);
#pragma unroll
                for (int cf=0;cf<4;cf++) acc[cf][r] *= fr;
            }
        }

        float e[4][4];
        float lsum = 0.f;
#pragma unroll
        for (int qt=0; qt<4; qt++)
#pragma unroll
            for (int r=0;r<4;r++){
                float ev = __expf(s2[qt][r] - m_run);
                e[qt][r] = ev;
                lsum += ev;
            }
        lsum += __shfl_xor(lsum, 16);
        lsum += __shfl_xor(lsum, 32);
        l_run += lsum;

#pragma unroll
        for (int qt=0; qt<4; qt++){
            uint2v pk;
            pk.x = cvt_pk_bf16(e[qt][0], e[qt][1]);
            pk.y = cvt_pk_bf16(e[qt][2], e[qt][3]);
            unsigned byte = prow*128 + (((unsigned)(qt*32 + g*8)) ^ psw);
            *reinterpret_cast<uint2v*>(Pbase + byte) = pk;
        }

        __builtin_amdgcn_s_setprio(1);
#pragma unroll
        for (int ks=0;ks<2;ks++){
            unsigned abyte = prow*128 + (((unsigned)(ks*64 + g*16)) ^ psw);
            const bf16x8 pa = *reinterpret_cast<const bf16x8*>(Pbase + abyte);
#pragma unroll
            for (int cf=0;cf<4;cf++){
                unsigned vrw = (unsigned)(cf*16 + l15);
                unsigned vbyte = vrw*128 + (((unsigned)(ks*64 + g*16)) ^ ((vrw&7u)<<4));
                const bf16x8 vb = *reinterpret_cast<const bf16x8*>(
                    reinterpret_cast<const char*>(Vt[pass][cur]) + vbyte);
                acc[cf] = __builtin_amdgcn_mfma_f32_16x16x32_bf16(pa, vb, acc[cf], 0,0,0);
            }
        }
        __builtin_amdgcn_s_setprio(0);

        if (it < 15) WRSTAGE(cur^1);
        __syncthreads();
    }
#undef LDSTAGE
#undef WRSTAGE

    {
        float rl = 1.0f / l_run;
        float rr[4];
#pragma unroll
        for (int r=0;r<4;r++) rr[r] = __shfl(rl, (l & 48) | ((l>>4)*4 + r), 64);
#pragma unroll
        for (int cf=0;cf<4;cf++)
#pragma unroll
            for (int r=0;r<4;r++){
                unsigned pix = (unsigned)(ph*16 + g*4 + r);
                unsigned cch = (unsigned)(pass*64 + cf*16 + l15);
                unsigned byte = pix*384 + ((cch*2) ^ ((pix&7u)<<4));
                *reinterpret_cast<unsigned short*>(reinterpret_cast<char*>(Bs) + byte)
                    = f2bf(acc[cf][r]*rr[r]);
            }
    }
    {   // write the register-held hT tile
        unsigned byte = (unsigned)(hrow*384) + 256u + (((unsigned)hoct*16) ^ ((unsigned)(hrow&7)<<4));
        *reinterpret_cast<ushort8*>(reinterpret_cast<char*>(Bs) + byte) = hreg;
    }
    __syncthreads();

    f32x4 acc1[2][2];
#pragma unroll
    for (int i=0;i<2;i++)
#pragma unroll
        for (int cf=0;cf<2;cf++) acc1[i][cf] = (f32x4){0.f,0.f,0.f,0.f};
#pragma unroll
    for (int ks=0; ks<4; ++ks){
        bf16x8 af[2];
#pragma unroll
        for (int i=0;i<2;i++)
            af[i] = *reinterpret_cast<const bf16x8*>(
                wzb + (size_t)(w*32 + i*16 + l15)*128 + ks*32 + g*8);
        __builtin_amdgcn_s_setprio(1);
#pragma unroll
        for (int cf=0;cf<2;cf++){
            unsigned p = (unsigned)(cf*16 + l15);
            unsigned byte = p*384 + (((unsigned)(ks*64 + g*16)) ^ ((p&7u)<<4));
            const bf16x8 bfr = *reinterpret_cast<const bf16x8*>(
                reinterpret_cast<const char*>(Bs) + byte);
            acc1[0][cf] = __builtin_amdgcn_mfma_f32_16x16x32_bf16(af[0], bfr, acc1[0][cf], 0,0,0);
            acc1[1][cf] = __builtin_amdgcn_mfma_f32_16x16x32_bf16(af[1], bfr, acc1[1][cf], 0,0,0);
        }
        __builtin_amdgcn_s_setprio(0);
    }
    __syncthreads();
#pragma unroll
    for (int i=0;i<2;i++){
        int co = w*32 + i*16 + g*4;
#pragma unroll
        for (int cf=0;cf<2;cf++){
            unsigned p = (unsigned)(cf*16 + l15);
#pragma unroll
            for (int r=0;r<4;r++){
                float val = acc1[i][cf][r] + bz[co+r];
                unsigned byte = p*384 + (((unsigned)((co+r)*2)) ^ ((p&7u)<<4));
                *reinterpret_cast<unsigned short*>(reinterpret_cast<char*>(Bs) + byte) = f2bf(val);
            }
        }
    }
    __syncthreads();

    f32x4 acc2[3][2];
#pragma unroll
    for (int j=0;j<3;j++)
#pragma unroll
        for (int cf=0;cf<2;cf++) acc2[j][cf] = (f32x4){0.f,0.f,0.f,0.f};
#pragma unroll
    for (int ks=0; ks<6; ++ks){
        bf16x8 am[3];
#pragma unroll
        for (int j=0;j<3;j++)
            am[j] = *reinterpret_cast<const bf16x8*>(
                wmb + (size_t)(j*64 + w*16 + l15)*192 + ks*32 + g*8);
        __builtin_amdgcn_s_setprio(1);
#pragma unroll
        for (int cf=0;cf<2;cf++){
            unsigned p = (unsigned)(cf*16 + l15);
            unsigned byte = p*384 + (((unsigned)(ks*64 + g*16)) ^ ((p&7u)<<4));
            const bf16x8 bfr = *reinterpret_cast<const bf16x8*>(
                reinterpret_cast<const char*>(Bs) + byte);
#pragma unroll
            for (int j=0;j<3;j++)
                acc2[j][cf] = __builtin_amdgcn_mfma_f32_16x16x32_bf16(am[j], bfr, acc2[j][cf], 0,0,0);
        }
        __builtin_amdgcn_s_setprio(0);
    }

    const int ch0 = w*16 + g*4;
#pragma unroll
    for (int cf=0;cf<2;cf++){
        int pix = p0 + cf*16 + l15;
#pragma unroll
        for (int r=0;r<4;r++){
            int ch = ch0 + r;
            float mo = acc2[0][cf][r] + bm[ch];
            float mg = acc2[1][cf][r] + bm[64+ch];
            float mi = sigmoidf_(acc2[2][cf][r] + bm[128+ch]);
            float mv = m_in[(size_t)(b*64+ch)*1024 + pix];
            float mn = (1.0f - mi)*mv + mi*tanhf_(mg);
            out_m[(size_t)(b*64+ch)*1024 + pix] = mn;
            out_h[(size_t)(b*64+ch)*1024 + pix] = sigmoidf_(mo)*mn;
        }
    }
}

extern "C" void kernel_launch(void* const* d_in, const int* in_sizes, int n_in,
                              void* d_out, int out_size, void* d_ws, size_t ws_size,
                              hipStream_t stream)
{
    const float* x      = (const float*)d_in[0];
    const float* h      = (const float*)d_in[1];
    const float* c      = (const float*)d_in[2];
    const float* m      = (const float*)d_in[3];
    const float* lc     = (const float*)d_in[4];
    const float* conv_w = (const float*)d_in[5];
    const float* conv_b = (const float*)d_in[6];
    const float* gn1_w  = (const float*)d_in[7];
    const float* gn1_b  = (const float*)d_in[8];
    const float* convL_w= (const float*)d_in[9];
    const float* convL_b= (const float*)d_in[10];
    const float* gn2_w  = (const float*)d_in[11];
    const float* gn2_b  = (const float*)d_in[12];
    const float* wq  = (const float*)d_in[13];
    const float* bq  = (const float*)d_in[14];
    const float* wk  = (const float*)d_in[15];
    const float* bk  = (const float*)d_in[16];
    const float* wk2 = (const float*)d_in[17];
    const float* bk2 = (const float*)d_in[18];
    const float* wv  = (const float*)d_in[19];
    const float* bv  = (const float*)d_in[20];
    const float* wv2 = (const float*)d_in[21];
    const float* bv2 = (const float*)d_in[22];
    const float* wz  = (const float*)d_in[23];
    const float* bz  = (const float*)d_in[24];
    const float* wmw = (const float*)d_in[25];
    const float* bm  = (const float*)d_in[26];

    float* out = (float*)d_out;
    float* F = (float*)d_ws;
    unsigned short* cc_bf  = (unsigned short*)F;              // [16][256][1024] bf16
    unsigned short* buf1   = (unsigned short*)(F + 2097152);  // padded [16][1156][128]
    unsigned short* buf2   = (unsigned short*)(F + 3280896);  // padded
    unsigned short* hT     = (unsigned short*)(F + 4464640);  // [16][1024][64]
    unsigned short* Qb     = (unsigned short*)(F + 4988928);
    unsigned short* Khb    = (unsigned short*)(F + 5251072);
    unsigned short* Kmb    = (unsigned short*)(F + 5513216);
    unsigned short* Vhb    = (unsigned short*)(F + 5775360);
    unsigned short* Vmb    = (unsigned short*)(F + 6299648);
    unsigned short* sig_pm = (unsigned short*)(F + 6823936);  // [16][1024][64]
    unsigned short* wpk1   = (unsigned short*)(F + 7348224);
    unsigned short* wpk2   = (unsigned short*)(F + 7495680);
    unsigned short* wzb    = (unsigned short*)(F + 7643136);
    unsigned short* wmb    = (unsigned short*)(F + 7651328);
    unsigned short* wph    = (unsigned short*)(F + 7669760);
    unsigned short* wpm    = (unsigned short*)(F + 7673856);
    float*          statsS = F + 7676928;                     // [16][8][256] f32
    float*          statsQ = F + 7709696;                     // [16][8][256] f32

    dim3 blk256(256);
    prep_kernel<<<dim3(1440), blk256, 0, stream>>>(conv_w, convL_w, wz, wmw,
                                                   wq, wk, wv, wk2, wv2, x, h,
                                                   wpk1, wpk2, wzb, wmb, wph, wpm,
                                                   buf1, buf2);
    conv_mfma_kernel<<<dim3(512), blk256, 0, stream>>>(buf1, wpk1, conv_b, cc_bf, statsS, statsQ);
    gn_gate1_kernel<<<dim3(512), blk256, 0, stream>>>(cc_bf, statsS, statsQ, gn1_w, gn1_b, c,
                                                      buf2, sig_pm);
    conv_mfma_kernel<<<dim3(512), blk256, 0, stream>>>(buf2, wpk2, convL_b, cc_bf, statsS, statsQ);
    gn2_proj_kernel<<<dim3(512), blk256, 0, stream>>>(cc_bf, statsS, statsQ, gn2_w, gn2_b,
                                                      lc, sig_pm, m, wph, wpm,
                                                      bq, bk, bv, bk2, bv2,
                                                      out + 3*1048576 /*lc_next*/,
                                                      out + 1*1048576 /*c_next*/,
                                                      hT, Qb, Khb, Kmb, Vhb, Vmb);
    attn_final_kernel<<<dim3(512), blk256, 0, stream>>>(Qb, Khb, Kmb, Vhb, Vmb, hT,
                                                        wzb, wmb, bz, bm, m,
                                                        out /*h_next*/, out + 2*1048576 /*m_next*/);
    (void)in_sizes; (void)n_in; (void)out_size; (void)ws_size;
}

// Round 13
// 103.774 us; speedup vs baseline: 1.4549x; 1.0019x over previous
//
#include <hip/hip_runtime.h>

#define DEV __device__ __forceinline__

typedef __attribute__((ext_vector_type(8))) __bf16 bf16x8;
typedef __attribute__((ext_vector_type(4))) float f32x4;
typedef __attribute__((ext_vector_type(8))) unsigned short ushort8;
typedef __attribute__((ext_vector_type(2))) unsigned short ushort2v;
typedef __attribute__((ext_vector_type(2))) unsigned int uint2v;

DEV float sigmoidf_(float x){ return 1.0f/(1.0f + __expf(-x)); }
DEV float tanhf_(float x){
    x = fminf(15.0f, fmaxf(-15.0f, x));
    float e = __expf(2.0f*x);
    return (e - 1.0f)/(e + 1.0f);
}
DEV unsigned short f2bf(float f){
    unsigned u = __builtin_bit_cast(unsigned, f);
    unsigned r = (u + 0x7FFFu + ((u>>16)&1u)) >> 16;
    return (unsigned short)r;
}
DEV float bf2f(unsigned short u){
    return __builtin_bit_cast(float, ((unsigned)u)<<16);
}
DEV unsigned cvt_pk_bf16(float lo, float hi){
    unsigned r;
    asm("v_cvt_pk_bf16_f32 %0, %1, %2" : "=v"(r) : "v"(lo), "v"(hi));
    return r;
}

// ---------- merged prep: weights -> bf16 packs ; pack x,h -> PADDED buf1/buf2 ----------
__global__ __launch_bounds__(256)
void prep_kernel(const float* __restrict__ conv_w, const float* __restrict__ convL_w,
                 const float* __restrict__ wz, const float* __restrict__ wm,
                 const float* __restrict__ wq, const float* __restrict__ wk,
                 const float* __restrict__ wv, const float* __restrict__ wk2,
                 const float* __restrict__ wv2,
                 const float* __restrict__ x, const float* __restrict__ h,
                 unsigned short* __restrict__ wpk1, unsigned short* __restrict__ wpk2,
                 unsigned short* __restrict__ wzb, unsigned short* __restrict__ wmb,
                 unsigned short* __restrict__ wph, unsigned short* __restrict__ wpm,
                 unsigned short* __restrict__ buf1, unsigned short* __restrict__ buf2)
{
    __shared__ float tile[128][65];
    if (blockIdx.x < 1152) {
        int oidx = blockIdx.x*256 + threadIdx.x;
        {
            int ci5 = oidx & 31;
            int co  = (oidx >> 5) & 255;
            int kch = oidx >> 13;
            int cic = kch / 9, tap = kch - 9*cic;
            int src = co*1152 + (cic*32 + ci5)*9 + tap;
            wpk1[oidx] = f2bf(conv_w[src]);
            wpk2[oidx] = f2bf(convL_w[src]);
        }
        if (oidx < 128*128) wzb[oidx] = f2bf(wz[oidx]);
        if (oidx < 192*192) wmb[oidx] = f2bf(wm[oidx]);
        if (oidx < 32*64){
            wph[oidx]        = f2bf(wq[oidx]);
            wph[2048 + oidx] = f2bf(wk[oidx]);
            wpm[oidx]        = f2bf(wk2[oidx]);
        }
        if (oidx < 64*64){
            wph[4096 + oidx] = f2bf(wv[oidx]);
            wpm[2048 + oidx] = f2bf(wv2[oidx]);
        }
    } else if (blockIdx.x < 1184) {
        int bx2 = blockIdx.x - 1152;
        int b = bx2 >> 1;
        unsigned short* buf = (bx2 & 1) ? buf2 : buf1;
        for (int i = threadIdx.x; i < 8448; i += 256){
            int px = i >> 6, u = i & 63;
            int rr, cc2;
            if (px < 34)      { rr = 0;         cc2 = px; }
            else if (px < 68) { rr = 33;        cc2 = px-34; }
            else if (px < 100){ rr = px-68+1;   cc2 = 0; }
            else              { rr = px-100+1;  cc2 = 33; }
            reinterpret_cast<unsigned*>(buf + (size_t)(b*1156 + rr*34 + cc2)*128)[u] = 0u;
        }
    } else {
        int i  = blockIdx.x - 1184;
        int b  = (i&7)*2 + ((i>>3)&1);
        int p0 = (i>>4) * 64;
        int t  = threadIdx.x;
        for (int k=t;k<8192;k+=256){
            int ci = k>>6, pp = k&63;
            const float* s = (ci<64) ? x + (size_t)(b*64+ci)*1024
                                     : h + (size_t)(b*64+ci-64)*1024;
            tile[ci][pp] = s[p0+pp];
        }
        __syncthreads();
        for (int k=t;k<4096;k+=256){
            int pp = k>>6, c2 = k&63;
            int p  = p0 + pp;
            size_t pidx = (size_t)(b*1156 + ((p>>5)+1)*34 + (p&31) + 1);
            ushort2v v;
            v.x = f2bf(tile[c2*2][pp]);
            v.y = f2bf(tile[c2*2+1][pp]);
            *reinterpret_cast<ushort2v*>(buf1 + pidx*128 + c2*2) = v;
            if (c2 >= 32)
                *reinterpret_cast<ushort2v*>(buf2 + pidx*128 + (c2-32)*2) = v;
        }
    }
}

// ---------- implicit-GEMM 3x3 conv via MFMA: A-ring-6 / B-ring-3 ----------
__global__ __launch_bounds__(256, 2)
void conv_mfma_kernel(const unsigned short* __restrict__ inp,
                      const unsigned short* __restrict__ wpk,
                      const float* __restrict__ bias,
                      unsigned short* __restrict__ out,
                      float* __restrict__ statsS, float* __restrict__ statsQ)
{
    const int bid = blockIdx.x;
    const int b   = (bid&7)*2 + ((bid>>3)&1);
    const int co0 = ((bid>>4)&3) * 64;
    const int rt  = bid>>6;
    const int r0  = rt * 4;
    const int t   = threadIdx.x;
    const int l   = t & 63;
    const int wv  = t >> 6;
    const int l15 = l & 15;
    const int lhi = l >> 4;

    __shared__ __align__(16) unsigned short in_t[26112];

    {
        const char* gsrc = reinterpret_cast<const char*>(inp + (size_t)(b*1156 + r0*34)*128);
#pragma unroll
        for (int it = 0; it < 13; ++it){
            unsigned lbase = (unsigned)(it*4096 + wv*1024);
            if (lbase < 52224u){
                unsigned beta = lbase + (unsigned)l*16u;
                unsigned soff = (beta & ~255u) + ((beta & 0xF0u) ^ (((beta>>8)&7u)<<4));
                __builtin_amdgcn_global_load_lds(
                    (const __attribute__((address_space(1))) void*)(gsrc + soff),
                    (__attribute__((address_space(3))) void*)(
                        (__attribute__((address_space(3))) char*)in_t + lbase),
                    16, 0, 0);
            }
        }
    }

    f32x4 acc[4][2];
#pragma unroll
    for (int i=0;i<4;i++)
#pragma unroll
        for (int f=0;f<2;f++)
            acc[i][f] = (f32x4){0.f,0.f,0.f,0.f};

    bf16x8 areg[6][4], breg[3][2];
#define LDA_(K, SLOT) do { const unsigned short* wrow_ = wpk + ((K)*256 + co0)*32; \
        for (int i_=0;i_<4;i_++) areg[SLOT][i_] = *reinterpret_cast<const bf16x8*>(wrow_ + (i_*16 + l15)*32 + lhi*8); } while(0)
#define LDB_(K, SLOT) do { const int cic_ = (K)/9, tap_ = (K) - 9*((K)/9); \
        const int ky_ = tap_/3, kx_ = tap_ - 3*(tap_/3); \
        for (int f_=0;f_<2;f_++){ int pl_ = (wv + ky_)*34 + (f_*16 + l15 + kx_); \
            unsigned by_ = (unsigned)(pl_*256 + cic_*64 + lhi*16) ^ (((unsigned)pl_ & 7u) << 4); \
            breg[SLOT][f_] = *reinterpret_cast<const bf16x8*>(reinterpret_cast<const char*>(in_t) + by_); } } while(0)

    LDA_(0, 0); LDA_(1, 1); LDA_(2, 2); LDA_(3, 3); LDA_(4, 4);
    __syncthreads();
    LDB_(0, 0); LDB_(1, 1);
#pragma unroll
    for (int k=0; k<36; ++k){
        const int as = k % 6, bs = k % 3;
        if (k+5 < 36) LDA_(k+5, (k+5)%6);
        if (k+2 < 36) LDB_(k+2, (k+2)%3);
        __builtin_amdgcn_s_setprio(1);
#pragma unroll
        for (int i=0;i<4;i++){
            acc[i][0] = __builtin_amdgcn_mfma_f32_16x16x32_bf16(areg[as][i], breg[bs][0], acc[i][0], 0,0,0);
            acc[i][1] = __builtin_amdgcn_mfma_f32_16x16x32_bf16(areg[as][i], breg[bs][1], acc[i][1], 0,0,0);
        }
        __builtin_amdgcn_s_setprio(0);
    }
#undef LDA_
#undef LDB_

    __syncthreads();
    float* red = reinterpret_cast<float*>(in_t);

    const int orow = r0 + wv;
    float s_ir[4][4], q_ir[4][4];
#pragma unroll
    for (int i=0;i<4;i++){
        int cobase = co0 + i*16 + lhi*4;
#pragma unroll
        for (int r=0;r<4;r++){
            float bs = bias[cobase+r];
            float e0 = acc[i][0][r] + bs;
            float e1 = acc[i][1][r] + bs;
            out[(size_t)(b*256 + cobase + r)*1024 + orow*32 + l15]      = f2bf(e0);
            out[(size_t)(b*256 + cobase + r)*1024 + orow*32 + 16 + l15] = f2bf(e1);
            s_ir[i][r] = e0 + e1;
            q_ir[i][r] = e0*e0 + e1*e1;
        }
    }
#pragma unroll
    for (int i=0;i<4;i++)
#pragma unroll
        for (int r=0;r<4;r++){
            float s = s_ir[i][r], q = q_ir[i][r];
            s += __shfl_xor(s,1); q += __shfl_xor(q,1);
            s += __shfl_xor(s,2); q += __shfl_xor(q,2);
            s += __shfl_xor(s,4); q += __shfl_xor(q,4);
            s += __shfl_xor(s,8); q += __shfl_xor(q,8);
            s_ir[i][r] = s; q_ir[i][r] = q;
        }
    if (l15 == 0){
#pragma unroll
        for (int i=0;i<4;i++)
#pragma unroll
            for (int r=0;r<4;r++){
                red[wv*64 + i*16 + lhi*4 + r]       = s_ir[i][r];
                red[256 + wv*64 + i*16 + lhi*4 + r] = q_ir[i][r];
            }
    }
    __syncthreads();
    if (t < 64){
        float S = red[t]+red[64+t]+red[128+t]+red[192+t];
        float Q = red[256+t]+red[320+t]+red[384+t]+red[448+t];
        statsS[((size_t)b*8 + rt)*256 + co0 + t] = S;
        statsQ[((size_t)b*8 + rt)*256 + co0 + t] = Q;
    }
}

// ---------- GN gate1, 32-pixel tiles (XCD-swizzled grid) ----------
__global__ __launch_bounds__(256)
void gn_gate1_kernel(const unsigned short* __restrict__ cc,
                     const float* __restrict__ statsS, const float* __restrict__ statsQ,
                     const float* __restrict__ gnw, const float* __restrict__ gnb,
                     const float* __restrict__ c_in,
                     unsigned short* __restrict__ buf2, unsigned short* __restrict__ sig_pm)
{
    const int bid = blockIdx.x;
    const int b   = (bid&7)*2 + ((bid>>3)&1);
    const int p0  = (bid>>4) * 32;
    const int t  = threadIdx.x;
    __shared__ float sc[256][2];
    __shared__ __align__(16) unsigned short cct[10240];

    {
        float S=0.f, Q=0.f;
#pragma unroll
        for (int part=0; part<8; ++part){
            S += statsS[((size_t)b*8 + part)*256 + t];
            Q += statsQ[((size_t)b*8 + part)*256 + t];
        }
        float mu  = S*(1.0f/1024.0f);
        float var = Q*(1.0f/1024.0f) - mu*mu;
        float rs  = rsqrtf(var + 1e-5f);
        float gw  = gnw[t];
        sc[t][0] = rs*gw;
        sc[t][1] = gnb[t] - mu*rs*gw;
    }
    for (int it=t; it<1024; it+=256){
        int row = it>>2, oct = it&3;
        ushort8 v = *reinterpret_cast<const ushort8*>(
            cc + (size_t)(b*256+row)*1024 + p0 + oct*8);
        *reinterpret_cast<ushort8*>(cct + row*40 + oct*8) = v;
    }
    __syncthreads();

    const int p = t & 31, cg = t >> 5;
    float cn[8], so[8];
#pragma unroll
    for (int j=0;j<8;j++){
        int ch = cg*8 + j;
        float xg[4];
#pragma unroll
        for (int g=0; g<4; g++){
            int row = g*64 + ch;
            float v = bf2f(cct[row*40 + p]);
            xg[g] = v*sc[row][0] + sc[row][1];
        }
        float cv = c_in[(size_t)(b*64+ch)*1024 + p0 + p];
        cn[j] = sigmoidf_(xg[1])*cv + sigmoidf_(xg[0])*tanhf_(xg[3]);
        so[j] = sigmoidf_(xg[2]);
    }
    ushort8 v0, s0;
#pragma unroll
    for (int j=0;j<8;j++){ v0[j]=f2bf(cn[j]); s0[j]=f2bf(so[j]); }
    int pg = p0 + p;
    size_t pidx = (size_t)(b*1156 + ((pg>>5)+1)*34 + (pg&31) + 1);
    *reinterpret_cast<ushort8*>(buf2 + pidx*128 + 64 + cg*8) = v0;
    *reinterpret_cast<ushort8*>(sig_pm + (size_t)(b*1024 + pg)*64 + cg*8) = s0;
}

// ---------- GN gate2 + projections fused, 32-pixel tiles (XCD-swizzled grid) ----------
__global__ __launch_bounds__(256)
void gn2_proj_kernel(const unsigned short* __restrict__ cc,
                     const float* __restrict__ statsS, const float* __restrict__ statsQ,
                     const float* __restrict__ gnw, const float* __restrict__ gnb,
                     const float* __restrict__ lc_in, const unsigned short* __restrict__ sig_pm,
                     const float* __restrict__ m_in,
                     const unsigned short* __restrict__ wph, const unsigned short* __restrict__ wpm,
                     const float* __restrict__ bq, const float* __restrict__ bk,
                     const float* __restrict__ bv, const float* __restrict__ bk2,
                     const float* __restrict__ bv2,
                     float* __restrict__ out_lc, float* __restrict__ out_c,
                     unsigned short* __restrict__ hT,
                     unsigned short* __restrict__ Qb, unsigned short* __restrict__ Khb,
                     unsigned short* __restrict__ Kmb,
                     unsigned short* __restrict__ Vhb, unsigned short* __restrict__ Vmb)
{
    const int bid = blockIdx.x;
    const int b   = (bid&7)*2 + ((bid>>3)&1);
    const int p0  = (bid>>4) * 32;
    const int t  = threadIdx.x;
    const int l  = t & 63;
    const int w  = t >> 6;
    const int l15 = l & 15, lhi = l >> 4;

    __shared__ float sc[256][2];
    __shared__ __align__(16) unsigned short cct[10240];

    {
        float S=0.f, Q=0.f;
#pragma unroll
        for (int part=0; part<8; ++part){
            S += statsS[((size_t)b*8 + part)*256 + t];
            Q += statsQ[((size_t)b*8 + part)*256 + t];
        }
        float mu  = S*(1.0f/1024.0f);
        float var = Q*(1.0f/1024.0f) - mu*mu;
        float rs  = rsqrtf(var + 1e-5f);
        float gw  = gnw[t];
        sc[t][0] = rs*gw;
        sc[t][1] = gnb[t] - mu*rs*gw;
    }
    for (int it=t; it<1024; it+=256){
        int row = it>>2, oct = it&3;
        ushort8 v = *reinterpret_cast<const ushort8*>(
            cc + (size_t)(b*256+row)*1024 + p0 + oct*8);
        *reinterpret_cast<ushort8*>(cct + row*40 + oct*8) = v;
    }
    __syncthreads();

    const int p = t & 31, cg = t >> 5;
    const size_t prow = (size_t)(b*1024 + p0 + p);
    float hm[8], mr[8];
    {
        ushort8 sv = *reinterpret_cast<const ushort8*>(sig_pm + prow*64 + cg*8);
#pragma unroll
        for (int j=0;j<8;j++){
            int ch = cg*8 + j;
            float xg[4];
#pragma unroll
            for (int g=0; g<4; g++){
                int row = g*64 + ch;
                float v = bf2f(cct[row*40 + p]);
                xg[g] = v*sc[row][0] + sc[row][1];
            }
            float lv  = lc_in[(size_t)(b*64+ch)*1024 + p0 + p];
            float lcn = sigmoidf_(xg[1])*lv + sigmoidf_(xg[0])*tanhf_(xg[3]);
            float cnx = sigmoidf_(xg[2])*tanhf_(lcn);
            out_lc[(size_t)(b*64+ch)*1024 + p0 + p] = lcn;
            out_c [(size_t)(b*64+ch)*1024 + p0 + p] = cnx;
            hm[j] = bf2f(sv[j])*tanhf_(cnx);
            mr[j] = m_in[(size_t)(b*64+ch)*1024 + p0 + p];
        }
    }
    __syncthreads();

    {
        ushort8 h0, m0;
#pragma unroll
        for (int j=0;j<8;j++){ h0[j]=f2bf(hm[j]); m0[j]=f2bf(mr[j]); }
        unsigned hb = (unsigned)(p*128) + (((unsigned)(cg*16)) ^ ((unsigned)(p&7)<<4));
        *reinterpret_cast<ushort8*>(reinterpret_cast<char*>(cct) + hb) = h0;
        *reinterpret_cast<ushort8*>(reinterpret_cast<char*>(cct) + 4096 + hb) = m0;
        *reinterpret_cast<ushort8*>(hT + prow*64 + cg*8) = h0;
    }
    __syncthreads();

    const int pass = w >> 1;
    const int pix  = (w&1)*16 + l15;
    const unsigned xsw = ((unsigned)(pix&7)) << 4;
    if (pass == 0){
        f32x4 dh[8];
#pragma unroll
        for (int i=0;i<8;i++) dh[i] = (f32x4){0.f,0.f,0.f,0.f};
#pragma unroll
        for (int ks=0; ks<2; ++ks){
            unsigned xb = (unsigned)(pix*128) + (((unsigned)(ks*64 + lhi*16)) ^ xsw);
            bf16x8 xh = *reinterpret_cast<const bf16x8*>(reinterpret_cast<const char*>(cct) + xb);
            __builtin_amdgcn_s_setprio(1);
#pragma unroll
            for (int ocf=0; ocf<8; ocf++){
                bf16x8 af = *reinterpret_cast<const bf16x8*>(
                    wph + (size_t)(ocf*16 + l15)*64 + ks*32 + lhi*8);
                dh[ocf] = __builtin_amdgcn_mfma_f32_16x16x32_bf16(af, xh, dh[ocf], 0,0,0);
            }
            __builtin_amdgcn_s_setprio(0);
        }
#pragma unroll
        for (int ocf=0; ocf<4; ocf++)
#pragma unroll
            for (int r=0;r<4;r++){
                int vc = ocf*16 + lhi*4 + r;
                Vhb[(size_t)(b*64+vc)*1024 + p0 + pix] = f2bf(dh[4+ocf][r] + bv[vc]);
            }
#pragma unroll
        for (int ocf=0; ocf<2; ocf++)
#pragma unroll
            for (int r=0;r<4;r++){
                int qc = ocf*16 + lhi*4 + r;
                unsigned byq = (unsigned)(pix*128) + (((unsigned)(qc*2))      ^ xsw);
                unsigned byk = (unsigned)(pix*128) + (((unsigned)(64 + qc*2)) ^ xsw);
                *reinterpret_cast<unsigned short*>(reinterpret_cast<char*>(cct) + 8192 + byq)
                    = f2bf(dh[ocf][r]   + bq[qc]);
                *reinterpret_cast<unsigned short*>(reinterpret_cast<char*>(cct) + 8192 + byk)
                    = f2bf(dh[2+ocf][r] + bk[qc]);
            }
    } else {
        f32x4 dm[6];
#pragma unroll
        for (int i=0;i<6;i++) dm[i] = (f32x4){0.f,0.f,0.f,0.f};
#pragma unroll
        for (int ks=0; ks<2; ++ks){
            unsigned xb = (unsigned)(pix*128) + (((unsigned)(ks*64 + lhi*16)) ^ xsw);
            bf16x8 xm = *reinterpret_cast<const bf16x8*>(
                reinterpret_cast<const char*>(cct) + 4096 + xb);
            __builtin_amdgcn_s_setprio(1);
#pragma unroll
            for (int ocf=0; ocf<6; ocf++){
                bf16x8 am = *reinterpret_cast<const bf16x8*>(
                    wpm + (size_t)(ocf*16 + l15)*64 + ks*32 + lhi*8);
                dm[ocf] = __builtin_amdgcn_mfma_f32_16x16x32_bf16(am, xm, dm[ocf], 0,0,0);
            }
            __builtin_amdgcn_s_setprio(0);
        }
#pragma unroll
        for (int ocf=0; ocf<4; ocf++)
#pragma unroll
            for (int r=0;r<4;r++){
                int vc = ocf*16 + lhi*4 + r;
                Vmb[(size_t)(b*64+vc)*1024 + p0 + pix] = f2bf(dm[2+ocf][r] + bv2[vc]);
            }
#pragma unroll
        for (int ocf=0; ocf<2; ocf++)
#pragma unroll
            for (int r=0;r<4;r++){
                int qc = ocf*16 + lhi*4 + r;
                unsigned byq = (unsigned)(pix*128) + (((unsigned)(qc*2)) ^ xsw);
                *reinterpret_cast<unsigned short*>(reinterpret_cast<char*>(cct) + 12288 + byq)
                    = f2bf(dm[ocf][r] + bk2[qc]);
            }
    }
    __syncthreads();

    {
        int pr = t>>3, oct = t&7;
        unsigned byte = (unsigned)(pr*128) + (((unsigned)(oct*16)) ^ ((unsigned)(pr&7)<<4));
        ushort8 v = *reinterpret_cast<const ushort8*>(
            reinterpret_cast<const char*>(cct) + 8192 + byte);
        if (oct < 4) *reinterpret_cast<ushort8*>(Qb  + (size_t)(b*1024+p0+pr)*32 + oct*8) = v;
        else         *reinterpret_cast<ushort8*>(Khb + (size_t)(b*1024+p0+pr)*32 + (oct-4)*8) = v;
    }
    if (t < 128){
        int pr = t>>2, oct = t&3;
        unsigned byte = (unsigned)(pr*128) + (((unsigned)(oct*16)) ^ ((unsigned)(pr&7)<<4));
        ushort8 v = *reinterpret_cast<const ushort8*>(
            reinterpret_cast<const char*>(cct) + 12288 + byte);
        *reinterpret_cast<ushort8*>(Kmb + (size_t)(b*1024+p0+pr)*32 + oct*8) = v;
    }
}

// ---------- fused attention + final mix: 256 blocks x 512 threads, 64 px/block ----------
__global__ __launch_bounds__(512)
void attn_final_kernel(const unsigned short* __restrict__ Qb,
                       const unsigned short* __restrict__ Kh,
                       const unsigned short* __restrict__ Km,
                       const unsigned short* __restrict__ Vh,
                       const unsigned short* __restrict__ Vm,
                       const unsigned short* __restrict__ hT,
                       const unsigned short* __restrict__ wzb,
                       const unsigned short* __restrict__ wmb,
                       const float* __restrict__ bz, const float* __restrict__ bm,
                       const float* __restrict__ m_in,
                       float* __restrict__ out_h, float* __restrict__ out_m)
{
    const int bid  = blockIdx.x;
    const int b    = (bid&7)*2 + ((bid>>3)&1);
    const int p0   = (bid>>4) * 64;
    const int t   = threadIdx.x;
    const int l   = t & 63;
    const int w   = t >> 6;            // 0..7
    const int l15 = l & 15, g = l >> 4;
    const int pass = w >> 2;           // waves 0-3: h, 4-7: m
    const int wq   = w & 3;            // 16-px slice within the 64-px tile

    __shared__ __align__(16) unsigned short Kt[2][2][2560];
    __shared__ __align__(16) unsigned short Vt[2][2][4096];
    __shared__ __align__(16) unsigned short Pt[2][4096];     // [pass][64px x 64q] swz
    __shared__ __align__(16) unsigned short Bs[64*192];

    const bf16x8 qa = *reinterpret_cast<const bf16x8*>(
        Qb + (size_t)(b*1024 + p0 + wq*16 + l15)*32 + g*8);

    // T14: hT tile (64 rows x 8 octs = 512 slots) held in regs through the loop
    const int hrow = t>>3, hoct = t&7;
    const ushort8 hreg = *reinterpret_cast<const ushort8*>(
        hT + (size_t)(b*1024 + p0 + hrow)*64 + hoct*8);

    float m_run = -1e30f, l_run = 0.0f;
    f32x4 acc[4];
#pragma unroll
    for (int cf=0;cf<4;cf++) acc[cf] = (f32x4){0.f,0.f,0.f,0.f};

    // staging: 3 loads/thread. K: tensor=t>>8, row=(t>>2)&63, oct=t&3. V: row=t>>3, oct=t&7 (both tensors).
    const int ktens = t>>8;
    const int krow  = (t>>2)&63, koct = t&3;
    const int vrow  = t>>3, voct = t&7;
    const unsigned kwb = (unsigned)(krow*80 + koct*16);
    const unsigned vwb = (unsigned)(vrow*128) + (((unsigned)voct*16) ^ ((unsigned)(vrow&7)<<4));
    const unsigned short* Kgsrc = ktens ? Km : Kh;

    ushort8 kr0, vv0, vv1;
#define LDSTAGE(Q0N) do { \
        kr0 = *reinterpret_cast<const ushort8*>(Kgsrc + (size_t)(b*1024 + (Q0N) + krow)*32 + koct*8); \
        vv0 = *reinterpret_cast<const ushort8*>(Vh + (size_t)(b*64 + vrow)*1024 + (Q0N) + voct*8); \
        vv1 = *reinterpret_cast<const ushort8*>(Vm + (size_t)(b*64 + vrow)*1024 + (Q0N) + voct*8); \
    } while(0)
#define WRSTAGE(BUF) do { \
        *reinterpret_cast<ushort8*>(reinterpret_cast<char*>(Kt[ktens][BUF]) + kwb) = kr0; \
        *reinterpret_cast<ushort8*>(reinterpret_cast<char*>(Vt[0][BUF]) + vwb) = vv0; \
        *reinterpret_cast<ushort8*>(reinterpret_cast<char*>(Vt[1][BUF]) + vwb) = vv1; \
    } while(0)

    LDSTAGE(0);
    WRSTAGE(0);
    __syncthreads();

    const unsigned prow = (unsigned)(wq*16 + l15);     // 0..63
    const unsigned psw  = (prow & 7u) << 4;
    char* Pbase = reinterpret_cast<char*>(Pt[pass]);

    for (int it=0; it<16; ++it){
        const int cur = it & 1;
        if (it < 15) LDSTAGE((it+1)*64);

        f32x4 s2[4];
        __builtin_amdgcn_s_setprio(1);
#pragma unroll
        for (int qt=0; qt<4; qt++){
            const bf16x8 kb = *reinterpret_cast<const bf16x8*>(
                reinterpret_cast<const char*>(Kt[pass][cur]) + (qt*16 + l15)*80 + g*16);
            s2[qt] = __builtin_amdgcn_mfma_f32_16x16x32_bf16(kb, qa, (f32x4){0.f,0.f,0.f,0.f}, 0,0,0);
        }
        __builtin_amdgcn_s_setprio(0);

        float pm = s2[0][0];
#pragma unroll
        for (int qt=0; qt<4; qt++)
#pragma unroll
            for (int r=0;r<4;r++) pm = fmaxf(pm, s2[qt][r]);
        pm = fmaxf(pm, __shfl_xor(pm, 16));
        pm = fmaxf(pm, __shfl_xor(pm, 32));

        if (!__all(pm <= m_run + 8.0f)){
            float mn = fmaxf(m_run, pm);
            float f  = __expf(m_run - mn);
            m_run = mn;
            l_run *= f;
#pragma unroll
            for (int r=0;r<4;r++){
                float fr = __shfl(f, (l & 48) | ((l>>4)*4 + r), 64);
#pragma unroll
                for (int cf=0;cf<4;cf++) acc[cf][r] *= fr;
            }
        }

        float e[4][4];
        float lsum = 0.f;
#pragma unroll
        for (int qt=0; qt<4; qt++)
#pragma unroll
            for (int r=0;r<4;r++){
                float ev = __expf(s2[qt][r] - m_run);
                e[qt][r] = ev;
                lsum += ev;
            }
        lsum += __shfl_xor(lsum, 16);
        lsum += __shfl_xor(lsum, 32);
        l_run += lsum;

#pragma unroll
        for (int qt=0; qt<4; qt++){
            uint2v pk;
            pk.x = cvt_pk_bf16(e[qt][0], e[qt][1]);
            pk.y = cvt_pk_bf16(e[qt][2], e[qt][3]);
            unsigned byte = prow*128 + (((unsigned)(qt*32 + g*8)) ^ psw);
            *reinterpret_cast<uint2v*>(Pbase + byte) = pk;
        }

        __builtin_amdgcn_s_setprio(1);
#pragma unroll
        for (int ks=0;ks<2;ks++){
            unsigned abyte = prow*128 + (((unsigned)(ks*64 + g*16)) ^ psw);
            const bf16x8 pa = *reinterpret_cast<const bf16x8*>(Pbase + abyte);
#pragma unroll
            for (int cf=0;cf<4;cf++){
                unsigned vrw = (unsigned)(cf*16 + l15);
                unsigned vbyte = vrw*128 + (((unsigned)(ks*64 + g*16)) ^ ((vrw&7u)<<4));
                const bf16x8 vb = *reinterpret_cast<const bf16x8*>(
                    reinterpret_cast<const char*>(Vt[pass][cur]) + vbyte);
                acc[cf] = __builtin_amdgcn_mfma_f32_16x16x32_bf16(pa, vb, acc[cf], 0,0,0);
            }
        }
        __builtin_amdgcn_s_setprio(0);

        if (it < 15) WRSTAGE(cur^1);
        __syncthreads();
    }
#undef LDSTAGE
#undef WRSTAGE

    {
        float rl = 1.0f / l_run;
        float rr[4];
#pragma unroll
        for (int r=0;r<4;r++) rr[r] = __shfl(rl, (l & 48) | ((l>>4)*4 + r), 64);
#pragma unroll
        for (int cf=0;cf<4;cf++)
#pragma unroll
            for (int r=0;r<4;r++){
                unsigned pix = (unsigned)(wq*16 + g*4 + r);
                unsigned cch = (unsigned)(pass*64 + cf*16 + l15);
                unsigned byte = pix*384 + ((cch*2) ^ ((pix&7u)<<4));
                *reinterpret_cast<unsigned short*>(reinterpret_cast<char*>(Bs) + byte)
                    = f2bf(acc[cf][r]*rr[r]);
            }
    }
    {
        unsigned byte = (unsigned)(hrow*384) + 256u + (((unsigned)hoct*16) ^ ((unsigned)(hrow&7)<<4));
        *reinterpret_cast<ushort8*>(reinterpret_cast<char*>(Bs) + byte) = hreg;
    }
    __syncthreads();

    // GEMM1: Z[128co][64px]. wave pair: co rows (w&3)*32..+31, px half (w>>2)*32..+31
    const int wk4 = w & 3, ph2 = w >> 2;
    f32x4 acc1[2][2];
#pragma unroll
    for (int i=0;i<2;i++)
#pragma unroll
        for (int cf=0;cf<2;cf++) acc1[i][cf] = (f32x4){0.f,0.f,0.f,0.f};
#pragma unroll
    for (int ks=0; ks<4; ++ks){
        bf16x8 af[2];
#pragma unroll
        for (int i=0;i<2;i++)
            af[i] = *reinterpret_cast<const bf16x8*>(
                wzb + (size_t)(wk4*32 + i*16 + l15)*128 + ks*32 + g*8);
        __builtin_amdgcn_s_setprio(1);
#pragma unroll
        for (int cf=0;cf<2;cf++){
            unsigned p = (unsigned)(ph2*32 + cf*16 + l15);
            unsigned byte = p*384 + (((unsigned)(ks*64 + g*16)) ^ ((p&7u)<<4));
            const bf16x8 bfr = *reinterpret_cast<const bf16x8*>(
                reinterpret_cast<const char*>(Bs) + byte);
            acc1[0][cf] = __builtin_amdgcn_mfma_f32_16x16x32_bf16(af[0], bfr, acc1[0][cf], 0,0,0);
            acc1[1][cf] = __builtin_amdgcn_mfma_f32_16x16x32_bf16(af[1], bfr, acc1[1][cf], 0,0,0);
        }
        __builtin_amdgcn_s_setprio(0);
    }
    __syncthreads();
#pragma unroll
    for (int i=0;i<2;i++){
        int co = wk4*32 + i*16 + g*4;
#pragma unroll
        for (int cf=0;cf<2;cf++){
            unsigned p = (unsigned)(ph2*32 + cf*16 + l15);
#pragma unroll
            for (int r=0;r<4;r++){
                float val = acc1[i][cf][r] + bz[co+r];
                unsigned byte = p*384 + (((unsigned)((co+r)*2)) ^ ((p&7u)<<4));
                *reinterpret_cast<unsigned short*>(reinterpret_cast<char*>(Bs) + byte) = f2bf(val);
            }
        }
    }
    __syncthreads();

    // GEMM2: comb[192][64px]. wave: rows {wk4*16, 64+wk4*16, 128+wk4*16}, px half ph2*32
    f32x4 acc2[3][2];
#pragma unroll
    for (int j=0;j<3;j++)
#pragma unroll
        for (int cf=0;cf<2;cf++) acc2[j][cf] = (f32x4){0.f,0.f,0.f,0.f};
#pragma unroll
    for (int ks=0; ks<6; ++ks){
        bf16x8 am[3];
#pragma unroll
        for (int j=0;j<3;j++)
            am[j] = *reinterpret_cast<const bf16x8*>(
                wmb + (size_t)(j*64 + wk4*16 + l15)*192 + ks*32 + g*8);
        __builtin_amdgcn_s_setprio(1);
#pragma unroll
        for (int cf=0;cf<2;cf++){
            unsigned p = (unsigned)(ph2*32 + cf*16 + l15);
            unsigned byte = p*384 + (((unsigned)(ks*64 + g*16)) ^ ((p&7u)<<4));
            const bf16x8 bfr = *reinterpret_cast<const bf16x8*>(
                reinterpret_cast<const char*>(Bs) + byte);
#pragma unroll
            for (int j=0;j<3;j++)
                acc2[j][cf] = __builtin_amdgcn_mfma_f32_16x16x32_bf16(am[j], bfr, acc2[j][cf], 0,0,0);
        }
        __builtin_amdgcn_s_setprio(0);
    }

    const int ch0 = wk4*16 + g*4;
#pragma unroll
    for (int cf=0;cf<2;cf++){
        int pix = p0 + ph2*32 + cf*16 + l15;
#pragma unroll
        for (int r=0;r<4;r++){
            int ch = ch0 + r;
            float mo = acc2[0][cf][r] + bm[ch];
            float mg = acc2[1][cf][r] + bm[64+ch];
            float mi = sigmoidf_(acc2[2][cf][r] + bm[128+ch]);
            float mv = m_in[(size_t)(b*64+ch)*1024 + pix];
            float mn = (1.0f - mi)*mv + mi*tanhf_(mg);
            out_m[(size_t)(b*64+ch)*1024 + pix] = mn;
            out_h[(size_t)(b*64+ch)*1024 + pix] = sigmoidf_(mo)*mn;
        }
    }
}

extern "C" void kernel_launch(void* const* d_in, const int* in_sizes, int n_in,
                              void* d_out, int out_size, void* d_ws, size_t ws_size,
                              hipStream_t stream)
{
    const float* x      = (const float*)d_in[0];
    const float* h      = (const float*)d_in[1];
    const float* c      = (const float*)d_in[2];
    const float* m      = (const float*)d_in[3];
    const float* lc     = (const float*)d_in[4];
    const float* conv_w = (const float*)d_in[5];
    const float* conv_b = (const float*)d_in[6];
    const float* gn1_w  = (const float*)d_in[7];
    const float* gn1_b  = (const float*)d_in[8];
    const float* convL_w= (const float*)d_in[9];
    const float* convL_b= (const float*)d_in[10];
    const float* gn2_w  = (const float*)d_in[11];
    const float* gn2_b  = (const float*)d_in[12];
    const float* wq  = (const float*)d_in[13];
    const float* bq  = (const float*)d_in[14];
    const float* wk  = (const float*)d_in[15];
    const float* bk  = (const float*)d_in[16];
    const float* wk2 = (const float*)d_in[17];
    const float* bk2 = (const float*)d_in[18];
    const float* wv  = (const float*)d_in[19];
    const float* bv  = (const float*)d_in[20];
    const float* wv2 = (const float*)d_in[21];
    const float* bv2 = (const float*)d_in[22];
    const float* wz  = (const float*)d_in[23];
    const float* bz  = (const float*)d_in[24];
    const float* wmw = (const float*)d_in[25];
    const float* bm  = (const float*)d_in[26];

    float* out = (float*)d_out;
    float* F = (float*)d_ws;
    unsigned short* cc_bf  = (unsigned short*)F;              // [16][256][1024] bf16
    unsigned short* buf1   = (unsigned short*)(F + 2097152);  // padded [16][1156][128]
    unsigned short* buf2   = (unsigned short*)(F + 3280896);  // padded
    unsigned short* hT     = (unsigned short*)(F + 4464640);  // [16][1024][64]
    unsigned short* Qb     = (unsigned short*)(F + 4988928);
    unsigned short* Khb    = (unsigned short*)(F + 5251072);
    unsigned short* Kmb    = (unsigned short*)(F + 5513216);
    unsigned short* Vhb    = (unsigned short*)(F + 5775360);
    unsigned short* Vmb    = (unsigned short*)(F + 6299648);
    unsigned short* sig_pm = (unsigned short*)(F + 6823936);  // [16][1024][64]
    unsigned short* wpk1   = (unsigned short*)(F + 7348224);
    unsigned short* wpk2   = (unsigned short*)(F + 7495680);
    unsigned short* wzb    = (unsigned short*)(F + 7643136);
    unsigned short* wmb    = (unsigned short*)(F + 7651328);
    unsigned short* wph    = (unsigned short*)(F + 7669760);
    unsigned short* wpm    = (unsigned short*)(F + 7673856);
    float*          statsS = F + 7676928;                     // [16][8][256] f32
    float*          statsQ = F + 7709696;                     // [16][8][256] f32

    dim3 blk256(256);
    prep_kernel<<<dim3(1440), blk256, 0, stream>>>(conv_w, convL_w, wz, wmw,
                                                   wq, wk, wv, wk2, wv2, x, h,
                                                   wpk1, wpk2, wzb, wmb, wph, wpm,
                                                   buf1, buf2);
    conv_mfma_kernel<<<dim3(512), blk256, 0, stream>>>(buf1, wpk1, conv_b, cc_bf, statsS, statsQ);
    gn_gate1_kernel<<<dim3(512), blk256, 0, stream>>>(cc_bf, statsS, statsQ, gn1_w, gn1_b, c,
                                                      buf2, sig_pm);
    conv_mfma_kernel<<<dim3(512), blk256, 0, stream>>>(buf2, wpk2, convL_b, cc_bf, statsS, statsQ);
    gn2_proj_kernel<<<dim3(512), blk256, 0, stream>>>(cc_bf, statsS, statsQ, gn2_w, gn2_b,
                                                      lc, sig_pm, m, wph, wpm,
                                                      bq, bk, bv, bk2, bv2,
                                                      out + 3*1048576 /*lc_next*/,
                                                      out + 1*1048576 /*c_next*/,
                                                      hT, Qb, Khb, Kmb, Vhb, Vmb);
    attn_final_kernel<<<dim3(256), dim3(512), 0, stream>>>(Qb, Khb, Kmb, Vhb, Vmb, hT,
                                                           wzb, wmb, bz, bm, m,
                                                           out /*h_next*/, out + 2*1048576 /*m_next*/);
    (void)in_sizes; (void)n_in; (void)out_size; (void)ws_size;
}

// Round 15
// 103.345 us; speedup vs baseline: 1.4609x; 1.0041x over previous
//
#include <hip/hip_runtime.h>

#define DEV __device__ __forceinline__

typedef __attribute__((ext_vector_type(8))) __bf16 bf16x8;
typedef __attribute__((ext_vector_type(4))) float f32x4;
typedef __attribute__((ext_vector_type(8))) unsigned short ushort8;
typedef __attribute__((ext_vector_type(2))) unsigned short ushort2v;
typedef __attribute__((ext_vector_type(2))) unsigned int uint2v;

DEV float sigmoidf_(float x){ return 1.0f/(1.0f + __expf(-x)); }
DEV float tanhf_(float x){
    x = fminf(15.0f, fmaxf(-15.0f, x));
    float e = __expf(2.0f*x);
    return (e - 1.0f)/(e + 1.0f);
}
DEV unsigned short f2bf(float f){
    unsigned u = __builtin_bit_cast(unsigned, f);
    unsigned r = (u + 0x7FFFu + ((u>>16)&1u)) >> 16;
    return (unsigned short)r;
}
DEV float bf2f(unsigned short u){
    return __builtin_bit_cast(float, ((unsigned)u)<<16);
}
DEV unsigned cvt_pk_bf16(float lo, float hi){
    unsigned r;
    asm("v_cvt_pk_bf16_f32 %0, %1, %2" : "=v"(r) : "v"(lo), "v"(hi));
    return r;
}

// ---------- merged prep: weights -> bf16 packs ; pack x,h -> PADDED buf1/buf2 ----------
__global__ __launch_bounds__(256)
void prep_kernel(const float* __restrict__ conv_w, const float* __restrict__ convL_w,
                 const float* __restrict__ wz, const float* __restrict__ wm,
                 const float* __restrict__ wq, const float* __restrict__ wk,
                 const float* __restrict__ wv, const float* __restrict__ wk2,
                 const float* __restrict__ wv2,
                 const float* __restrict__ x, const float* __restrict__ h,
                 unsigned short* __restrict__ wpk1, unsigned short* __restrict__ wpk2,
                 unsigned short* __restrict__ wzb, unsigned short* __restrict__ wmb,
                 unsigned short* __restrict__ wph, unsigned short* __restrict__ wpm,
                 unsigned short* __restrict__ buf1, unsigned short* __restrict__ buf2)
{
    __shared__ float tile[128][65];
    if (blockIdx.x < 1152) {
        int oidx = blockIdx.x*256 + threadIdx.x;
        {
            int ci5 = oidx & 31;
            int co  = (oidx >> 5) & 255;
            int kch = oidx >> 13;
            int cic = kch / 9, tap = kch - 9*cic;
            int src = co*1152 + (cic*32 + ci5)*9 + tap;
            wpk1[oidx] = f2bf(conv_w[src]);
            wpk2[oidx] = f2bf(convL_w[src]);
        }
        if (oidx < 128*128) wzb[oidx] = f2bf(wz[oidx]);
        if (oidx < 192*192) wmb[oidx] = f2bf(wm[oidx]);
        if (oidx < 32*64){
            wph[oidx]        = f2bf(wq[oidx]);
            wph[2048 + oidx] = f2bf(wk[oidx]);
            wpm[oidx]        = f2bf(wk2[oidx]);
        }
        if (oidx < 64*64){
            wph[4096 + oidx] = f2bf(wv[oidx]);
            wpm[2048 + oidx] = f2bf(wv2[oidx]);
        }
    } else if (blockIdx.x < 1184) {
        int bx2 = blockIdx.x - 1152;
        int b = bx2 >> 1;
        unsigned short* buf = (bx2 & 1) ? buf2 : buf1;
        for (int i = threadIdx.x; i < 8448; i += 256){
            int px = i >> 6, u = i & 63;
            int rr, cc2;
            if (px < 34)      { rr = 0;         cc2 = px; }
            else if (px < 68) { rr = 33;        cc2 = px-34; }
            else if (px < 100){ rr = px-68+1;   cc2 = 0; }
            else              { rr = px-100+1;  cc2 = 33; }
            reinterpret_cast<unsigned*>(buf + (size_t)(b*1156 + rr*34 + cc2)*128)[u] = 0u;
        }
    } else {
        int i  = blockIdx.x - 1184;
        int b  = (i&7)*2 + ((i>>3)&1);
        int p0 = (i>>4) * 64;
        int t  = threadIdx.x;
        for (int k=t;k<8192;k+=256){
            int ci = k>>6, pp = k&63;
            const float* s = (ci<64) ? x + (size_t)(b*64+ci)*1024
                                     : h + (size_t)(b*64+ci-64)*1024;
            tile[ci][pp] = s[p0+pp];
        }
        __syncthreads();
        for (int k=t;k<4096;k+=256){
            int pp = k>>6, c2 = k&63;
            int p  = p0 + pp;
            size_t pidx = (size_t)(b*1156 + ((p>>5)+1)*34 + (p&31) + 1);
            ushort2v v;
            v.x = f2bf(tile[c2*2][pp]);
            v.y = f2bf(tile[c2*2+1][pp]);
            *reinterpret_cast<ushort2v*>(buf1 + pidx*128 + c2*2) = v;
            if (c2 >= 32)
                *reinterpret_cast<ushort2v*>(buf2 + pidx*128 + (c2-32)*2) = v;
        }
    }
}

// ---------- implicit-GEMM 3x3 conv via MFMA: A-ring-6 / B-ring-3 ----------
__global__ __launch_bounds__(256, 2)
void conv_mfma_kernel(const unsigned short* __restrict__ inp,
                      const unsigned short* __restrict__ wpk,
                      const float* __restrict__ bias,
                      unsigned short* __restrict__ out,
                      float* __restrict__ statsS, float* __restrict__ statsQ)
{
    const int bid = blockIdx.x;
    const int b   = (bid&7)*2 + ((bid>>3)&1);
    const int co0 = ((bid>>4)&3) * 64;
    const int rt  = bid>>6;
    const int r0  = rt * 4;
    const int t   = threadIdx.x;
    const int l   = t & 63;
    const int wv  = t >> 6;
    const int l15 = l & 15;
    const int lhi = l >> 4;

    __shared__ __align__(16) unsigned short in_t[26112];

    {
        const char* gsrc = reinterpret_cast<const char*>(inp + (size_t)(b*1156 + r0*34)*128);
#pragma unroll
        for (int it = 0; it < 13; ++it){
            unsigned lbase = (unsigned)(it*4096 + wv*1024);
            if (lbase < 52224u){
                unsigned beta = lbase + (unsigned)l*16u;
                unsigned soff = (beta & ~255u) + ((beta & 0xF0u) ^ (((beta>>8)&7u)<<4));
                __builtin_amdgcn_global_load_lds(
                    (const __attribute__((address_space(1))) void*)(gsrc + soff),
                    (__attribute__((address_space(3))) void*)(
                        (__attribute__((address_space(3))) char*)in_t + lbase),
                    16, 0, 0);
            }
        }
    }

    f32x4 acc[4][2];
#pragma unroll
    for (int i=0;i<4;i++)
#pragma unroll
        for (int f=0;f<2;f++)
            acc[i][f] = (f32x4){0.f,0.f,0.f,0.f};

    bf16x8 areg[6][4], breg[3][2];
#define LDA_(K, SLOT) do { const unsigned short* wrow_ = wpk + ((K)*256 + co0)*32; \
        for (int i_=0;i_<4;i_++) areg[SLOT][i_] = *reinterpret_cast<const bf16x8*>(wrow_ + (i_*16 + l15)*32 + lhi*8); } while(0)
#define LDB_(K, SLOT) do { const int cic_ = (K)/9, tap_ = (K) - 9*((K)/9); \
        const int ky_ = tap_/3, kx_ = tap_ - 3*(tap_/3); \
        for (int f_=0;f_<2;f_++){ int pl_ = (wv + ky_)*34 + (f_*16 + l15 + kx_); \
            unsigned by_ = (unsigned)(pl_*256 + cic_*64 + lhi*16) ^ (((unsigned)pl_ & 7u) << 4); \
            breg[SLOT][f_] = *reinterpret_cast<const bf16x8*>(reinterpret_cast<const char*>(in_t) + by_); } } while(0)

    LDA_(0, 0); LDA_(1, 1); LDA_(2, 2); LDA_(3, 3); LDA_(4, 4);
    __syncthreads();
    LDB_(0, 0); LDB_(1, 1);
#pragma unroll
    for (int k=0; k<36; ++k){
        const int as = k % 6, bs = k % 3;
        if (k+5 < 36) LDA_(k+5, (k+5)%6);
        if (k+2 < 36) LDB_(k+2, (k+2)%3);
        __builtin_amdgcn_s_setprio(1);
#pragma unroll
        for (int i=0;i<4;i++){
            acc[i][0] = __builtin_amdgcn_mfma_f32_16x16x32_bf16(areg[as][i], breg[bs][0], acc[i][0], 0,0,0);
            acc[i][1] = __builtin_amdgcn_mfma_f32_16x16x32_bf16(areg[as][i], breg[bs][1], acc[i][1], 0,0,0);
        }
        __builtin_amdgcn_s_setprio(0);
    }
#undef LDA_
#undef LDB_

    __syncthreads();
    float* red = reinterpret_cast<float*>(in_t);

    const int orow = r0 + wv;
    float s_ir[4][4], q_ir[4][4];
#pragma unroll
    for (int i=0;i<4;i++){
        int cobase = co0 + i*16 + lhi*4;
#pragma unroll
        for (int r=0;r<4;r++){
            float bs = bias[cobase+r];
            float e0 = acc[i][0][r] + bs;
            float e1 = acc[i][1][r] + bs;
            out[(size_t)(b*256 + cobase + r)*1024 + orow*32 + l15]      = f2bf(e0);
            out[(size_t)(b*256 + cobase + r)*1024 + orow*32 + 16 + l15] = f2bf(e1);
            s_ir[i][r] = e0 + e1;
            q_ir[i][r] = e0*e0 + e1*e1;
        }
    }
#pragma unroll
    for (int i=0;i<4;i++)
#pragma unroll
        for (int r=0;r<4;r++){
            float s = s_ir[i][r], q = q_ir[i][r];
            s += __shfl_xor(s,1); q += __shfl_xor(q,1);
            s += __shfl_xor(s,2); q += __shfl_xor(q,2);
            s += __shfl_xor(s,4); q += __shfl_xor(q,4);
            s += __shfl_xor(s,8); q += __shfl_xor(q,8);
            s_ir[i][r] = s; q_ir[i][r] = q;
        }
    if (l15 == 0){
#pragma unroll
        for (int i=0;i<4;i++)
#pragma unroll
            for (int r=0;r<4;r++){
                red[wv*64 + i*16 + lhi*4 + r]       = s_ir[i][r];
                red[256 + wv*64 + i*16 + lhi*4 + r] = q_ir[i][r];
            }
    }
    __syncthreads();
    if (t < 64){
        float S = red[t]+red[64+t]+red[128+t]+red[192+t];
        float Q = red[256+t]+red[320+t]+red[384+t]+red[448+t];
        statsS[((size_t)b*8 + rt)*256 + co0 + t] = S;
        statsQ[((size_t)b*8 + rt)*256 + co0 + t] = Q;
    }
}

// ---------- GN gate1, 32-pixel tiles (XCD-swizzled grid) ----------
__global__ __launch_bounds__(256)
void gn_gate1_kernel(const unsigned short* __restrict__ cc,
                     const float* __restrict__ statsS, const float* __restrict__ statsQ,
                     const float* __restrict__ gnw, const float* __restrict__ gnb,
                     const float* __restrict__ c_in,
                     unsigned short* __restrict__ buf2, unsigned short* __restrict__ sig_pm)
{
    const int bid = blockIdx.x;
    const int b   = (bid&7)*2 + ((bid>>3)&1);
    const int p0  = (bid>>4) * 32;
    const int t  = threadIdx.x;
    __shared__ float sc[256][2];
    __shared__ __align__(16) unsigned short cct[10240];

    {
        float S=0.f, Q=0.f;
#pragma unroll
        for (int part=0; part<8; ++part){
            S += statsS[((size_t)b*8 + part)*256 + t];
            Q += statsQ[((size_t)b*8 + part)*256 + t];
        }
        float mu  = S*(1.0f/1024.0f);
        float var = Q*(1.0f/1024.0f) - mu*mu;
        float rs  = rsqrtf(var + 1e-5f);
        float gw  = gnw[t];
        sc[t][0] = rs*gw;
        sc[t][1] = gnb[t] - mu*rs*gw;
    }
    for (int it=t; it<1024; it+=256){
        int row = it>>2, oct = it&3;
        ushort8 v = *reinterpret_cast<const ushort8*>(
            cc + (size_t)(b*256+row)*1024 + p0 + oct*8);
        *reinterpret_cast<ushort8*>(cct + row*40 + oct*8) = v;
    }
    __syncthreads();

    const int p = t & 31, cg = t >> 5;
    float cn[8], so[8];
#pragma unroll
    for (int j=0;j<8;j++){
        int ch = cg*8 + j;
        float xg[4];
#pragma unroll
        for (int g=0; g<4; g++){
            int row = g*64 + ch;
            float v = bf2f(cct[row*40 + p]);
            xg[g] = v*sc[row][0] + sc[row][1];
        }
        float cv = c_in[(size_t)(b*64+ch)*1024 + p0 + p];
        cn[j] = sigmoidf_(xg[1])*cv + sigmoidf_(xg[0])*tanhf_(xg[3]);
        so[j] = sigmoidf_(xg[2]);
    }
    ushort8 v0, s0;
#pragma unroll
    for (int j=0;j<8;j++){ v0[j]=f2bf(cn[j]); s0[j]=f2bf(so[j]); }
    int pg = p0 + p;
    size_t pidx = (size_t)(b*1156 + ((pg>>5)+1)*34 + (pg&31) + 1);
    *reinterpret_cast<ushort8*>(buf2 + pidx*128 + 64 + cg*8) = v0;
    *reinterpret_cast<ushort8*>(sig_pm + (size_t)(b*1024 + pg)*64 + cg*8) = s0;
}

// ---------- GN gate2 + projections fused, 32-pixel tiles (XCD-swizzled grid) ----------
__global__ __launch_bounds__(256)
void gn2_proj_kernel(const unsigned short* __restrict__ cc,
                     const float* __restrict__ statsS, const float* __restrict__ statsQ,
                     const float* __restrict__ gnw, const float* __restrict__ gnb,
                     const float* __restrict__ lc_in, const unsigned short* __restrict__ sig_pm,
                     const float* __restrict__ m_in,
                     const unsigned short* __restrict__ wph, const unsigned short* __restrict__ wpm,
                     const float* __restrict__ bq, const float* __restrict__ bk,
                     const float* __restrict__ bv, const float* __restrict__ bk2,
                     const float* __restrict__ bv2,
                     float* __restrict__ out_lc, float* __restrict__ out_c,
                     unsigned short* __restrict__ hT,
                     unsigned short* __restrict__ Qb, unsigned short* __restrict__ Khb,
                     unsigned short* __restrict__ Kmb,
                     unsigned short* __restrict__ Vhb, unsigned short* __restrict__ Vmb)
{
    const int bid = blockIdx.x;
    const int b   = (bid&7)*2 + ((bid>>3)&1);
    const int p0  = (bid>>4) * 32;
    const int t  = threadIdx.x;
    const int l  = t & 63;
    const int w  = t >> 6;
    const int l15 = l & 15, lhi = l >> 4;

    __shared__ float sc[256][2];
    __shared__ __align__(16) unsigned short cct[10240];

    {
        float S=0.f, Q=0.f;
#pragma unroll
        for (int part=0; part<8; ++part){
            S += statsS[((size_t)b*8 + part)*256 + t];
            Q += statsQ[((size_t)b*8 + part)*256 + t];
        }
        float mu  = S*(1.0f/1024.0f);
        float var = Q*(1.0f/1024.0f) - mu*mu;
        float rs  = rsqrtf(var + 1e-5f);
        float gw  = gnw[t];
        sc[t][0] = rs*gw;
        sc[t][1] = gnb[t] - mu*rs*gw;
    }
    for (int it=t; it<1024; it+=256){
        int row = it>>2, oct = it&3;
        ushort8 v = *reinterpret_cast<const ushort8*>(
            cc + (size_t)(b*256+row)*1024 + p0 + oct*8);
        *reinterpret_cast<ushort8*>(cct + row*40 + oct*8) = v;
    }
    __syncthreads();

    const int p = t & 31, cg = t >> 5;
    const size_t prow = (size_t)(b*1024 + p0 + p);
    float hm[8], mr[8];
    {
        ushort8 sv = *reinterpret_cast<const ushort8*>(sig_pm + prow*64 + cg*8);
#pragma unroll
        for (int j=0;j<8;j++){
            int ch = cg*8 + j;
            float xg[4];
#pragma unroll
            for (int g=0; g<4; g++){
                int row = g*64 + ch;
                float v = bf2f(cct[row*40 + p]);
                xg[g] = v*sc[row][0] + sc[row][1];
            }
            float lv  = lc_in[(size_t)(b*64+ch)*1024 + p0 + p];
            float lcn = sigmoidf_(xg[1])*lv + sigmoidf_(xg[0])*tanhf_(xg[3]);
            float cnx = sigmoidf_(xg[2])*tanhf_(lcn);
            out_lc[(size_t)(b*64+ch)*1024 + p0 + p] = lcn;
            out_c [(size_t)(b*64+ch)*1024 + p0 + p] = cnx;
            hm[j] = bf2f(sv[j])*tanhf_(cnx);
            mr[j] = m_in[(size_t)(b*64+ch)*1024 + p0 + p];
        }
    }
    __syncthreads();

    {
        ushort8 h0, m0;
#pragma unroll
        for (int j=0;j<8;j++){ h0[j]=f2bf(hm[j]); m0[j]=f2bf(mr[j]); }
        unsigned hb = (unsigned)(p*128) + (((unsigned)(cg*16)) ^ ((unsigned)(p&7)<<4));
        *reinterpret_cast<ushort8*>(reinterpret_cast<char*>(cct) + hb) = h0;
        *reinterpret_cast<ushort8*>(reinterpret_cast<char*>(cct) + 4096 + hb) = m0;
        *reinterpret_cast<ushort8*>(hT + prow*64 + cg*8) = h0;
    }
    __syncthreads();

    const int pass = w >> 1;
    const int pix  = (w&1)*16 + l15;
    const unsigned xsw = ((unsigned)(pix&7)) << 4;
    if (pass == 0){
        f32x4 dh[8];
#pragma unroll
        for (int i=0;i<8;i++) dh[i] = (f32x4){0.f,0.f,0.f,0.f};
#pragma unroll
        for (int ks=0; ks<2; ++ks){
            unsigned xb = (unsigned)(pix*128) + (((unsigned)(ks*64 + lhi*16)) ^ xsw);
            bf16x8 xh = *reinterpret_cast<const bf16x8*>(reinterpret_cast<const char*>(cct) + xb);
            __builtin_amdgcn_s_setprio(1);
#pragma unroll
            for (int ocf=0; ocf<8; ocf++){
                bf16x8 af = *reinterpret_cast<const bf16x8*>(
                    wph + (size_t)(ocf*16 + l15)*64 + ks*32 + lhi*8);
                dh[ocf] = __builtin_amdgcn_mfma_f32_16x16x32_bf16(af, xh, dh[ocf], 0,0,0);
            }
            __builtin_amdgcn_s_setprio(0);
        }
#pragma unroll
        for (int ocf=0; ocf<4; ocf++)
#pragma unroll
            for (int r=0;r<4;r++){
                int vc = ocf*16 + lhi*4 + r;
                Vhb[(size_t)(b*64+vc)*1024 + p0 + pix] = f2bf(dh[4+ocf][r] + bv[vc]);
            }
#pragma unroll
        for (int ocf=0; ocf<2; ocf++)
#pragma unroll
            for (int r=0;r<4;r++){
                int qc = ocf*16 + lhi*4 + r;
                unsigned byq = (unsigned)(pix*128) + (((unsigned)(qc*2))      ^ xsw);
                unsigned byk = (unsigned)(pix*128) + (((unsigned)(64 + qc*2)) ^ xsw);
                *reinterpret_cast<unsigned short*>(reinterpret_cast<char*>(cct) + 8192 + byq)
                    = f2bf(dh[ocf][r]   + bq[qc]);
                *reinterpret_cast<unsigned short*>(reinterpret_cast<char*>(cct) + 8192 + byk)
                    = f2bf(dh[2+ocf][r] + bk[qc]);
            }
    } else {
        f32x4 dm[6];
#pragma unroll
        for (int i=0;i<6;i++) dm[i] = (f32x4){0.f,0.f,0.f,0.f};
#pragma unroll
        for (int ks=0; ks<2; ++ks){
            unsigned xb = (unsigned)(pix*128) + (((unsigned)(ks*64 + lhi*16)) ^ xsw);
            bf16x8 xm = *reinterpret_cast<const bf16x8*>(
                reinterpret_cast<const char*>(cct) + 4096 + xb);
            __builtin_amdgcn_s_setprio(1);
#pragma unroll
            for (int ocf=0; ocf<6; ocf++){
                bf16x8 am = *reinterpret_cast<const bf16x8*>(
                    wpm + (size_t)(ocf*16 + l15)*64 + ks*32 + lhi*8);
                dm[ocf] = __builtin_amdgcn_mfma_f32_16x16x32_bf16(am, xm, dm[ocf], 0,0,0);
            }
            __builtin_amdgcn_s_setprio(0);
        }
#pragma unroll
        for (int ocf=0; ocf<4; ocf++)
#pragma unroll
            for (int r=0;r<4;r++){
                int vc = ocf*16 + lhi*4 + r;
                Vmb[(size_t)(b*64+vc)*1024 + p0 + pix] = f2bf(dm[2+ocf][r] + bv2[vc]);
            }
#pragma unroll
        for (int ocf=0; ocf<2; ocf++)
#pragma unroll
            for (int r=0;r<4;r++){
                int qc = ocf*16 + lhi*4 + r;
                unsigned byq = (unsigned)(pix*128) + (((unsigned)(qc*2)) ^ xsw);
                *reinterpret_cast<unsigned short*>(reinterpret_cast<char*>(cct) + 12288 + byq)
                    = f2bf(dm[ocf][r] + bk2[qc]);
            }
    }
    __syncthreads();

    {
        int pr = t>>3, oct = t&7;
        unsigned byte = (unsigned)(pr*128) + (((unsigned)(oct*16)) ^ ((unsigned)(pr&7)<<4));
        ushort8 v = *reinterpret_cast<const ushort8*>(
            reinterpret_cast<const char*>(cct) + 8192 + byte);
        if (oct < 4) *reinterpret_cast<ushort8*>(Qb  + (size_t)(b*1024+p0+pr)*32 + oct*8) = v;
        else         *reinterpret_cast<ushort8*>(Khb + (size_t)(b*1024+p0+pr)*32 + (oct-4)*8) = v;
    }
    if (t < 128){
        int pr = t>>2, oct = t&3;
        unsigned byte = (unsigned)(pr*128) + (((unsigned)(oct*16)) ^ ((unsigned)(pr&7)<<4));
        ushort8 v = *reinterpret_cast<const ushort8*>(
            reinterpret_cast<const char*>(cct) + 12288 + byte);
        *reinterpret_cast<ushort8*>(Kmb + (size_t)(b*1024+p0+pr)*32 + oct*8) = v;
    }
}

// ---------- fused attention + final mix: 256 blocks x 512 threads, 64 px/block ----------
__global__ __launch_bounds__(512)
void attn_final_kernel(const unsigned short* __restrict__ Qb,
                       const unsigned short* __restrict__ Kh,
                       const unsigned short* __restrict__ Km,
                       const unsigned short* __restrict__ Vh,
                       const unsigned short* __restrict__ Vm,
                       const unsigned short* __restrict__ hT,
                       const unsigned short* __restrict__ wzb,
                       const unsigned short* __restrict__ wmb,
                       const float* __restrict__ bz, const float* __restrict__ bm,
                       const float* __restrict__ m_in,
                       float* __restrict__ out_h, float* __restrict__ out_m)
{
    const int bid  = blockIdx.x;
    const int b    = (bid&7)*2 + ((bid>>3)&1);
    const int p0   = (bid>>4) * 64;
    const int t   = threadIdx.x;
    const int l   = t & 63;
    const int w   = t >> 6;
    const int l15 = l & 15, g = l >> 4;
    const int pass = w >> 2;
    const int wq   = w & 3;

    __shared__ __align__(16) unsigned short Kt[2][2][2560];
    __shared__ __align__(16) unsigned short Vt[2][2][4096];
    __shared__ __align__(16) unsigned short Pt[2][4096];
    __shared__ __align__(16) unsigned short Bs[64*192];

    const bf16x8 qa = *reinterpret_cast<const bf16x8*>(
        Qb + (size_t)(b*1024 + p0 + wq*16 + l15)*32 + g*8);

    const int hrow = t>>3, hoct = t&7;
    const ushort8 hreg = *reinterpret_cast<const ushort8*>(
        hT + (size_t)(b*1024 + p0 + hrow)*64 + hoct*8);

    float m_run = -1e30f, l_run = 0.0f;
    f32x4 acc[4];
#pragma unroll
    for (int cf=0;cf<4;cf++) acc[cf] = (f32x4){0.f,0.f,0.f,0.f};

    const int ktens = t>>8;
    const int krow  = (t>>2)&63, koct = t&3;
    const int vrow  = t>>3, voct = t&7;
    const unsigned kwb = (unsigned)(krow*80 + koct*16);
    const unsigned vwb = (unsigned)(vrow*128) + (((unsigned)voct*16) ^ ((unsigned)(vrow&7)<<4));
    const unsigned short* Kgsrc = ktens ? Km : Kh;

    ushort8 kr0, vv0, vv1;
#define LDSTAGE(Q0N) do { \
        kr0 = *reinterpret_cast<const ushort8*>(Kgsrc + (size_t)(b*1024 + (Q0N) + krow)*32 + koct*8); \
        vv0 = *reinterpret_cast<const ushort8*>(Vh + (size_t)(b*64 + vrow)*1024 + (Q0N) + voct*8); \
        vv1 = *reinterpret_cast<const ushort8*>(Vm + (size_t)(b*64 + vrow)*1024 + (Q0N) + voct*8); \
    } while(0)
#define WRSTAGE(BUF) do { \
        *reinterpret_cast<ushort8*>(reinterpret_cast<char*>(Kt[ktens][BUF]) + kwb) = kr0; \
        *reinterpret_cast<ushort8*>(reinterpret_cast<char*>(Vt[0][BUF]) + vwb) = vv0; \
        *reinterpret_cast<ushort8*>(reinterpret_cast<char*>(Vt[1][BUF]) + vwb) = vv1; \
    } while(0)

    LDSTAGE(0);
    WRSTAGE(0);
    __syncthreads();

    const unsigned prow = (unsigned)(wq*16 + l15);
    const unsigned psw  = (prow & 7u) << 4;
    char* Pbase = reinterpret_cast<char*>(Pt[pass]);

    for (int it=0; it<16; ++it){
        const int cur = it & 1;
        if (it < 15) LDSTAGE((it+1)*64);

        f32x4 s2[4];
        __builtin_amdgcn_s_setprio(1);
#pragma unroll
        for (int qt=0; qt<4; qt++){
            const bf16x8 kb = *reinterpret_cast<const bf16x8*>(
                reinterpret_cast<const char*>(Kt[pass][cur]) + (qt*16 + l15)*80 + g*16);
            s2[qt] = __builtin_amdgcn_mfma_f32_16x16x32_bf16(kb, qa, (f32x4){0.f,0.f,0.f,0.f}, 0,0,0);
        }
        __builtin_amdgcn_s_setprio(0);

        float pm = s2[0][0];
#pragma unroll
        for (int qt=0; qt<4; qt++)
#pragma unroll
            for (int r=0;r<4;r++) pm = fmaxf(pm, s2[qt][r]);
        pm = fmaxf(pm, __shfl_xor(pm, 16));
        pm = fmaxf(pm, __shfl_xor(pm, 32));

        if (!__all(pm <= m_run + 8.0f)){
            float mn = fmaxf(m_run, pm);
            float f  = __expf(m_run - mn);
            m_run = mn;
            l_run *= f;
#pragma unroll
            for (int r=0;r<4;r++){
                float fr = __shfl(f, (l & 48) | ((l>>4)*4 + r), 64);
#pragma unroll
                for (int cf=0;cf<4;cf++) acc[cf][r] *= fr;
            }
        }

        float e[4][4];
        float lsum = 0.f;
#pragma unroll
        for (int qt=0; qt<4; qt++)
#pragma unroll
            for (int r=0;r<4;r++){
                float ev = __expf(s2[qt][r] - m_run);
                e[qt][r] = ev;
                lsum += ev;
            }
        lsum += __shfl_xor(lsum, 16);
        lsum += __shfl_xor(lsum, 32);
        l_run += lsum;

#pragma unroll
        for (int qt=0; qt<4; qt++){
            uint2v pk;
            pk.x = cvt_pk_bf16(e[qt][0], e[qt][1]);
            pk.y = cvt_pk_bf16(e[qt][2], e[qt][3]);
            unsigned byte = prow*128 + (((unsigned)(qt*32 + g*8)) ^ psw);
            *reinterpret_cast<uint2v*>(Pbase + byte) = pk;
        }

        __builtin_amdgcn_s_setprio(1);
#pragma unroll
        for (int ks=0;ks<2;ks++){
            unsigned abyte = prow*128 + (((unsigned)(ks*64 + g*16)) ^ psw);
            const bf16x8 pa = *reinterpret_cast<const bf16x8*>(Pbase + abyte);
#pragma unroll
            for (int cf=0;cf<4;cf++){
                unsigned vrw = (unsigned)(cf*16 + l15);
                unsigned vbyte = vrw*128 + (((unsigned)(ks*64 + g*16)) ^ ((vrw&7u)<<4));
                const bf16x8 vb = *reinterpret_cast<const bf16x8*>(
                    reinterpret_cast<const char*>(Vt[pass][cur]) + vbyte);
                acc[cf] = __builtin_amdgcn_mfma_f32_16x16x32_bf16(pa, vb, acc[cf], 0,0,0);
            }
        }
        __builtin_amdgcn_s_setprio(0);

        if (it < 15) WRSTAGE(cur^1);
        __syncthreads();
    }
#undef LDSTAGE
#undef WRSTAGE

    {
        float rl = 1.0f / l_run;
        float rr[4];
#pragma unroll
        for (int r=0;r<4;r++) rr[r] = __shfl(rl, (l & 48) | ((l>>4)*4 + r), 64);
#pragma unroll
        for (int cf=0;cf<4;cf++)
#pragma unroll
            for (int r=0;r<4;r++){
                unsigned pix = (unsigned)(wq*16 + g*4 + r);
                unsigned cch = (unsigned)(pass*64 + cf*16 + l15);
                unsigned byte = pix*384 + ((cch*2) ^ ((pix&7u)<<4));
                *reinterpret_cast<unsigned short*>(reinterpret_cast<char*>(Bs) + byte)
                    = f2bf(acc[cf][r]*rr[r]);
            }
    }
    {
        unsigned byte = (unsigned)(hrow*384) + 256u + (((unsigned)hoct*16) ^ ((unsigned)(hrow&7)<<4));
        *reinterpret_cast<ushort8*>(reinterpret_cast<char*>(Bs) + byte) = hreg;
    }
    __syncthreads();

    const int wk4 = w & 3, ph2 = w >> 2;
    f32x4 acc1[2][2];
#pragma unroll
    for (int i=0;i<2;i++)
#pragma unroll
        for (int cf=0;cf<2;cf++) acc1[i][cf] = (f32x4){0.f,0.f,0.f,0.f};
#pragma unroll
    for (int ks=0; ks<4; ++ks){
        bf16x8 af[2];
#pragma unroll
        for (int i=0;i<2;i++)
            af[i] = *reinterpret_cast<const bf16x8*>(
                wzb + (size_t)(wk4*32 + i*16 + l15)*128 + ks*32 + g*8);
        __builtin_amdgcn_s_setprio(1);
#pragma unroll
        for (int cf=0;cf<2;cf++){
            unsigned p = (unsigned)(ph2*32 + cf*16 + l15);
            unsigned byte = p*384 + (((unsigned)(ks*64 + g*16)) ^ ((p&7u)<<4));
            const bf16x8 bfr = *reinterpret_cast<const bf16x8*>(
                reinterpret_cast<const char*>(Bs) + byte);
            acc1[0][cf] = __builtin_amdgcn_mfma_f32_16x16x32_bf16(af[0], bfr, acc1[0][cf], 0,0,0);
            acc1[1][cf] = __builtin_amdgcn_mfma_f32_16x16x32_bf16(af[1], bfr, acc1[1][cf], 0,0,0);
        }
        __builtin_amdgcn_s_setprio(0);
    }
    __syncthreads();
#pragma unroll
    for (int i=0;i<2;i++){
        int co = wk4*32 + i*16 + g*4;
#pragma unroll
        for (int cf=0;cf<2;cf++){
            unsigned p = (unsigned)(ph2*32 + cf*16 + l15);
#pragma unroll
            for (int r=0;r<4;r++){
                float val = acc1[i][cf][r] + bz[co+r];
                unsigned byte = p*384 + (((unsigned)((co+r)*2)) ^ ((p&7u)<<4));
                *reinterpret_cast<unsigned short*>(reinterpret_cast<char*>(Bs) + byte) = f2bf(val);
            }
        }
    }
    __syncthreads();

    f32x4 acc2[3][2];
#pragma unroll
    for (int j=0;j<3;j++)
#pragma unroll
        for (int cf=0;cf<2;cf++) acc2[j][cf] = (f32x4){0.f,0.f,0.f,0.f};
#pragma unroll
    for (int ks=0; ks<6; ++ks){
        bf16x8 am[3];
#pragma unroll
        for (int j=0;j<3;j++)
            am[j] = *reinterpret_cast<const bf16x8*>(
                wmb + (size_t)(j*64 + wk4*16 + l15)*192 + ks*32 + g*8);
        __builtin_amdgcn_s_setprio(1);
#pragma unroll
        for (int cf=0;cf<2;cf++){
            unsigned p = (unsigned)(ph2*32 + cf*16 + l15);
            unsigned byte = p*384 + (((unsigned)(ks*64 + g*16)) ^ ((p&7u)<<4));
            const bf16x8 bfr = *reinterpret_cast<const bf16x8*>(
                reinterpret_cast<const char*>(Bs) + byte);
#pragma unroll
            for (int j=0;j<3;j++)
                acc2[j][cf] = __builtin_amdgcn_mfma_f32_16x16x32_bf16(am[j], bfr, acc2[j][cf], 0,0,0);
        }
        __builtin_amdgcn_s_setprio(0);
    }

    const int ch0 = wk4*16 + g*4;
#pragma unroll
    for (int cf=0;cf<2;cf++){
        int pix = p0 + ph2*32 + cf*16 + l15;
#pragma unroll
        for (int r=0;r<4;r++){
            int ch = ch0 + r;
            float mo = acc2[0][cf][r] + bm[ch];
            float mg = acc2[1][cf][r] + bm[64+ch];
            float mi = sigmoidf_(acc2[2][cf][r] + bm[128+ch]);
            float mv = m_in[(size_t)(b*64+ch)*1024 + pix];
            float mn = (1.0f - mi)*mv + mi*tanhf_(mg);
            out_m[(size_t)(b*64+ch)*1024 + pix] = mn;
            out_h[(size_t)(b*64+ch)*1024 + pix] = sigmoidf_(mo)*mn;
        }
    }
}

extern "C" void kernel_launch(void* const* d_in, const int* in_sizes, int n_in,
                              void* d_out, int out_size, void* d_ws, size_t ws_size,
                              hipStream_t stream)
{
    const float* x      = (const float*)d_in[0];
    const float* h      = (const float*)d_in[1];
    const float* c      = (const float*)d_in[2];
    const float* m      = (const float*)d_in[3];
    const float* lc     = (const float*)d_in[4];
    const float* conv_w = (const float*)d_in[5];
    const float* conv_b = (const float*)d_in[6];
    const float* gn1_w  = (const float*)d_in[7];
    const float* gn1_b  = (const float*)d_in[8];
    const float* convL_w= (const float*)d_in[9];
    const float* convL_b= (const float*)d_in[10];
    const float* gn2_w  = (const float*)d_in[11];
    const float* gn2_b  = (const float*)d_in[12];
    const float* wq  = (const float*)d_in[13];
    const float* bq  = (const float*)d_in[14];
    const float* wk  = (const float*)d_in[15];
    const float* bk  = (const float*)d_in[16];
    const float* wk2 = (const float*)d_in[17];
    const float* bk2 = (const float*)d_in[18];
    const float* wv  = (const float*)d_in[19];
    const float* bv  = (const float*)d_in[20];
    const float* wv2 = (const float*)d_in[21];
    const float* bv2 = (const float*)d_in[22];
    const float* wz  = (const float*)d_in[23];
    const float* bz  = (const float*)d_in[24];
    const float* wmw = (const float*)d_in[25];
    const float* bm  = (const float*)d_in[26];

    float* out = (float*)d_out;
    float* F = (float*)d_ws;
    unsigned short* cc_bf  = (unsigned short*)F;
    unsigned short* buf1   = (unsigned short*)(F + 2097152);
    unsigned short* buf2   = (unsigned short*)(F + 3280896);
    unsigned short* hT     = (unsigned short*)(F + 4464640);
    unsigned short* Qb     = (unsigned short*)(F + 4988928);
    unsigned short* Khb    = (unsigned short*)(F + 5251072);
    unsigned short* Kmb    = (unsigned short*)(F + 5513216);
    unsigned short* Vhb    = (unsigned short*)(F + 5775360);
    unsigned short* Vmb    = (unsigned short*)(F + 6299648);
    unsigned short* sig_pm = (unsigned short*)(F + 6823936);
    unsigned short* wpk1   = (unsigned short*)(F + 7348224);
    unsigned short* wpk2   = (unsigned short*)(F + 7495680);
    unsigned short* wzb    = (unsigned short*)(F + 7643136);
    unsigned short* wmb    = (unsigned short*)(F + 7651328);
    unsigned short* wph    = (unsigned short*)(F + 7669760);
    unsigned short* wpm    = (unsigned short*)(F + 7673856);
    float*          statsS = F + 7676928;
    float*          statsQ = F + 7709696;

    dim3 blk256(256);
    prep_kernel<<<dim3(1440), blk256, 0, stream>>>(conv_w, convL_w, wz, wmw,
                                                   wq, wk, wv, wk2, wv2, x, h,
                                                   wpk1, wpk2, wzb, wmb, wph, wpm,
                                                   buf1, buf2);
    conv_mfma_kernel<<<dim3(512), blk256, 0, stream>>>(buf1, wpk1, conv_b, cc_bf, statsS, statsQ);
    gn_gate1_kernel<<<dim3(512), blk256, 0, stream>>>(cc_bf, statsS, statsQ, gn1_w, gn1_b, c,
                                                      buf2, sig_pm);
    conv_mfma_kernel<<<dim3(512), blk256, 0, stream>>>(buf2, wpk2, convL_b, cc_bf, statsS, statsQ);
    gn2_proj_kernel<<<dim3(512), blk256, 0, stream>>>(cc_bf, statsS, statsQ, gn2_w, gn2_b,
                                                      lc, sig_pm, m, wph, wpm,
                                                      bq, bk, bv, bk2, bv2,
                                                      out + 3*1048576 /*lc_next*/,
                                                      out + 1*1048576 /*c_next*/,
                                                      hT, Qb, Khb, Kmb, Vhb, Vmb);
    attn_final_kernel<<<dim3(256), dim3(512), 0, stream>>>(Qb, Khb, Kmb, Vhb, Vmb, hT,
                                                           wzb, wmb, bz, bm, m,
                                                           out /*h_next*/, out + 2*1048576 /*m_next*/);
    (void)in_sizes; (void)n_in; (void)out_size; (void)ws_size;
}